// Round 9
// baseline (457.174 us; speedup 1.0000x reference)
//
#include <hip/hip_runtime.h>
#include <hip/hip_fp16.h>

// Problem constants
static constexpr int kN = 50000;      // nodes per side
static constexpr int kE = 800000;     // edges per side
static constexpr int kG = 1024;       // graphs per batch
static constexpr int kEMB = 128;
static constexpr int kGH = 256;
static constexpr int kEH = 256;
static constexpr int kOUT = 128;
static constexpr int kHID = 512;
static constexpr int kNB = (kN + 255) / 256;   // 196 chunks per side
static constexpr int kMD = 64;        // ELL stride; deg ~ Poisson(16), P(deg>=64)~e^-125
static constexpr int kNBKT = 196;     // dst buckets of 256 nodes (50000 -> 196)
static constexpr int kEPB = 3125;     // edges per bin block; 256 blocks exactly
static constexpr int kPBLK = 256;     // bin blocks per side (256*3125 = 800000)
static constexpr int kPP = 8;         // aggpool partitions per graph

typedef __attribute__((ext_vector_type(8))) _Float16 half8v;
typedef __attribute__((ext_vector_type(4))) _Float16 half4v;
typedef __attribute__((ext_vector_type(4))) float floatx4;
typedef __attribute__((ext_vector_type(2))) float floatx2;

// NOTE (R6): cross-XCD plain-data handoff through grid.sync() gave stale reads.
// NOTE (R7/R12): device atomics memory-side; floor is OP-COUNT ~21/ns.
// (R10) lookback scan regressed. (R11) role-merged grids regressed.
// (R2) fp8 hs: 659->616us. (R3) conv1 DPP groups: ->596us. (R4) NEUTRAL.
// (R5) ELL fusion regressed rank (atomics+random stores share mem-op pipe).
// (R6) LDS bucket binning, zero global atomics: 585->523us.
// (R7) fp16-MFMA unified tail: 523->439us, absmax UNCHANGED.
// (R8) aggregate+pool fusion: 439->429us BUT aggpool itself 102us vs 60.5+pool
// — one-block-per-graph starved parallelism (HBM 45%->23%, occ 70%->45%,
// serial ~12-node wave loops + graph-size stragglers). Traffic win was real
// (WRITE 50MB->1MB). This revision (R9): keep fusion, restore parallelism —
// P=8 partition blocks per graph write private fp32 partials (no atomics),
// tiny preduce sums them. 16384x2 blocks, 1-2 nodes/wave.

// fp8 fixed scale: |hs| <~ 0.2 typ; x128 keeps values in e4m3 normal range.
#define HS_SCALE 128.0f
#define HS_INV   (1.0f / 128.0f)

__device__ inline void acc_fp8x4(unsigned int w, float& a0, float& a1, float& a2, float& a3) {
    floatx2 lo = __builtin_amdgcn_cvt_pk_f32_fp8(w, false);
    floatx2 hi = __builtin_amdgcn_cvt_pk_f32_fp8(w, true);
    a0 += lo[0]; a1 += lo[1]; a2 += hi[0]; a3 += hi[1];
}

// 16-lane group sum via DPP row_ror rotations (1,2,4,8).
__device__ inline float grp16_reduce(float v) {
    int x;
    x = __builtin_amdgcn_update_dpp(0, __float_as_int(v), 0x121, 0xF, 0xF, true);
    v += __int_as_float(x);
    x = __builtin_amdgcn_update_dpp(0, __float_as_int(v), 0x122, 0xF, 0xF, true);
    v += __int_as_float(x);
    x = __builtin_amdgcn_update_dpp(0, __float_as_int(v), 0x124, 0xF, 0xF, true);
    v += __int_as_float(x);
    x = __builtin_amdgcn_update_dpp(0, __float_as_int(v), 0x128, 0xF, 0xF, true);
    v += __int_as_float(x);
    return v;
}

// ---------------------------------------------------------------------------
// prep: w2t = fp16(gW2^T) (blocks 0..255), M11 = atom_emb@gW1 (blocks 256..266)
// ---------------------------------------------------------------------------
__global__ void prep_kernel(const float* __restrict__ atom_emb, const float* __restrict__ gW1,
                            const float* __restrict__ gW2,
                            float* __restrict__ M11, _Float16* __restrict__ w2t) {
    int i = blockIdx.x * 256 + threadIdx.x;
    if (blockIdx.x < 256) {
        int k = i >> 8, n = i & 255;
        w2t[(size_t)n * kGH + k] = (_Float16)gW2[(size_t)k * kGH + n];
    } else {
        int j = i - 65536;
        if (j < 11 * kGH) {
            int r = j >> 8, c = j & 255;
            float s = 0.f;
            for (int k = 0; k < kEMB; k++) s += atom_emb[r * kEMB + k] * gW1[k * kGH + c];
            M11[j] = s;
        }
    }
}

// ---------------------------------------------------------------------------
// wtrans: all tail weights -> fp16 transposed ([N][K] from [K][N]).
// ---------------------------------------------------------------------------
__global__ void wtrans_kernel(const float* __restrict__ dW1, const float* __restrict__ dW2,
                              const float* __restrict__ dW3, const float* __restrict__ fcW,
                              const float* __restrict__ eW1, const float* __restrict__ eW2,
                              _Float16* __restrict__ dW1t, _Float16* __restrict__ dW2t,
                              _Float16* __restrict__ dW3t, _Float16* __restrict__ fcWt,
                              _Float16* __restrict__ eW1t, _Float16* __restrict__ eW2t) {
    int b = blockIdx.x;
    const float* src; _Float16* dst; int K, N, j0;
    if (b < 1024)      { src = dW1; dst = dW1t; K = 512; N = 512; j0 = b * 256; }
    else if (b < 2048) { src = dW2; dst = dW2t; K = 512; N = 512; j0 = (b - 1024) * 256; }
    else if (b < 2304) { src = dW3; dst = dW3t; K = 512; N = 128; j0 = (b - 2048) * 256; }
    else if (b < 2560) { src = fcW; dst = fcWt; K = 256; N = 256; j0 = (b - 2304) * 256; }
    else if (b < 2688) { src = eW1; dst = eW1t; K = 128; N = 256; j0 = (b - 2560) * 256; }
    else               { src = eW2; dst = eW2t; K = 256; N = 256; j0 = (b - 2688) * 256; }
    int j = j0 + threadIdx.x;            // dst linear: n*K + k
    int n = j / K, k = j - n * K;
    dst[j] = (_Float16)src[(size_t)k * N + n];
}

// ---------------------------------------------------------------------------
// binp1: per-block LDS histogram over 196 dst-buckets.
// ---------------------------------------------------------------------------
__global__ void binp1_kernel(const int* __restrict__ ei1, const int* __restrict__ ei2,
                             int* __restrict__ poff) {
    int side = blockIdx.y;
    const int* dst = (side ? ei2 : ei1) + kE;
    __shared__ int hist[kNBKT];
    int t = threadIdx.x;
    if (t < kNBKT) hist[t] = 0;
    __syncthreads();
    int base = blockIdx.x * kEPB;
    for (int j = t; j < kEPB; j += 256)
        atomicAdd(&hist[dst[base + j] >> 8], 1);
    __syncthreads();
    if (t < kNBKT) poff[((side * kNBKT + t) << 8) | blockIdx.x] = hist[t];
}

// scanA: per (side,bucket) exclusive scan over the 256 block counts.
__global__ void scanA_kernel(int* __restrict__ poff, int* __restrict__ btot) {
    int b = blockIdx.x, side = blockIdx.y, t = threadIdx.x;
    __shared__ int s[256];
    int idx = ((side * kNBKT + b) << 8) | t;
    int v = poff[idx];
    s[t] = v;
    __syncthreads();
    for (int o = 1; o < 256; o <<= 1) {
        int u = (t >= o) ? s[t - o] : 0;
        __syncthreads();
        s[t] += u;
        __syncthreads();
    }
    poff[idx] = s[t] - v;
    if (t == 255) btot[side * kNBKT + b] = s[255];
}

// scanB: exclusive scan of bucket totals -> bbase.
__global__ void scanB_kernel(const int* __restrict__ btot, int* __restrict__ bbase) {
    int side = blockIdx.x, t = threadIdx.x;
    __shared__ int s[256];
    int v = (t < kNBKT) ? btot[side * kNBKT + t] : 0;
    s[t] = v;
    __syncthreads();
    for (int o = 1; o < 256; o <<= 1) {
        int u = (t >= o) ? s[t - o] : 0;
        __syncthreads();
        s[t] += u;
        __syncthreads();
    }
    if (t < kNBKT) bbase[side * (kNBKT + 1) + t] = s[t] - v;
    if (t == 255) bbase[side * (kNBKT + 1) + kNBKT] = s[255];
}

// ---------------------------------------------------------------------------
// binp2: block-local LDS bucket-sort, coalesced bucket-major write-out.
// ---------------------------------------------------------------------------
__launch_bounds__(256)
__global__ void binp2_kernel(const int* __restrict__ ei1, const int* __restrict__ ei2,
                             const int* __restrict__ poff, const int* __restrict__ bbase,
                             unsigned int* __restrict__ ebuf) {
    int side = blockIdx.y, blk = blockIdx.x, t = threadIdx.x;
    const int* ei = side ? ei2 : ei1;
    __shared__ int hist[kNBKT], lb[kNBKT], gb[kNBKT], scanbuf[256];
    __shared__ unsigned int sorted[kEPB];
    if (t < kNBKT) hist[t] = 0;
    __syncthreads();
    int base = blk * kEPB;
    for (int j = t; j < kEPB; j += 256)
        atomicAdd(&hist[ei[kE + base + j] >> 8], 1);
    __syncthreads();
    int v = (t < kNBKT) ? hist[t] : 0;
    scanbuf[t] = v;
    __syncthreads();
    for (int o = 1; o < 256; o <<= 1) {
        int u = (t >= o) ? scanbuf[t - o] : 0;
        __syncthreads();
        scanbuf[t] += u;
        __syncthreads();
    }
    if (t < kNBKT) {
        lb[t] = scanbuf[t] - v;
        gb[t] = bbase[side * (kNBKT + 1) + t] + poff[((side * kNBKT + t) << 8) | blk];
        hist[t] = 0;
    }
    __syncthreads();
    for (int j = t; j < kEPB; j += 256) {
        int s_ = ei[base + j];
        int d  = ei[kE + base + j];
        int b  = d >> 8;
        int r  = atomicAdd(&hist[b], 1);
        sorted[lb[b] + r] = ((unsigned int)d << 16) | (unsigned int)s_;
    }
    __syncthreads();
    for (int j = t; j < kEPB; j += 256) {
        unsigned int val = sorted[j];
        int b = val >> 24;
        int gpos = gb[b] + (j - lb[b]);
        ebuf[(size_t)side * kE + gpos] = val;
    }
}

// ---------------------------------------------------------------------------
// binp3: one block per bucket; LDS slot counters; col_ell stores in a 32KB
// window. Fused epilogue: degrees->counts, dinv, xd.
// ---------------------------------------------------------------------------
__global__ void binp3_kernel(const unsigned int* __restrict__ ebuf, const int* __restrict__ bbase,
                             unsigned short* __restrict__ col_ell, int* __restrict__ counts,
                             float* __restrict__ dinv, int2* __restrict__ xd,
                             const int* __restrict__ x1, const int* __restrict__ x2) {
    int b = blockIdx.x, side = blockIdx.y, t = threadIdx.x;
    __shared__ int cnt[256];
    cnt[t] = 0;
    __syncthreads();
    int start = bbase[side * (kNBKT + 1) + b];
    int end   = bbase[side * (kNBKT + 1) + b + 1];
    for (int k = start + t; k < end; k += 256) {
        unsigned int v = ebuf[(size_t)side * kE + k];
        int d8 = (v >> 16) & 255;
        int slot = atomicAdd(&cnt[d8], 1);
        if (slot > kMD - 1) slot = kMD - 1;
        int node = (b << 8) | d8;
        col_ell[((size_t)side * kN + node) * kMD + slot] = (unsigned short)(v & 0xFFFFu);
    }
    __syncthreads();
    int node = (b << 8) | t;
    if (node < kN) {
        int d = cnt[t];
        counts[side * kN + node] = d;
        float dv = rsqrtf((float)(d + 1));           // +1 self-loop
        dinv[side * kN + node] = dv;
        const int* x = side ? x2 : x1;
        xd[side * kN + node] = make_int2(x[node], __float_as_int(dv));
    }
}

// ---------------------------------------------------------------------------
// Conv1 combine, 16-lane groups (4 nodes/wave), DPP reduce, zero LDS ops.
// ---------------------------------------------------------------------------
__global__ void conv1_combine_kernel(const int2* __restrict__ xd,
                                     const int* __restrict__ counts,
                                     const unsigned short* __restrict__ col_ell,
                                     const float* __restrict__ M11,
                                     const float* __restrict__ bias,
                                     _Float16* __restrict__ out) {
    int side = blockIdx.y;
    const int2* xdb = xd + (size_t)side * kN;
    const int* deg = counts + side * kN;
    const unsigned short* ci = col_ell + (size_t)side * kN * kMD;
    _Float16* ob = out + (size_t)side * kN * kGH;

    int tid = threadIdx.x;
    int sub = tid & 15;
    int v = blockIdx.x * 16 + (tid >> 4);

    int cnt = min(deg[v], kMD);
    const unsigned short* cv = ci + (size_t)v * kMD;
    float wt[11];
    #pragma unroll
    for (int t = 0; t < 11; t++) wt[t] = 0.f;
    for (int base = 0; base < cnt; base += 16) {
        int e = base + sub;
        int xs = 15; float ds = 0.f;
        if (e < cnt) {
            int2 t = xdb[(int)cv[e]];
            xs = t.x; ds = __int_as_float(t.y);
        }
        #pragma unroll
        for (int t = 0; t < 11; t++) wt[t] += (xs == t) ? ds : 0.f;
    }
    #pragma unroll
    for (int t = 0; t < 11; t++) wt[t] = grp16_reduce(wt[t]);

    int2 xv = xdb[v];
    float dv = __int_as_float(xv.y);
    #pragma unroll
    for (int q = 0; q < 4; q++) {
        int c = q * 64 + sub * 4;
        float4 bia = *(const float4*)(bias + c);
        float4 m = *(const float4*)(M11 + xv.x * kGH + c);
        float4 acc = make_float4(dv * m.x, dv * m.y, dv * m.z, dv * m.w);
        #pragma unroll
        for (int t = 0; t < 11; t++) {
            float w = wt[t];
            float4 mt = *(const float4*)(M11 + t * kGH + c);
            acc.x += w * mt.x; acc.y += w * mt.y;
            acc.z += w * mt.z; acc.w += w * mt.w;
        }
        half4v o;
        o[0] = (_Float16)fmaxf(dv * acc.x + bia.x, 0.f);
        o[1] = (_Float16)fmaxf(dv * acc.y + bia.y, 0.f);
        o[2] = (_Float16)fmaxf(dv * acc.z + bia.z, 0.f);
        o[3] = (_Float16)fmaxf(dv * acc.w + bia.w, 0.f);
        *(half4v*)(ob + (size_t)v * kGH + c) = o;
    }
}

// ---------------------------------------------------------------------------
// Conv2 GEMM via MFMA f16, LDS-tiled: hs = fp8(HS_SCALE * dinv ⊙ (h2 @ W2))
// BM=128, BN=128, BK=64. 4 waves (2x2); wave = 64x64.
// ---------------------------------------------------------------------------
__launch_bounds__(256)
__global__ void gemm2_mfma_kernel(const _Float16* __restrict__ A,
                                  const _Float16* __restrict__ Bt,
                                  const float* __restrict__ dinv,
                                  unsigned char* __restrict__ C) {
    __shared__ _Float16 As[128][72];
    __shared__ _Float16 Bs[128][72];

    int side = blockIdx.z;
    const _Float16* Ab = A + (size_t)side * kN * kGH;
    const float* db = dinv + (size_t)side * kN;
    unsigned char* Cb = C + (size_t)side * kN * kGH;

    int tid = threadIdx.x;
    int wave = tid >> 6, lane = tid & 63;
    int quad = lane >> 4, r = lane & 15;
    int wm = wave >> 1, wn = wave & 1;
    int row0 = blockIdx.x * 128;
    int col0 = blockIdx.y * 128;

    floatx4 acc[4][4];
    #pragma unroll
    for (int i = 0; i < 4; i++)
        #pragma unroll
        for (int j = 0; j < 4; j++) acc[i][j] = (floatx4){0.f, 0.f, 0.f, 0.f};

    for (int k0 = 0; k0 < kGH; k0 += 64) {
        #pragma unroll
        for (int u = 0; u < 4; u++) {
            int idx = tid + u * 256;
            int row = idx >> 3;
            int seg = (idx & 7) * 8;
            int gr = row0 + row;
            if (gr >= kN) gr = kN - 1;
            *(half8v*)&As[row][seg] = *(const half8v*)(Ab + (size_t)gr * kGH + k0 + seg);
            *(half8v*)&Bs[row][seg] = *(const half8v*)(Bt + (size_t)(col0 + row) * kGH + k0 + seg);
        }
        __syncthreads();
        #pragma unroll
        for (int ks = 0; ks < 2; ks++) {
            half8v af[4], bf[4];
            #pragma unroll
            for (int mt = 0; mt < 4; mt++)
                af[mt] = *(const half8v*)&As[wm * 64 + mt * 16 + r][ks * 32 + quad * 8];
            #pragma unroll
            for (int nt = 0; nt < 4; nt++)
                bf[nt] = *(const half8v*)&Bs[wn * 64 + nt * 16 + r][ks * 32 + quad * 8];
            #pragma unroll
            for (int mt = 0; mt < 4; mt++)
                #pragma unroll
                for (int nt = 0; nt < 4; nt++)
                    acc[mt][nt] = __builtin_amdgcn_mfma_f32_16x16x32_f16(af[mt], bf[nt],
                                                                         acc[mt][nt], 0, 0, 0);
        }
        __syncthreads();
    }

    #pragma unroll
    for (int mt = 0; mt < 4; mt++) {
        #pragma unroll
        for (int i = 0; i < 4; i++) {
            int grow = row0 + wm * 64 + mt * 16 + quad * 4 + i;
            if (grow >= kN) continue;
            float rsq = db[grow] * HS_SCALE;
            #pragma unroll
            for (int nt = 0; nt < 4; nt++) {
                int gcol = col0 + wn * 64 + nt * 16 + r;
                float q = acc[mt][nt][i] * rsq;
                Cb[(size_t)grow * kGH + gcol] =
                    (unsigned char)__builtin_amdgcn_cvt_pk_fp8_f32(q, q, 0, false);
            }
        }
    }
}

// ---------------------------------------------------------------------------
// Unified tail GEMM via MFMA f16 (fp32 accum): C = [relu](A @ B + bias)
// ---------------------------------------------------------------------------
__launch_bounds__(256)
__global__ void gemm_tail_kernel(const _Float16* __restrict__ A,
                                 const _Float16* __restrict__ Bt,
                                 void* __restrict__ Cout,
                                 int N, int K,
                                 const float* __restrict__ bias,
                                 int relu, int f32out) {
    __shared__ _Float16 As[64][72];
    __shared__ _Float16 Bs[64][72];
    int tid = threadIdx.x;
    int wave = tid >> 6, lane = tid & 63;
    int quad = lane >> 4, r = lane & 15;
    int wm = wave >> 1, wn = wave & 1;
    int row0 = blockIdx.x * 64, col0 = blockIdx.y * 64;

    floatx4 acc[2][2];
    #pragma unroll
    for (int i = 0; i < 2; i++)
        #pragma unroll
        for (int j = 0; j < 2; j++) acc[i][j] = (floatx4){0.f, 0.f, 0.f, 0.f};

    for (int k0 = 0; k0 < K; k0 += 64) {
        #pragma unroll
        for (int u = 0; u < 2; u++) {
            int idx = tid + u * 256;           // 0..511
            int row = idx >> 3;                // 0..63
            int seg = (idx & 7) * 8;           // 0..56
            *(half8v*)&As[row][seg] = *(const half8v*)(A + (size_t)(row0 + row) * K + k0 + seg);
            *(half8v*)&Bs[row][seg] = *(const half8v*)(Bt + (size_t)(col0 + row) * K + k0 + seg);
        }
        __syncthreads();
        #pragma unroll
        for (int ks = 0; ks < 2; ks++) {
            half8v af[2], bf[2];
            #pragma unroll
            for (int mt = 0; mt < 2; mt++)
                af[mt] = *(const half8v*)&As[wm * 32 + mt * 16 + r][ks * 32 + quad * 8];
            #pragma unroll
            for (int nt = 0; nt < 2; nt++)
                bf[nt] = *(const half8v*)&Bs[wn * 32 + nt * 16 + r][ks * 32 + quad * 8];
            #pragma unroll
            for (int mt = 0; mt < 2; mt++)
                #pragma unroll
                for (int nt = 0; nt < 2; nt++)
                    acc[mt][nt] = __builtin_amdgcn_mfma_f32_16x16x32_f16(af[mt], bf[nt],
                                                                         acc[mt][nt], 0, 0, 0);
        }
        __syncthreads();
    }

    #pragma unroll
    for (int mt = 0; mt < 2; mt++) {
        #pragma unroll
        for (int i = 0; i < 4; i++) {
            int grow = row0 + wm * 32 + mt * 16 + quad * 4 + i;
            #pragma unroll
            for (int nt = 0; nt < 2; nt++) {
                int gcol = col0 + wn * 32 + nt * 16 + r;
                float v = acc[mt][nt][i] + bias[gcol];
                if (relu) v = fmaxf(v, 0.f);
                if (f32out) ((float*)Cout)[(size_t)grow * N + gcol] = v;
                else ((_Float16*)Cout)[(size_t)grow * N + gcol] = (_Float16)v;
            }
        }
    }
}

// ---------------------------------------------------------------------------
// Fused conv2-aggregate + mean-pool, P-partitioned (R9): grid (kG*kPP, 2).
// Block (g,p) covers nodes start + (p*4+wave) + 32*k of graph g — 1-2 nodes
// per wave, 64K waves total (restores R7's BW-bound parallelism). Per-block
// fp32 partial -> ppart (private slot, no atomics); preduce sums P slots.
// ---------------------------------------------------------------------------
__global__ void aggpoolp_kernel(const unsigned char* __restrict__ hs, const float* __restrict__ dinv,
                                const int* __restrict__ counts,
                                const unsigned short* __restrict__ col_ell,
                                const float* __restrict__ bias,
                                const int* __restrict__ batch1, const int* __restrict__ batch2,
                                float* __restrict__ ppart) {
    int side = blockIdx.y;
    int g = blockIdx.x / kPP;
    int pI = blockIdx.x - g * kPP;
    const unsigned char* hb = hs + (size_t)side * kN * kGH;
    const float* dv_ = dinv + side * kN;
    const int* deg = counts + side * kN;
    const unsigned short* ci = col_ell + (size_t)side * kN * kMD;
    const int* batch = side ? batch2 : batch1;

    int lo = 0, hi = kN;
    while (lo < hi) { int mid = (lo + hi) >> 1; if (batch[mid] < g) lo = mid + 1; else hi = mid; }
    int start = lo;
    lo = start; hi = kN;
    while (lo < hi) { int mid = (lo + hi) >> 1; if (batch[mid] < g + 1) lo = mid + 1; else hi = mid; }
    int end = lo;

    int wave = threadIdx.x >> 6;
    int lane = threadIdx.x & 63;
    int c = lane * 4;
    float4 bia = *(const float4*)(bias + c);
    float p0 = 0.f, p1 = 0.f, p2 = 0.f, p3 = 0.f;

    for (int v = start + pI * 4 + wave; v < end; v += 4 * kPP) {
        float dv = dv_[v];
        float a0 = 0.f, a1 = 0.f, a2 = 0.f, a3 = 0.f;
        acc_fp8x4(*(const unsigned int*)(hb + (size_t)v * kGH + c), a0, a1, a2, a3); // self
        int cnt = min(deg[v], kMD);
        int idxl = (lane < cnt) ? (int)ci[(size_t)v * kMD + lane] : 0;
        int j = 0;
        for (; j + 16 <= cnt; j += 16) {
            unsigned int w[16];
            #pragma unroll
            for (int u = 0; u < 16; u++)
                w[u] = *(const unsigned int*)(hb + (size_t)__shfl(idxl, j + u) * kGH + c);
            #pragma unroll
            for (int u = 0; u < 16; u++) acc_fp8x4(w[u], a0, a1, a2, a3);
        }
        for (; j + 8 <= cnt; j += 8) {
            unsigned int w[8];
            #pragma unroll
            for (int u = 0; u < 8; u++)
                w[u] = *(const unsigned int*)(hb + (size_t)__shfl(idxl, j + u) * kGH + c);
            #pragma unroll
            for (int u = 0; u < 8; u++) acc_fp8x4(w[u], a0, a1, a2, a3);
        }
        for (; j < cnt; j++)
            acc_fp8x4(*(const unsigned int*)(hb + (size_t)__shfl(idxl, j) * kGH + c),
                      a0, a1, a2, a3);
        float f = dv * HS_INV;
        p0 += fmaxf(f * a0 + bia.x, 0.f);
        p1 += fmaxf(f * a1 + bia.y, 0.f);
        p2 += fmaxf(f * a2 + bia.z, 0.f);
        p3 += fmaxf(f * a3 + bia.w, 0.f);
    }

    __shared__ float psum[4][256];
    *(float4*)&psum[wave][c] = make_float4(p0, p1, p2, p3);
    __syncthreads();
    int t = threadIdx.x;
    float s = psum[0][t] + psum[1][t] + psum[2][t] + psum[3][t];
    ppart[(((size_t)side * kG + g) * kPP + pI) * kGH + t] = s;
}

// preduce: sum the kPP partials, divide by graph size -> pooled16.
__global__ void preduce_kernel(const float* __restrict__ ppart,
                               const int* __restrict__ batch1, const int* __restrict__ batch2,
                               _Float16* __restrict__ pooled16) {
    int side = blockIdx.y;
    int g = blockIdx.x;
    const int* batch = side ? batch2 : batch1;
    int lo = 0, hi = kN;
    while (lo < hi) { int mid = (lo + hi) >> 1; if (batch[mid] < g) lo = mid + 1; else hi = mid; }
    int start = lo;
    lo = start; hi = kN;
    while (lo < hi) { int mid = (lo + hi) >> 1; if (batch[mid] < g + 1) lo = mid + 1; else hi = mid; }
    int end = lo;
    int t = threadIdx.x;
    const float* pb = ppart + (((size_t)side * kG + g) * kPP) * kGH;
    float s = 0.f;
    #pragma unroll
    for (int p = 0; p < kPP; p++) s += pb[p * kGH + t];
    float inv = 1.0f / fmaxf((float)(end - start), 1.0f);
    pooled16[(size_t)(side * kG + g) * kGH + t] = (_Float16)(s * inv);
}

// entity gather: e16[r][k] = fp16(relu(emb[ent[r]][k])), r in [0,2G)
__global__ void egather_kernel(const float* __restrict__ emb,
                               const int* __restrict__ ent1, const int* __restrict__ ent2,
                               _Float16* __restrict__ e16) {
    int rr = blockIdx.x;
    int idx = (rr < kG) ? ent1[rr] : ent2[rr - kG];
    int k = threadIdx.x;   // 128
    e16[(size_t)rr * kEMB + k] = (_Float16)fmaxf(emb[(size_t)idx * kEMB + k], 0.f);
}

// egs prep: egs16[g][k] = fp16(relu(eg1[g][k] + eg2[g][k]))
__global__ void egsprep_kernel(const _Float16* __restrict__ gfc16,
                               const _Float16* __restrict__ ento16,
                               _Float16* __restrict__ egs16) {
    int idx = blockIdx.x * 256 + threadIdx.x;   // 0..65535
    int g = idx >> 6;                            // 0..1023
    int k8 = (idx & 63) * 8;                     // 0..504
    const _Float16* src = (k8 < kGH) ? gfc16 : ento16;
    int kk = (k8 < kGH) ? k8 : k8 - kGH;
    half8v a = *(const half8v*)(src + (size_t)g * kGH + kk);
    half8v b = *(const half8v*)(src + (size_t)(g + kG) * kGH + kk);
    half8v o;
    #pragma unroll
    for (int u = 0; u < 8; u++) o[u] = (_Float16)fmaxf((float)a[u] + (float)b[u], 0.f);
    *(half8v*)(egs16 + (size_t)g * kHID + k8) = o;
}

// ---------------------------------------------------------------------------
// Host launch
// ---------------------------------------------------------------------------
static inline char* carve(char*& p, size_t bytes) {
    char* r = p;
    p += (bytes + 255) & ~(size_t)255;
    return r;
}

extern "C" void kernel_launch(void* const* d_in, const int* in_sizes, int n_in,
                              void* d_out, int out_size, void* d_ws, size_t ws_size,
                              hipStream_t stream) {
    const int*   x1       = (const int*)d_in[0];
    const int*   ei1      = (const int*)d_in[1];
    const int*   ent1     = (const int*)d_in[2];
    const int*   batch1   = (const int*)d_in[3];
    const int*   x2       = (const int*)d_in[4];
    const int*   ei2      = (const int*)d_in[5];
    const int*   ent2     = (const int*)d_in[6];
    const int*   batch2   = (const int*)d_in[7];
    const float* atom_emb = (const float*)d_in[8];
    const float* gW1      = (const float*)d_in[9];
    const float* gb1      = (const float*)d_in[10];
    const float* gW2      = (const float*)d_in[11];
    const float* gb2      = (const float*)d_in[12];
    const float* fcW      = (const float*)d_in[13];
    const float* fcb      = (const float*)d_in[14];
    const float* ent_emb  = (const float*)d_in[15];
    const float* eW1      = (const float*)d_in[16];
    const float* eb1      = (const float*)d_in[17];
    const float* eW2      = (const float*)d_in[18];
    const float* eb2      = (const float*)d_in[19];
    const float* dW1      = (const float*)d_in[20];
    const float* db1      = (const float*)d_in[21];
    const float* dW2      = (const float*)d_in[22];
    const float* db2      = (const float*)d_in[23];
    const float* dW3      = (const float*)d_in[24];
    const float* db3      = (const float*)d_in[25];
    float* out = (float*)d_out;

    // Workspace carve (no zeroed spans needed — binp3 writes all counts).
    char* p = (char*)d_ws;
    _Float16* h2_h   = (_Float16*)carve(p, (size_t)2 * kN * kGH * 2);
    unsigned char* hs8 = (unsigned char*)carve(p, (size_t)2 * kN * kGH); // fp8 hs
    unsigned short* col_ell = (unsigned short*)carve(p, (size_t)2 * kN * kMD * 2);
    unsigned int* ebuf = (unsigned int*)carve(p, (size_t)2 * kE * 4);
    int*   poff    = (int*)  carve(p, (size_t)2 * kNBKT * 256 * 4);
    int*   btot    = (int*)  carve(p, (size_t)2 * kNBKT * 4);
    int*   bbase   = (int*)  carve(p, (size_t)2 * (kNBKT + 1) * 4);
    int*   counts  = (int*)  carve(p, (size_t)2 * kN * 4);
    float* dinv    = (float*)carve(p, (size_t)2 * kN * 4);
    int2*  xd      = (int2*) carve(p, (size_t)2 * kN * 8);
    float* M11     = (float*)carve(p, 11 * kGH * 4);
    _Float16* w2t  = (_Float16*)carve(p, (size_t)kGH * kGH * 2);
    float* ppart   = (float*)carve(p, (size_t)2 * kG * kPP * kGH * 4);
    // fp16 tail buffers
    _Float16* pooled16 = (_Float16*)carve(p, (size_t)2 * kG * kGH * 2);
    _Float16* gfc16    = (_Float16*)carve(p, (size_t)2 * kG * kGH * 2);
    _Float16* e16      = (_Float16*)carve(p, (size_t)2 * kG * kEMB * 2);
    _Float16* etmp16   = (_Float16*)carve(p, (size_t)2 * kG * kEH * 2);
    _Float16* ento16   = (_Float16*)carve(p, (size_t)2 * kG * kEH * 2);
    _Float16* egs16    = (_Float16*)carve(p, (size_t)kG * kHID * 2);
    _Float16* dh1_16   = (_Float16*)carve(p, (size_t)kG * kHID * 2);
    _Float16* dh2_16   = (_Float16*)carve(p, (size_t)kG * kHID * 2);
    // fp16 transposed tail weights
    _Float16* dW1t = (_Float16*)carve(p, (size_t)kHID * kHID * 2);
    _Float16* dW2t = (_Float16*)carve(p, (size_t)kHID * kHID * 2);
    _Float16* dW3t = (_Float16*)carve(p, (size_t)kOUT * kHID * 2);
    _Float16* fcWt = (_Float16*)carve(p, (size_t)kGH * kGH * 2);
    _Float16* eW1t = (_Float16*)carve(p, (size_t)kEH * kEMB * 2);
    _Float16* eW2t = (_Float16*)carve(p, (size_t)kEH * kEH * 2);

    // --- Graph structure via LDS binning (zero global atomics) + conv1 ---
    prep_kernel<<<267, 256, 0, stream>>>(atom_emb, gW1, gW2, M11, w2t);
    wtrans_kernel<<<2944, 256, 0, stream>>>(dW1, dW2, dW3, fcW, eW1, eW2,
                                            dW1t, dW2t, dW3t, fcWt, eW1t, eW2t);
    binp1_kernel<<<dim3(kPBLK, 2), 256, 0, stream>>>(ei1, ei2, poff);
    scanA_kernel<<<dim3(kNBKT, 2), 256, 0, stream>>>(poff, btot);
    scanB_kernel<<<2, 256, 0, stream>>>(btot, bbase);
    binp2_kernel<<<dim3(kPBLK, 2), 256, 0, stream>>>(ei1, ei2, poff, bbase, ebuf);
    binp3_kernel<<<dim3(kNBKT, 2), 256, 0, stream>>>(ebuf, bbase, col_ell, counts,
                                                     dinv, xd, x1, x2);
    conv1_combine_kernel<<<dim3(kN / 16, 2), 256, 0, stream>>>(xd, counts, col_ell,
                                                               M11, gb1, h2_h);

    // --- Conv2 GEMM (MFMA f16): hs8 = fp8(128 * dinv ⊙ (h2 @ W2)) ---
    gemm2_mfma_kernel<<<dim3((kN + 127) / 128, kGH / 128, 2), 256, 0, stream>>>(h2_h, w2t,
                                                                                dinv, hs8);
    // --- Fused aggregate + mean-pool, P-partitioned (h4 never materialized) ---
    aggpoolp_kernel<<<dim3(kG * kPP, 2), 256, 0, stream>>>(hs8, dinv, counts, col_ell,
                                                           gb2, batch1, batch2, ppart);
    preduce_kernel<<<dim3(kG, 2), 256, 0, stream>>>(ppart, batch1, batch2, pooled16);
    // --- Entity gather (fp16) ---
    egather_kernel<<<2 * kG, 128, 0, stream>>>(ent_emb, ent1, ent2, e16);

    // --- Tail GEMMs, all fp16 MFMA (fp32 accum) ---
    gemm_tail_kernel<<<dim3(2 * kG / 64, kGH / 64), 256, 0, stream>>>(
        pooled16, fcWt, gfc16, kGH, kGH, fcb, 0, 0);
    gemm_tail_kernel<<<dim3(2 * kG / 64, kEH / 64), 256, 0, stream>>>(
        e16, eW1t, etmp16, kEH, kEMB, eb1, 1, 0);
    gemm_tail_kernel<<<dim3(2 * kG / 64, kEH / 64), 256, 0, stream>>>(
        etmp16, eW2t, ento16, kEH, kEH, eb2, 1, 0);
    egsprep_kernel<<<kG * kHID / 8 / 256, 256, 0, stream>>>(gfc16, ento16, egs16);
    gemm_tail_kernel<<<dim3(kG / 64, kHID / 64), 256, 0, stream>>>(
        egs16, dW1t, dh1_16, kHID, kHID, db1, 1, 0);
    gemm_tail_kernel<<<dim3(kG / 64, kHID / 64), 256, 0, stream>>>(
        dh1_16, dW2t, dh2_16, kHID, kHID, db2, 1, 0);
    gemm_tail_kernel<<<dim3(kG / 64, kOUT / 64), 256, 0, stream>>>(
        dh2_16, dW3t, out, kOUT, kHID, db3, 0, 1);
}

// Round 10
// 424.660 us; speedup vs baseline: 1.0766x; 1.0766x over previous
//
#include <hip/hip_runtime.h>
#include <hip/hip_fp16.h>

// Problem constants
static constexpr int kN = 50000;      // nodes per side
static constexpr int kE = 800000;     // edges per side
static constexpr int kG = 1024;      // graphs per batch
static constexpr int kEMB = 128;
static constexpr int kGH = 256;
static constexpr int kEH = 256;
static constexpr int kOUT = 128;
static constexpr int kHID = 512;
static constexpr int kNB = (kN + 255) / 256;   // 196 chunks per side
static constexpr int kMD = 64;        // ELL stride; deg ~ Poisson(16), P(deg>=64)~e^-125
static constexpr int kNBKT = 196;     // dst buckets of 256 nodes (50000 -> 196)
static constexpr int kEPB = 3125;     // edges per bin block; 256 blocks exactly
static constexpr int kPBLK = 256;     // bin blocks per side (256*3125 = 800000)
static constexpr int kPP = 8;         // aggpool partitions per graph

typedef __attribute__((ext_vector_type(8))) _Float16 half8v;
typedef __attribute__((ext_vector_type(4))) _Float16 half4v;
typedef __attribute__((ext_vector_type(4))) float floatx4;
typedef __attribute__((ext_vector_type(2))) float floatx2;

// NOTE (R6): cross-XCD plain-data handoff through grid.sync() gave stale reads.
// NOTE (R7/R12): device atomics memory-side; floor is OP-COUNT ~21/ns.
// (R10) lookback scan regressed. (R11) role-merged grids regressed.
// (R2) fp8 hs: 659->616us. (R3) conv1 DPP groups: ->596us. (R4) NEUTRAL.
// (R5) ELL fusion regressed rank (atomics+random stores share mem-op pipe).
// (R6) LDS bucket binning, zero global atomics: 585->523us.
// (R7) fp16-MFMA unified tail: 523->439us, absmax UNCHANGED.
// (R8) agg+pool fusion: 439->429us (aggpool 102us — 1-block/graph starved).
// (R9) P=8 partitions REGRESSED (457us, aggpoolp 113us): every block ran two
// 17-step binary searches over batch = ~34 DEPENDENT L2 hits before any work;
// 8x more blocks made the per-block chain dominate (HBM 21%, occ 64%).
// This revision (R10): gbounds_kernel precomputes gstart[side][g] with one
// PARALLEL search per thread (~2us); aggpoolp/preduce read 2 coalesced words.
// Per-block fixed cost collapses; gather returns to BW-bound.

// fp8 fixed scale: |hs| <~ 0.2 typ; x128 keeps values in e4m3 normal range.
#define HS_SCALE 128.0f
#define HS_INV   (1.0f / 128.0f)

__device__ inline void acc_fp8x4(unsigned int w, float& a0, float& a1, float& a2, float& a3) {
    floatx2 lo = __builtin_amdgcn_cvt_pk_f32_fp8(w, false);
    floatx2 hi = __builtin_amdgcn_cvt_pk_f32_fp8(w, true);
    a0 += lo[0]; a1 += lo[1]; a2 += hi[0]; a3 += hi[1];
}

// 16-lane group sum via DPP row_ror rotations (1,2,4,8).
__device__ inline float grp16_reduce(float v) {
    int x;
    x = __builtin_amdgcn_update_dpp(0, __float_as_int(v), 0x121, 0xF, 0xF, true);
    v += __int_as_float(x);
    x = __builtin_amdgcn_update_dpp(0, __float_as_int(v), 0x122, 0xF, 0xF, true);
    v += __int_as_float(x);
    x = __builtin_amdgcn_update_dpp(0, __float_as_int(v), 0x124, 0xF, 0xF, true);
    v += __int_as_float(x);
    x = __builtin_amdgcn_update_dpp(0, __float_as_int(v), 0x128, 0xF, 0xF, true);
    v += __int_as_float(x);
    return v;
}

// ---------------------------------------------------------------------------
// prep: w2t = fp16(gW2^T) (blocks 0..255), M11 = atom_emb@gW1 (blocks 256..266)
// ---------------------------------------------------------------------------
__global__ void prep_kernel(const float* __restrict__ atom_emb, const float* __restrict__ gW1,
                            const float* __restrict__ gW2,
                            float* __restrict__ M11, _Float16* __restrict__ w2t) {
    int i = blockIdx.x * 256 + threadIdx.x;
    if (blockIdx.x < 256) {
        int k = i >> 8, n = i & 255;
        w2t[(size_t)n * kGH + k] = (_Float16)gW2[(size_t)k * kGH + n];
    } else {
        int j = i - 65536;
        if (j < 11 * kGH) {
            int r = j >> 8, c = j & 255;
            float s = 0.f;
            for (int k = 0; k < kEMB; k++) s += atom_emb[r * kEMB + k] * gW1[k * kGH + c];
            M11[j] = s;
        }
    }
}

// ---------------------------------------------------------------------------
// wtrans: all tail weights -> fp16 transposed ([N][K] from [K][N]).
// ---------------------------------------------------------------------------
__global__ void wtrans_kernel(const float* __restrict__ dW1, const float* __restrict__ dW2,
                              const float* __restrict__ dW3, const float* __restrict__ fcW,
                              const float* __restrict__ eW1, const float* __restrict__ eW2,
                              _Float16* __restrict__ dW1t, _Float16* __restrict__ dW2t,
                              _Float16* __restrict__ dW3t, _Float16* __restrict__ fcWt,
                              _Float16* __restrict__ eW1t, _Float16* __restrict__ eW2t) {
    int b = blockIdx.x;
    const float* src; _Float16* dst; int K, N, j0;
    if (b < 1024)      { src = dW1; dst = dW1t; K = 512; N = 512; j0 = b * 256; }
    else if (b < 2048) { src = dW2; dst = dW2t; K = 512; N = 512; j0 = (b - 1024) * 256; }
    else if (b < 2304) { src = dW3; dst = dW3t; K = 512; N = 128; j0 = (b - 2048) * 256; }
    else if (b < 2560) { src = fcW; dst = fcWt; K = 256; N = 256; j0 = (b - 2304) * 256; }
    else if (b < 2688) { src = eW1; dst = eW1t; K = 128; N = 256; j0 = (b - 2560) * 256; }
    else               { src = eW2; dst = eW2t; K = 256; N = 256; j0 = (b - 2688) * 256; }
    int j = j0 + threadIdx.x;            // dst linear: n*K + k
    int n = j / K, k = j - n * K;
    dst[j] = (_Float16)src[(size_t)k * N + n];
}

// ---------------------------------------------------------------------------
// gbounds: gstart[side][g] = lower_bound(batch, g), one PARALLEL search per
// thread (kills R9's per-block serial search chains).
// ---------------------------------------------------------------------------
__global__ void gbounds_kernel(const int* __restrict__ batch1, const int* __restrict__ batch2,
                               int* __restrict__ gstart) {
    int side = blockIdx.y;
    const int* batch = side ? batch2 : batch1;
    int g = blockIdx.x * 256 + threadIdx.x;
    if (g > kG) return;
    int lo = 0, hi = kN;
    while (lo < hi) { int mid = (lo + hi) >> 1; if (batch[mid] < g) lo = mid + 1; else hi = mid; }
    gstart[side * (kG + 1) + g] = lo;
}

// ---------------------------------------------------------------------------
// binp1: per-block LDS histogram over 196 dst-buckets.
// ---------------------------------------------------------------------------
__global__ void binp1_kernel(const int* __restrict__ ei1, const int* __restrict__ ei2,
                             int* __restrict__ poff) {
    int side = blockIdx.y;
    const int* dst = (side ? ei2 : ei1) + kE;
    __shared__ int hist[kNBKT];
    int t = threadIdx.x;
    if (t < kNBKT) hist[t] = 0;
    __syncthreads();
    int base = blockIdx.x * kEPB;
    for (int j = t; j < kEPB; j += 256)
        atomicAdd(&hist[dst[base + j] >> 8], 1);
    __syncthreads();
    if (t < kNBKT) poff[((side * kNBKT + t) << 8) | blockIdx.x] = hist[t];
}

// scanA: per (side,bucket) exclusive scan over the 256 block counts.
__global__ void scanA_kernel(int* __restrict__ poff, int* __restrict__ btot) {
    int b = blockIdx.x, side = blockIdx.y, t = threadIdx.x;
    __shared__ int s[256];
    int idx = ((side * kNBKT + b) << 8) | t;
    int v = poff[idx];
    s[t] = v;
    __syncthreads();
    for (int o = 1; o < 256; o <<= 1) {
        int u = (t >= o) ? s[t - o] : 0;
        __syncthreads();
        s[t] += u;
        __syncthreads();
    }
    poff[idx] = s[t] - v;
    if (t == 255) btot[side * kNBKT + b] = s[255];
}

// scanB: exclusive scan of bucket totals -> bbase.
__global__ void scanB_kernel(const int* __restrict__ btot, int* __restrict__ bbase) {
    int side = blockIdx.x, t = threadIdx.x;
    __shared__ int s[256];
    int v = (t < kNBKT) ? btot[side * kNBKT + t] : 0;
    s[t] = v;
    __syncthreads();
    for (int o = 1; o < 256; o <<= 1) {
        int u = (t >= o) ? s[t - o] : 0;
        __syncthreads();
        s[t] += u;
        __syncthreads();
    }
    if (t < kNBKT) bbase[side * (kNBKT + 1) + t] = s[t] - v;
    if (t == 255) bbase[side * (kNBKT + 1) + kNBKT] = s[255];
}

// ---------------------------------------------------------------------------
// binp2: block-local LDS bucket-sort, coalesced bucket-major write-out.
// ---------------------------------------------------------------------------
__launch_bounds__(256)
__global__ void binp2_kernel(const int* __restrict__ ei1, const int* __restrict__ ei2,
                             const int* __restrict__ poff, const int* __restrict__ bbase,
                             unsigned int* __restrict__ ebuf) {
    int side = blockIdx.y, blk = blockIdx.x, t = threadIdx.x;
    const int* ei = side ? ei2 : ei1;
    __shared__ int hist[kNBKT], lb[kNBKT], gb[kNBKT], scanbuf[256];
    __shared__ unsigned int sorted[kEPB];
    if (t < kNBKT) hist[t] = 0;
    __syncthreads();
    int base = blk * kEPB;
    for (int j = t; j < kEPB; j += 256)
        atomicAdd(&hist[ei[kE + base + j] >> 8], 1);
    __syncthreads();
    int v = (t < kNBKT) ? hist[t] : 0;
    scanbuf[t] = v;
    __syncthreads();
    for (int o = 1; o < 256; o <<= 1) {
        int u = (t >= o) ? scanbuf[t - o] : 0;
        __syncthreads();
        scanbuf[t] += u;
        __syncthreads();
    }
    if (t < kNBKT) {
        lb[t] = scanbuf[t] - v;
        gb[t] = bbase[side * (kNBKT + 1) + t] + poff[((side * kNBKT + t) << 8) | blk];
        hist[t] = 0;
    }
    __syncthreads();
    for (int j = t; j < kEPB; j += 256) {
        int s_ = ei[base + j];
        int d  = ei[kE + base + j];
        int b  = d >> 8;
        int r  = atomicAdd(&hist[b], 1);
        sorted[lb[b] + r] = ((unsigned int)d << 16) | (unsigned int)s_;
    }
    __syncthreads();
    for (int j = t; j < kEPB; j += 256) {
        unsigned int val = sorted[j];
        int b = val >> 24;
        int gpos = gb[b] + (j - lb[b]);
        ebuf[(size_t)side * kE + gpos] = val;
    }
}

// ---------------------------------------------------------------------------
// binp3: one block per bucket; LDS slot counters; col_ell stores in a 32KB
// window. Fused epilogue: degrees->counts, dinv, xd.
// ---------------------------------------------------------------------------
__global__ void binp3_kernel(const unsigned int* __restrict__ ebuf, const int* __restrict__ bbase,
                             unsigned short* __restrict__ col_ell, int* __restrict__ counts,
                             float* __restrict__ dinv, int2* __restrict__ xd,
                             const int* __restrict__ x1, const int* __restrict__ x2) {
    int b = blockIdx.x, side = blockIdx.y, t = threadIdx.x;
    __shared__ int cnt[256];
    cnt[t] = 0;
    __syncthreads();
    int start = bbase[side * (kNBKT + 1) + b];
    int end   = bbase[side * (kNBKT + 1) + b + 1];
    for (int k = start + t; k < end; k += 256) {
        unsigned int v = ebuf[(size_t)side * kE + k];
        int d8 = (v >> 16) & 255;
        int slot = atomicAdd(&cnt[d8], 1);
        if (slot > kMD - 1) slot = kMD - 1;
        int node = (b << 8) | d8;
        col_ell[((size_t)side * kN + node) * kMD + slot] = (unsigned short)(v & 0xFFFFu);
    }
    __syncthreads();
    int node = (b << 8) | t;
    if (node < kN) {
        int d = cnt[t];
        counts[side * kN + node] = d;
        float dv = rsqrtf((float)(d + 1));           // +1 self-loop
        dinv[side * kN + node] = dv;
        const int* x = side ? x2 : x1;
        xd[side * kN + node] = make_int2(x[node], __float_as_int(dv));
    }
}

// ---------------------------------------------------------------------------
// Conv1 combine, 16-lane groups (4 nodes/wave), DPP reduce, zero LDS ops.
// ---------------------------------------------------------------------------
__global__ void conv1_combine_kernel(const int2* __restrict__ xd,
                                     const int* __restrict__ counts,
                                     const unsigned short* __restrict__ col_ell,
                                     const float* __restrict__ M11,
                                     const float* __restrict__ bias,
                                     _Float16* __restrict__ out) {
    int side = blockIdx.y;
    const int2* xdb = xd + (size_t)side * kN;
    const int* deg = counts + side * kN;
    const unsigned short* ci = col_ell + (size_t)side * kN * kMD;
    _Float16* ob = out + (size_t)side * kN * kGH;

    int tid = threadIdx.x;
    int sub = tid & 15;
    int v = blockIdx.x * 16 + (tid >> 4);

    int cnt = min(deg[v], kMD);
    const unsigned short* cv = ci + (size_t)v * kMD;
    float wt[11];
    #pragma unroll
    for (int t = 0; t < 11; t++) wt[t] = 0.f;
    for (int base = 0; base < cnt; base += 16) {
        int e = base + sub;
        int xs = 15; float ds = 0.f;
        if (e < cnt) {
            int2 t = xdb[(int)cv[e]];
            xs = t.x; ds = __int_as_float(t.y);
        }
        #pragma unroll
        for (int t = 0; t < 11; t++) wt[t] += (xs == t) ? ds : 0.f;
    }
    #pragma unroll
    for (int t = 0; t < 11; t++) wt[t] = grp16_reduce(wt[t]);

    int2 xv = xdb[v];
    float dv = __int_as_float(xv.y);
    #pragma unroll
    for (int q = 0; q < 4; q++) {
        int c = q * 64 + sub * 4;
        float4 bia = *(const float4*)(bias + c);
        float4 m = *(const float4*)(M11 + xv.x * kGH + c);
        float4 acc = make_float4(dv * m.x, dv * m.y, dv * m.z, dv * m.w);
        #pragma unroll
        for (int t = 0; t < 11; t++) {
            float w = wt[t];
            float4 mt = *(const float4*)(M11 + t * kGH + c);
            acc.x += w * mt.x; acc.y += w * mt.y;
            acc.z += w * mt.z; acc.w += w * mt.w;
        }
        half4v o;
        o[0] = (_Float16)fmaxf(dv * acc.x + bia.x, 0.f);
        o[1] = (_Float16)fmaxf(dv * acc.y + bia.y, 0.f);
        o[2] = (_Float16)fmaxf(dv * acc.z + bia.z, 0.f);
        o[3] = (_Float16)fmaxf(dv * acc.w + bia.w, 0.f);
        *(half4v*)(ob + (size_t)v * kGH + c) = o;
    }
}

// ---------------------------------------------------------------------------
// Conv2 GEMM via MFMA f16, LDS-tiled: hs = fp8(HS_SCALE * dinv ⊙ (h2 @ W2))
// BM=128, BN=128, BK=64. 4 waves (2x2); wave = 64x64.
// ---------------------------------------------------------------------------
__launch_bounds__(256)
__global__ void gemm2_mfma_kernel(const _Float16* __restrict__ A,
                                  const _Float16* __restrict__ Bt,
                                  const float* __restrict__ dinv,
                                  unsigned char* __restrict__ C) {
    __shared__ _Float16 As[128][72];
    __shared__ _Float16 Bs[128][72];

    int side = blockIdx.z;
    const _Float16* Ab = A + (size_t)side * kN * kGH;
    const float* db = dinv + (size_t)side * kN;
    unsigned char* Cb = C + (size_t)side * kN * kGH;

    int tid = threadIdx.x;
    int wave = tid >> 6, lane = tid & 63;
    int quad = lane >> 4, r = lane & 15;
    int wm = wave >> 1, wn = wave & 1;
    int row0 = blockIdx.x * 128;
    int col0 = blockIdx.y * 128;

    floatx4 acc[4][4];
    #pragma unroll
    for (int i = 0; i < 4; i++)
        #pragma unroll
        for (int j = 0; j < 4; j++) acc[i][j] = (floatx4){0.f, 0.f, 0.f, 0.f};

    for (int k0 = 0; k0 < kGH; k0 += 64) {
        #pragma unroll
        for (int u = 0; u < 4; u++) {
            int idx = tid + u * 256;
            int row = idx >> 3;
            int seg = (idx & 7) * 8;
            int gr = row0 + row;
            if (gr >= kN) gr = kN - 1;
            *(half8v*)&As[row][seg] = *(const half8v*)(Ab + (size_t)gr * kGH + k0 + seg);
            *(half8v*)&Bs[row][seg] = *(const half8v*)(Bt + (size_t)(col0 + row) * kGH + k0 + seg);
        }
        __syncthreads();
        #pragma unroll
        for (int ks = 0; ks < 2; ks++) {
            half8v af[4], bf[4];
            #pragma unroll
            for (int mt = 0; mt < 4; mt++)
                af[mt] = *(const half8v*)&As[wm * 64 + mt * 16 + r][ks * 32 + quad * 8];
            #pragma unroll
            for (int nt = 0; nt < 4; nt++)
                bf[nt] = *(const half8v*)&Bs[wn * 64 + nt * 16 + r][ks * 32 + quad * 8];
            #pragma unroll
            for (int mt = 0; mt < 4; mt++)
                #pragma unroll
                for (int nt = 0; nt < 4; nt++)
                    acc[mt][nt] = __builtin_amdgcn_mfma_f32_16x16x32_f16(af[mt], bf[nt],
                                                                         acc[mt][nt], 0, 0, 0);
        }
        __syncthreads();
    }

    #pragma unroll
    for (int mt = 0; mt < 4; mt++) {
        #pragma unroll
        for (int i = 0; i < 4; i++) {
            int grow = row0 + wm * 64 + mt * 16 + quad * 4 + i;
            if (grow >= kN) continue;
            float rsq = db[grow] * HS_SCALE;
            #pragma unroll
            for (int nt = 0; nt < 4; nt++) {
                int gcol = col0 + wn * 64 + nt * 16 + r;
                float q = acc[mt][nt][i] * rsq;
                Cb[(size_t)grow * kGH + gcol] =
                    (unsigned char)__builtin_amdgcn_cvt_pk_fp8_f32(q, q, 0, false);
            }
        }
    }
}

// ---------------------------------------------------------------------------
// Unified tail GEMM via MFMA f16 (fp32 accum): C = [relu](A @ B + bias)
// ---------------------------------------------------------------------------
__launch_bounds__(256)
__global__ void gemm_tail_kernel(const _Float16* __restrict__ A,
                                 const _Float16* __restrict__ Bt,
                                 void* __restrict__ Cout,
                                 int N, int K,
                                 const float* __restrict__ bias,
                                 int relu, int f32out) {
    __shared__ _Float16 As[64][72];
    __shared__ _Float16 Bs[64][72];
    int tid = threadIdx.x;
    int wave = tid >> 6, lane = tid & 63;
    int quad = lane >> 4, r = lane & 15;
    int wm = wave >> 1, wn = wave & 1;
    int row0 = blockIdx.x * 64, col0 = blockIdx.y * 64;

    floatx4 acc[2][2];
    #pragma unroll
    for (int i = 0; i < 2; i++)
        #pragma unroll
        for (int j = 0; j < 2; j++) acc[i][j] = (floatx4){0.f, 0.f, 0.f, 0.f};

    for (int k0 = 0; k0 < K; k0 += 64) {
        #pragma unroll
        for (int u = 0; u < 2; u++) {
            int idx = tid + u * 256;           // 0..511
            int row = idx >> 3;                // 0..63
            int seg = (idx & 7) * 8;           // 0..56
            *(half8v*)&As[row][seg] = *(const half8v*)(A + (size_t)(row0 + row) * K + k0 + seg);
            *(half8v*)&Bs[row][seg] = *(const half8v*)(Bt + (size_t)(col0 + row) * K + k0 + seg);
        }
        __syncthreads();
        #pragma unroll
        for (int ks = 0; ks < 2; ks++) {
            half8v af[2], bf[2];
            #pragma unroll
            for (int mt = 0; mt < 2; mt++)
                af[mt] = *(const half8v*)&As[wm * 32 + mt * 16 + r][ks * 32 + quad * 8];
            #pragma unroll
            for (int nt = 0; nt < 2; nt++)
                bf[nt] = *(const half8v*)&Bs[wn * 32 + nt * 16 + r][ks * 32 + quad * 8];
            #pragma unroll
            for (int mt = 0; mt < 2; mt++)
                #pragma unroll
                for (int nt = 0; nt < 2; nt++)
                    acc[mt][nt] = __builtin_amdgcn_mfma_f32_16x16x32_f16(af[mt], bf[nt],
                                                                         acc[mt][nt], 0, 0, 0);
        }
        __syncthreads();
    }

    #pragma unroll
    for (int mt = 0; mt < 2; mt++) {
        #pragma unroll
        for (int i = 0; i < 4; i++) {
            int grow = row0 + wm * 32 + mt * 16 + quad * 4 + i;
            #pragma unroll
            for (int nt = 0; nt < 2; nt++) {
                int gcol = col0 + wn * 32 + nt * 16 + r;
                float v = acc[mt][nt][i] + bias[gcol];
                if (relu) v = fmaxf(v, 0.f);
                if (f32out) ((float*)Cout)[(size_t)grow * N + gcol] = v;
                else ((_Float16*)Cout)[(size_t)grow * N + gcol] = (_Float16)v;
            }
        }
    }
}

// ---------------------------------------------------------------------------
// Fused conv2-aggregate + mean-pool, P-partitioned, bounds PRECOMPUTED (R10).
// Grid (kG*kPP, 2); block (g,p) covers nodes gstart[g] + (p*4+wave) + 32*k.
// Per-block fp32 partial -> ppart (private slot, no atomics).
// ---------------------------------------------------------------------------
__global__ void aggpoolp_kernel(const unsigned char* __restrict__ hs, const float* __restrict__ dinv,
                                const int* __restrict__ counts,
                                const unsigned short* __restrict__ col_ell,
                                const float* __restrict__ bias,
                                const int* __restrict__ gstart,
                                float* __restrict__ ppart) {
    int side = blockIdx.y;
    int g = blockIdx.x / kPP;
    int pI = blockIdx.x - g * kPP;
    const unsigned char* hb = hs + (size_t)side * kN * kGH;
    const float* dv_ = dinv + side * kN;
    const int* deg = counts + side * kN;
    const unsigned short* ci = col_ell + (size_t)side * kN * kMD;

    int start = gstart[side * (kG + 1) + g];
    int end   = gstart[side * (kG + 1) + g + 1];

    int wave = threadIdx.x >> 6;
    int lane = threadIdx.x & 63;
    int c = lane * 4;
    float4 bia = *(const float4*)(bias + c);
    float p0 = 0.f, p1 = 0.f, p2 = 0.f, p3 = 0.f;

    for (int v = start + pI * 4 + wave; v < end; v += 4 * kPP) {
        float dv = dv_[v];
        float a0 = 0.f, a1 = 0.f, a2 = 0.f, a3 = 0.f;
        acc_fp8x4(*(const unsigned int*)(hb + (size_t)v * kGH + c), a0, a1, a2, a3); // self
        int cnt = min(deg[v], kMD);
        int idxl = (lane < cnt) ? (int)ci[(size_t)v * kMD + lane] : 0;
        int j = 0;
        for (; j + 16 <= cnt; j += 16) {
            unsigned int w[16];
            #pragma unroll
            for (int u = 0; u < 16; u++)
                w[u] = *(const unsigned int*)(hb + (size_t)__shfl(idxl, j + u) * kGH + c);
            #pragma unroll
            for (int u = 0; u < 16; u++) acc_fp8x4(w[u], a0, a1, a2, a3);
        }
        for (; j + 8 <= cnt; j += 8) {
            unsigned int w[8];
            #pragma unroll
            for (int u = 0; u < 8; u++)
                w[u] = *(const unsigned int*)(hb + (size_t)__shfl(idxl, j + u) * kGH + c);
            #pragma unroll
            for (int u = 0; u < 8; u++) acc_fp8x4(w[u], a0, a1, a2, a3);
        }
        for (; j < cnt; j++)
            acc_fp8x4(*(const unsigned int*)(hb + (size_t)__shfl(idxl, j) * kGH + c),
                      a0, a1, a2, a3);
        float f = dv * HS_INV;
        p0 += fmaxf(f * a0 + bia.x, 0.f);
        p1 += fmaxf(f * a1 + bia.y, 0.f);
        p2 += fmaxf(f * a2 + bia.z, 0.f);
        p3 += fmaxf(f * a3 + bia.w, 0.f);
    }

    __shared__ float psum[4][256];
    *(float4*)&psum[wave][c] = make_float4(p0, p1, p2, p3);
    __syncthreads();
    int t = threadIdx.x;
    float s = psum[0][t] + psum[1][t] + psum[2][t] + psum[3][t];
    ppart[(((size_t)side * kG + g) * kPP + pI) * kGH + t] = s;
}

// preduce: sum the kPP partials, divide by graph size -> pooled16.
__global__ void preduce_kernel(const float* __restrict__ ppart,
                               const int* __restrict__ gstart,
                               _Float16* __restrict__ pooled16) {
    int side = blockIdx.y;
    int g = blockIdx.x;
    int start = gstart[side * (kG + 1) + g];
    int end   = gstart[side * (kG + 1) + g + 1];
    int t = threadIdx.x;
    const float* pb = ppart + (((size_t)side * kG + g) * kPP) * kGH;
    float s = 0.f;
    #pragma unroll
    for (int p = 0; p < kPP; p++) s += pb[p * kGH + t];
    float inv = 1.0f / fmaxf((float)(end - start), 1.0f);
    pooled16[(size_t)(side * kG + g) * kGH + t] = (_Float16)(s * inv);
}

// entity gather: e16[r][k] = fp16(relu(emb[ent[r]][k])), r in [0,2G)
__global__ void egather_kernel(const float* __restrict__ emb,
                               const int* __restrict__ ent1, const int* __restrict__ ent2,
                               _Float16* __restrict__ e16) {
    int rr = blockIdx.x;
    int idx = (rr < kG) ? ent1[rr] : ent2[rr - kG];
    int k = threadIdx.x;   // 128
    e16[(size_t)rr * kEMB + k] = (_Float16)fmaxf(emb[(size_t)idx * kEMB + k], 0.f);
}

// egs prep: egs16[g][k] = fp16(relu(eg1[g][k] + eg2[g][k]))
__global__ void egsprep_kernel(const _Float16* __restrict__ gfc16,
                               const _Float16* __restrict__ ento16,
                               _Float16* __restrict__ egs16) {
    int idx = blockIdx.x * 256 + threadIdx.x;   // 0..65535
    int g = idx >> 6;                            // 0..1023
    int k8 = (idx & 63) * 8;                     // 0..504
    const _Float16* src = (k8 < kGH) ? gfc16 : ento16;
    int kk = (k8 < kGH) ? k8 : k8 - kGH;
    half8v a = *(const half8v*)(src + (size_t)g * kGH + kk);
    half8v b = *(const half8v*)(src + (size_t)(g + kG) * kGH + kk);
    half8v o;
    #pragma unroll
    for (int u = 0; u < 8; u++) o[u] = (_Float16)fmaxf((float)a[u] + (float)b[u], 0.f);
    *(half8v*)(egs16 + (size_t)g * kHID + k8) = o;
}

// ---------------------------------------------------------------------------
// Host launch
// ---------------------------------------------------------------------------
static inline char* carve(char*& p, size_t bytes) {
    char* r = p;
    p += (bytes + 255) & ~(size_t)255;
    return r;
}

extern "C" void kernel_launch(void* const* d_in, const int* in_sizes, int n_in,
                              void* d_out, int out_size, void* d_ws, size_t ws_size,
                              hipStream_t stream) {
    const int*   x1       = (const int*)d_in[0];
    const int*   ei1      = (const int*)d_in[1];
    const int*   ent1     = (const int*)d_in[2];
    const int*   batch1   = (const int*)d_in[3];
    const int*   x2       = (const int*)d_in[4];
    const int*   ei2      = (const int*)d_in[5];
    const int*   ent2     = (const int*)d_in[6];
    const int*   batch2   = (const int*)d_in[7];
    const float* atom_emb = (const float*)d_in[8];
    const float* gW1      = (const float*)d_in[9];
    const float* gb1      = (const float*)d_in[10];
    const float* gW2      = (const float*)d_in[11];
    const float* gb2      = (const float*)d_in[12];
    const float* fcW      = (const float*)d_in[13];
    const float* fcb      = (const float*)d_in[14];
    const float* ent_emb  = (const float*)d_in[15];
    const float* eW1      = (const float*)d_in[16];
    const float* eb1      = (const float*)d_in[17];
    const float* eW2      = (const float*)d_in[18];
    const float* eb2      = (const float*)d_in[19];
    const float* dW1      = (const float*)d_in[20];
    const float* db1      = (const float*)d_in[21];
    const float* dW2      = (const float*)d_in[22];
    const float* db2      = (const float*)d_in[23];
    const float* dW3      = (const float*)d_in[24];
    const float* db3      = (const float*)d_in[25];
    float* out = (float*)d_out;

    // Workspace carve (no zeroed spans needed — binp3 writes all counts).
    char* p = (char*)d_ws;
    _Float16* h2_h   = (_Float16*)carve(p, (size_t)2 * kN * kGH * 2);
    unsigned char* hs8 = (unsigned char*)carve(p, (size_t)2 * kN * kGH); // fp8 hs
    unsigned short* col_ell = (unsigned short*)carve(p, (size_t)2 * kN * kMD * 2);
    unsigned int* ebuf = (unsigned int*)carve(p, (size_t)2 * kE * 4);
    int*   poff    = (int*)  carve(p, (size_t)2 * kNBKT * 256 * 4);
    int*   btot    = (int*)  carve(p, (size_t)2 * kNBKT * 4);
    int*   bbase   = (int*)  carve(p, (size_t)2 * (kNBKT + 1) * 4);
    int*   counts  = (int*)  carve(p, (size_t)2 * kN * 4);
    float* dinv    = (float*)carve(p, (size_t)2 * kN * 4);
    int2*  xd      = (int2*) carve(p, (size_t)2 * kN * 8);
    int*   gstart  = (int*)  carve(p, (size_t)2 * (kG + 1) * 4);
    float* M11     = (float*)carve(p, 11 * kGH * 4);
    _Float16* w2t  = (_Float16*)carve(p, (size_t)kGH * kGH * 2);
    float* ppart   = (float*)carve(p, (size_t)2 * kG * kPP * kGH * 4);
    // fp16 tail buffers
    _Float16* pooled16 = (_Float16*)carve(p, (size_t)2 * kG * kGH * 2);
    _Float16* gfc16    = (_Float16*)carve(p, (size_t)2 * kG * kGH * 2);
    _Float16* e16      = (_Float16*)carve(p, (size_t)2 * kG * kEMB * 2);
    _Float16* etmp16   = (_Float16*)carve(p, (size_t)2 * kG * kEH * 2);
    _Float16* ento16   = (_Float16*)carve(p, (size_t)2 * kG * kEH * 2);
    _Float16* egs16    = (_Float16*)carve(p, (size_t)kG * kHID * 2);
    _Float16* dh1_16   = (_Float16*)carve(p, (size_t)kG * kHID * 2);
    _Float16* dh2_16   = (_Float16*)carve(p, (size_t)kG * kHID * 2);
    // fp16 transposed tail weights
    _Float16* dW1t = (_Float16*)carve(p, (size_t)kHID * kHID * 2);
    _Float16* dW2t = (_Float16*)carve(p, (size_t)kHID * kHID * 2);
    _Float16* dW3t = (_Float16*)carve(p, (size_t)kOUT * kHID * 2);
    _Float16* fcWt = (_Float16*)carve(p, (size_t)kGH * kGH * 2);
    _Float16* eW1t = (_Float16*)carve(p, (size_t)kEH * kEMB * 2);
    _Float16* eW2t = (_Float16*)carve(p, (size_t)kEH * kEH * 2);

    // --- Graph structure via LDS binning (zero global atomics) + conv1 ---
    prep_kernel<<<267, 256, 0, stream>>>(atom_emb, gW1, gW2, M11, w2t);
    wtrans_kernel<<<2944, 256, 0, stream>>>(dW1, dW2, dW3, fcW, eW1, eW2,
                                            dW1t, dW2t, dW3t, fcWt, eW1t, eW2t);
    gbounds_kernel<<<dim3((kG + 256) / 256, 2), 256, 0, stream>>>(batch1, batch2, gstart);
    binp1_kernel<<<dim3(kPBLK, 2), 256, 0, stream>>>(ei1, ei2, poff);
    scanA_kernel<<<dim3(kNBKT, 2), 256, 0, stream>>>(poff, btot);
    scanB_kernel<<<2, 256, 0, stream>>>(btot, bbase);
    binp2_kernel<<<dim3(kPBLK, 2), 256, 0, stream>>>(ei1, ei2, poff, bbase, ebuf);
    binp3_kernel<<<dim3(kNBKT, 2), 256, 0, stream>>>(ebuf, bbase, col_ell, counts,
                                                     dinv, xd, x1, x2);
    conv1_combine_kernel<<<dim3(kN / 16, 2), 256, 0, stream>>>(xd, counts, col_ell,
                                                               M11, gb1, h2_h);

    // --- Conv2 GEMM (MFMA f16): hs8 = fp8(128 * dinv ⊙ (h2 @ W2)) ---
    gemm2_mfma_kernel<<<dim3((kN + 127) / 128, kGH / 128, 2), 256, 0, stream>>>(h2_h, w2t,
                                                                                dinv, hs8);
    // --- Fused aggregate + mean-pool, P-partitioned, precomputed bounds ---
    aggpoolp_kernel<<<dim3(kG * kPP, 2), 256, 0, stream>>>(hs8, dinv, counts, col_ell,
                                                           gb2, gstart, ppart);
    preduce_kernel<<<dim3(kG, 2), 256, 0, stream>>>(ppart, gstart, pooled16);
    // --- Entity gather (fp16) ---
    egather_kernel<<<2 * kG, 128, 0, stream>>>(ent_emb, ent1, ent2, e16);

    // --- Tail GEMMs, all fp16 MFMA (fp32 accum) ---
    gemm_tail_kernel<<<dim3(2 * kG / 64, kGH / 64), 256, 0, stream>>>(
        pooled16, fcWt, gfc16, kGH, kGH, fcb, 0, 0);
    gemm_tail_kernel<<<dim3(2 * kG / 64, kEH / 64), 256, 0, stream>>>(
        e16, eW1t, etmp16, kEH, kEMB, eb1, 1, 0);
    gemm_tail_kernel<<<dim3(2 * kG / 64, kEH / 64), 256, 0, stream>>>(
        etmp16, eW2t, ento16, kEH, kEH, eb2, 1, 0);
    egsprep_kernel<<<kG * kHID / 8 / 256, 256, 0, stream>>>(gfc16, ento16, egs16);
    gemm_tail_kernel<<<dim3(kG / 64, kHID / 64), 256, 0, stream>>>(
        egs16, dW1t, dh1_16, kHID, kHID, db1, 1, 0);
    gemm_tail_kernel<<<dim3(kG / 64, kHID / 64), 256, 0, stream>>>(
        dh1_16, dW2t, dh2_16, kHID, kHID, db2, 1, 0);
    gemm_tail_kernel<<<dim3(kG / 64, kOUT / 64), 256, 0, stream>>>(
        dh2_16, dW3t, out, kOUT, kHID, db3, 0, 1);
}

// Round 11
// 422.571 us; speedup vs baseline: 1.0819x; 1.0049x over previous
//
#include <hip/hip_runtime.h>
#include <hip/hip_fp16.h>

// Problem constants
static constexpr int kN = 50000;      // nodes per side
static constexpr int kE = 800000;     // edges per side
static constexpr int kG = 1024;       // graphs per batch
static constexpr int kEMB = 128;
static constexpr int kGH = 256;
static constexpr int kEH = 256;
static constexpr int kOUT = 128;
static constexpr int kHID = 512;
static constexpr int kNB = (kN + 255) / 256;   // 196 chunks per side
static constexpr int kMD = 64;        // ELL stride; deg ~ Poisson(16), P(deg>=64)~e^-125
static constexpr int kNBKT = 196;     // dst buckets of 256 nodes (50000 -> 196)
static constexpr int kEPB = 3125;     // edges per bin block; 256 blocks exactly
static constexpr int kPBLK = 256;     // bin blocks per side (256*3125 = 800000)
static constexpr int kPP = 8;         // aggpool wave-slots per graph

typedef __attribute__((ext_vector_type(8))) _Float16 half8v;
typedef __attribute__((ext_vector_type(4))) _Float16 half4v;
typedef __attribute__((ext_vector_type(4))) float floatx4;
typedef __attribute__((ext_vector_type(2))) float floatx2;

// NOTE (R6): cross-XCD plain-data handoff through grid.sync() gave stale reads.
// NOTE (R7/R12): device atomics memory-side; floor is OP-COUNT ~21/ns.
// (R10) lookback scan regressed. (R11) role-merged grids regressed.
// (R2) fp8 hs: 659->616us. (R3) conv1 DPP groups: ->596us. (R4) NEUTRAL.
// (R5) ELL fusion regressed rank (atomics+random stores share mem-op pipe).
// (R6) LDS bucket binning, zero global atomics: 585->523us.
// (R7) fp16-MFMA unified tail: 523->439us, absmax UNCHANGED.
// (R8) agg+pool fusion: aggpool 102us (1 block/graph starved parallelism).
// (R9) P=8 block-partitions REGRESSED (113us): per-block serial binary-search
// chains. (R10) gbounds precompute: aggpoolp 82us, total 424.7 — but still
// HBM 28% vs R7's barrier-free 45%: the block-level __syncthreads + LDS
// reduce couples 4 waves -> makespan = max of degree-sums (+~25%) + reduce.
// This revision (R11): WAVE-granular partials. Assignment a=blk*4+wave ->
// (g = a>>3, slot = a&7); wave strides graph nodes by 8 (~6 nodes, variance
// averaged), accumulates in regs, writes its own 1KB fp32 partial. Zero LDS,
// zero barriers, zero atomics — R7's free-running wave regime + fusion.

// fp8 fixed scale: |hs| <~ 0.2 typ; x128 keeps values in e4m3 normal range.
#define HS_SCALE 128.0f
#define HS_INV   (1.0f / 128.0f)

__device__ inline void acc_fp8x4(unsigned int w, float& a0, float& a1, float& a2, float& a3) {
    floatx2 lo = __builtin_amdgcn_cvt_pk_f32_fp8(w, false);
    floatx2 hi = __builtin_amdgcn_cvt_pk_f32_fp8(w, true);
    a0 += lo[0]; a1 += lo[1]; a2 += hi[0]; a3 += hi[1];
}

// 16-lane group sum via DPP row_ror rotations (1,2,4,8).
__device__ inline float grp16_reduce(float v) {
    int x;
    x = __builtin_amdgcn_update_dpp(0, __float_as_int(v), 0x121, 0xF, 0xF, true);
    v += __int_as_float(x);
    x = __builtin_amdgcn_update_dpp(0, __float_as_int(v), 0x122, 0xF, 0xF, true);
    v += __int_as_float(x);
    x = __builtin_amdgcn_update_dpp(0, __float_as_int(v), 0x124, 0xF, 0xF, true);
    v += __int_as_float(x);
    x = __builtin_amdgcn_update_dpp(0, __float_as_int(v), 0x128, 0xF, 0xF, true);
    v += __int_as_float(x);
    return v;
}

// ---------------------------------------------------------------------------
// prep: w2t = fp16(gW2^T) (blocks 0..255), M11 = atom_emb@gW1 (blocks 256..266)
// ---------------------------------------------------------------------------
__global__ void prep_kernel(const float* __restrict__ atom_emb, const float* __restrict__ gW1,
                            const float* __restrict__ gW2,
                            float* __restrict__ M11, _Float16* __restrict__ w2t) {
    int i = blockIdx.x * 256 + threadIdx.x;
    if (blockIdx.x < 256) {
        int k = i >> 8, n = i & 255;
        w2t[(size_t)n * kGH + k] = (_Float16)gW2[(size_t)k * kGH + n];
    } else {
        int j = i - 65536;
        if (j < 11 * kGH) {
            int r = j >> 8, c = j & 255;
            float s = 0.f;
            for (int k = 0; k < kEMB; k++) s += atom_emb[r * kEMB + k] * gW1[k * kGH + c];
            M11[j] = s;
        }
    }
}

// ---------------------------------------------------------------------------
// wtrans: all tail weights -> fp16 transposed ([N][K] from [K][N]).
// ---------------------------------------------------------------------------
__global__ void wtrans_kernel(const float* __restrict__ dW1, const float* __restrict__ dW2,
                              const float* __restrict__ dW3, const float* __restrict__ fcW,
                              const float* __restrict__ eW1, const float* __restrict__ eW2,
                              _Float16* __restrict__ dW1t, _Float16* __restrict__ dW2t,
                              _Float16* __restrict__ dW3t, _Float16* __restrict__ fcWt,
                              _Float16* __restrict__ eW1t, _Float16* __restrict__ eW2t) {
    int b = blockIdx.x;
    const float* src; _Float16* dst; int K, N, j0;
    if (b < 1024)      { src = dW1; dst = dW1t; K = 512; N = 512; j0 = b * 256; }
    else if (b < 2048) { src = dW2; dst = dW2t; K = 512; N = 512; j0 = (b - 1024) * 256; }
    else if (b < 2304) { src = dW3; dst = dW3t; K = 512; N = 128; j0 = (b - 2048) * 256; }
    else if (b < 2560) { src = fcW; dst = fcWt; K = 256; N = 256; j0 = (b - 2304) * 256; }
    else if (b < 2688) { src = eW1; dst = eW1t; K = 128; N = 256; j0 = (b - 2560) * 256; }
    else               { src = eW2; dst = eW2t; K = 256; N = 256; j0 = (b - 2688) * 256; }
    int j = j0 + threadIdx.x;            // dst linear: n*K + k
    int n = j / K, k = j - n * K;
    dst[j] = (_Float16)src[(size_t)k * N + n];
}

// ---------------------------------------------------------------------------
// gbounds: gstart[side][g] = lower_bound(batch, g), one PARALLEL search per
// thread.
// ---------------------------------------------------------------------------
__global__ void gbounds_kernel(const int* __restrict__ batch1, const int* __restrict__ batch2,
                               int* __restrict__ gstart) {
    int side = blockIdx.y;
    const int* batch = side ? batch2 : batch1;
    int g = blockIdx.x * 256 + threadIdx.x;
    if (g > kG) return;
    int lo = 0, hi = kN;
    while (lo < hi) { int mid = (lo + hi) >> 1; if (batch[mid] < g) lo = mid + 1; else hi = mid; }
    gstart[side * (kG + 1) + g] = lo;
}

// ---------------------------------------------------------------------------
// binp1: per-block LDS histogram over 196 dst-buckets.
// ---------------------------------------------------------------------------
__global__ void binp1_kernel(const int* __restrict__ ei1, const int* __restrict__ ei2,
                             int* __restrict__ poff) {
    int side = blockIdx.y;
    const int* dst = (side ? ei2 : ei1) + kE;
    __shared__ int hist[kNBKT];
    int t = threadIdx.x;
    if (t < kNBKT) hist[t] = 0;
    __syncthreads();
    int base = blockIdx.x * kEPB;
    for (int j = t; j < kEPB; j += 256)
        atomicAdd(&hist[dst[base + j] >> 8], 1);
    __syncthreads();
    if (t < kNBKT) poff[((side * kNBKT + t) << 8) | blockIdx.x] = hist[t];
}

// scanA: per (side,bucket) exclusive scan over the 256 block counts.
__global__ void scanA_kernel(int* __restrict__ poff, int* __restrict__ btot) {
    int b = blockIdx.x, side = blockIdx.y, t = threadIdx.x;
    __shared__ int s[256];
    int idx = ((side * kNBKT + b) << 8) | t;
    int v = poff[idx];
    s[t] = v;
    __syncthreads();
    for (int o = 1; o < 256; o <<= 1) {
        int u = (t >= o) ? s[t - o] : 0;
        __syncthreads();
        s[t] += u;
        __syncthreads();
    }
    poff[idx] = s[t] - v;
    if (t == 255) btot[side * kNBKT + b] = s[255];
}

// scanB: exclusive scan of bucket totals -> bbase.
__global__ void scanB_kernel(const int* __restrict__ btot, int* __restrict__ bbase) {
    int side = blockIdx.x, t = threadIdx.x;
    __shared__ int s[256];
    int v = (t < kNBKT) ? btot[side * kNBKT + t] : 0;
    s[t] = v;
    __syncthreads();
    for (int o = 1; o < 256; o <<= 1) {
        int u = (t >= o) ? s[t - o] : 0;
        __syncthreads();
        s[t] += u;
        __syncthreads();
    }
    if (t < kNBKT) bbase[side * (kNBKT + 1) + t] = s[t] - v;
    if (t == 255) bbase[side * (kNBKT + 1) + kNBKT] = s[255];
}

// ---------------------------------------------------------------------------
// binp2: block-local LDS bucket-sort, coalesced bucket-major write-out.
// ---------------------------------------------------------------------------
__launch_bounds__(256)
__global__ void binp2_kernel(const int* __restrict__ ei1, const int* __restrict__ ei2,
                             const int* __restrict__ poff, const int* __restrict__ bbase,
                             unsigned int* __restrict__ ebuf) {
    int side = blockIdx.y, blk = blockIdx.x, t = threadIdx.x;
    const int* ei = side ? ei2 : ei1;
    __shared__ int hist[kNBKT], lb[kNBKT], gb[kNBKT], scanbuf[256];
    __shared__ unsigned int sorted[kEPB];
    if (t < kNBKT) hist[t] = 0;
    __syncthreads();
    int base = blk * kEPB;
    for (int j = t; j < kEPB; j += 256)
        atomicAdd(&hist[ei[kE + base + j] >> 8], 1);
    __syncthreads();
    int v = (t < kNBKT) ? hist[t] : 0;
    scanbuf[t] = v;
    __syncthreads();
    for (int o = 1; o < 256; o <<= 1) {
        int u = (t >= o) ? scanbuf[t - o] : 0;
        __syncthreads();
        scanbuf[t] += u;
        __syncthreads();
    }
    if (t < kNBKT) {
        lb[t] = scanbuf[t] - v;
        gb[t] = bbase[side * (kNBKT + 1) + t] + poff[((side * kNBKT + t) << 8) | blk];
        hist[t] = 0;
    }
    __syncthreads();
    for (int j = t; j < kEPB; j += 256) {
        int s_ = ei[base + j];
        int d  = ei[kE + base + j];
        int b  = d >> 8;
        int r  = atomicAdd(&hist[b], 1);
        sorted[lb[b] + r] = ((unsigned int)d << 16) | (unsigned int)s_;
    }
    __syncthreads();
    for (int j = t; j < kEPB; j += 256) {
        unsigned int val = sorted[j];
        int b = val >> 24;
        int gpos = gb[b] + (j - lb[b]);
        ebuf[(size_t)side * kE + gpos] = val;
    }
}

// ---------------------------------------------------------------------------
// binp3: one block per bucket; LDS slot counters; col_ell stores in a 32KB
// window. Fused epilogue: degrees->counts, dinv, xd.
// ---------------------------------------------------------------------------
__global__ void binp3_kernel(const unsigned int* __restrict__ ebuf, const int* __restrict__ bbase,
                             unsigned short* __restrict__ col_ell, int* __restrict__ counts,
                             float* __restrict__ dinv, int2* __restrict__ xd,
                             const int* __restrict__ x1, const int* __restrict__ x2) {
    int b = blockIdx.x, side = blockIdx.y, t = threadIdx.x;
    __shared__ int cnt[256];
    cnt[t] = 0;
    __syncthreads();
    int start = bbase[side * (kNBKT + 1) + b];
    int end   = bbase[side * (kNBKT + 1) + b + 1];
    for (int k = start + t; k < end; k += 256) {
        unsigned int v = ebuf[(size_t)side * kE + k];
        int d8 = (v >> 16) & 255;
        int slot = atomicAdd(&cnt[d8], 1);
        if (slot > kMD - 1) slot = kMD - 1;
        int node = (b << 8) | d8;
        col_ell[((size_t)side * kN + node) * kMD + slot] = (unsigned short)(v & 0xFFFFu);
    }
    __syncthreads();
    int node = (b << 8) | t;
    if (node < kN) {
        int d = cnt[t];
        counts[side * kN + node] = d;
        float dv = rsqrtf((float)(d + 1));           // +1 self-loop
        dinv[side * kN + node] = dv;
        const int* x = side ? x2 : x1;
        xd[side * kN + node] = make_int2(x[node], __float_as_int(dv));
    }
}

// ---------------------------------------------------------------------------
// Conv1 combine, 16-lane groups (4 nodes/wave), DPP reduce, zero LDS ops.
// ---------------------------------------------------------------------------
__global__ void conv1_combine_kernel(const int2* __restrict__ xd,
                                     const int* __restrict__ counts,
                                     const unsigned short* __restrict__ col_ell,
                                     const float* __restrict__ M11,
                                     const float* __restrict__ bias,
                                     _Float16* __restrict__ out) {
    int side = blockIdx.y;
    const int2* xdb = xd + (size_t)side * kN;
    const int* deg = counts + side * kN;
    const unsigned short* ci = col_ell + (size_t)side * kN * kMD;
    _Float16* ob = out + (size_t)side * kN * kGH;

    int tid = threadIdx.x;
    int sub = tid & 15;
    int v = blockIdx.x * 16 + (tid >> 4);

    int cnt = min(deg[v], kMD);
    const unsigned short* cv = ci + (size_t)v * kMD;
    float wt[11];
    #pragma unroll
    for (int t = 0; t < 11; t++) wt[t] = 0.f;
    for (int base = 0; base < cnt; base += 16) {
        int e = base + sub;
        int xs = 15; float ds = 0.f;
        if (e < cnt) {
            int2 t = xdb[(int)cv[e]];
            xs = t.x; ds = __int_as_float(t.y);
        }
        #pragma unroll
        for (int t = 0; t < 11; t++) wt[t] += (xs == t) ? ds : 0.f;
    }
    #pragma unroll
    for (int t = 0; t < 11; t++) wt[t] = grp16_reduce(wt[t]);

    int2 xv = xdb[v];
    float dv = __int_as_float(xv.y);
    #pragma unroll
    for (int q = 0; q < 4; q++) {
        int c = q * 64 + sub * 4;
        float4 bia = *(const float4*)(bias + c);
        float4 m = *(const float4*)(M11 + xv.x * kGH + c);
        float4 acc = make_float4(dv * m.x, dv * m.y, dv * m.z, dv * m.w);
        #pragma unroll
        for (int t = 0; t < 11; t++) {
            float w = wt[t];
            float4 mt = *(const float4*)(M11 + t * kGH + c);
            acc.x += w * mt.x; acc.y += w * mt.y;
            acc.z += w * mt.z; acc.w += w * mt.w;
        }
        half4v o;
        o[0] = (_Float16)fmaxf(dv * acc.x + bia.x, 0.f);
        o[1] = (_Float16)fmaxf(dv * acc.y + bia.y, 0.f);
        o[2] = (_Float16)fmaxf(dv * acc.z + bia.z, 0.f);
        o[3] = (_Float16)fmaxf(dv * acc.w + bia.w, 0.f);
        *(half4v*)(ob + (size_t)v * kGH + c) = o;
    }
}

// ---------------------------------------------------------------------------
// Conv2 GEMM via MFMA f16, LDS-tiled: hs = fp8(HS_SCALE * dinv ⊙ (h2 @ W2))
// BM=128, BN=128, BK=64. 4 waves (2x2); wave = 64x64.
// ---------------------------------------------------------------------------
__launch_bounds__(256)
__global__ void gemm2_mfma_kernel(const _Float16* __restrict__ A,
                                  const _Float16* __restrict__ Bt,
                                  const float* __restrict__ dinv,
                                  unsigned char* __restrict__ C) {
    __shared__ _Float16 As[128][72];
    __shared__ _Float16 Bs[128][72];

    int side = blockIdx.z;
    const _Float16* Ab = A + (size_t)side * kN * kGH;
    const float* db = dinv + (size_t)side * kN;
    unsigned char* Cb = C + (size_t)side * kN * kGH;

    int tid = threadIdx.x;
    int wave = tid >> 6, lane = tid & 63;
    int quad = lane >> 4, r = lane & 15;
    int wm = wave >> 1, wn = wave & 1;
    int row0 = blockIdx.x * 128;
    int col0 = blockIdx.y * 128;

    floatx4 acc[4][4];
    #pragma unroll
    for (int i = 0; i < 4; i++)
        #pragma unroll
        for (int j = 0; j < 4; j++) acc[i][j] = (floatx4){0.f, 0.f, 0.f, 0.f};

    for (int k0 = 0; k0 < kGH; k0 += 64) {
        #pragma unroll
        for (int u = 0; u < 4; u++) {
            int idx = tid + u * 256;
            int row = idx >> 3;
            int seg = (idx & 7) * 8;
            int gr = row0 + row;
            if (gr >= kN) gr = kN - 1;
            *(half8v*)&As[row][seg] = *(const half8v*)(Ab + (size_t)gr * kGH + k0 + seg);
            *(half8v*)&Bs[row][seg] = *(const half8v*)(Bt + (size_t)(col0 + row) * kGH + k0 + seg);
        }
        __syncthreads();
        #pragma unroll
        for (int ks = 0; ks < 2; ks++) {
            half8v af[4], bf[4];
            #pragma unroll
            for (int mt = 0; mt < 4; mt++)
                af[mt] = *(const half8v*)&As[wm * 64 + mt * 16 + r][ks * 32 + quad * 8];
            #pragma unroll
            for (int nt = 0; nt < 4; nt++)
                bf[nt] = *(const half8v*)&Bs[wn * 64 + nt * 16 + r][ks * 32 + quad * 8];
            #pragma unroll
            for (int mt = 0; mt < 4; mt++)
                #pragma unroll
                for (int nt = 0; nt < 4; nt++)
                    acc[mt][nt] = __builtin_amdgcn_mfma_f32_16x16x32_f16(af[mt], bf[nt],
                                                                         acc[mt][nt], 0, 0, 0);
        }
        __syncthreads();
    }

    #pragma unroll
    for (int mt = 0; mt < 4; mt++) {
        #pragma unroll
        for (int i = 0; i < 4; i++) {
            int grow = row0 + wm * 64 + mt * 16 + quad * 4 + i;
            if (grow >= kN) continue;
            float rsq = db[grow] * HS_SCALE;
            #pragma unroll
            for (int nt = 0; nt < 4; nt++) {
                int gcol = col0 + wn * 64 + nt * 16 + r;
                float q = acc[mt][nt][i] * rsq;
                Cb[(size_t)grow * kGH + gcol] =
                    (unsigned char)__builtin_amdgcn_cvt_pk_fp8_f32(q, q, 0, false);
            }
        }
    }
}

// ---------------------------------------------------------------------------
// Unified tail GEMM via MFMA f16 (fp32 accum): C = [relu](A @ B + bias)
// ---------------------------------------------------------------------------
__launch_bounds__(256)
__global__ void gemm_tail_kernel(const _Float16* __restrict__ A,
                                 const _Float16* __restrict__ Bt,
                                 void* __restrict__ Cout,
                                 int N, int K,
                                 const float* __restrict__ bias,
                                 int relu, int f32out) {
    __shared__ _Float16 As[64][72];
    __shared__ _Float16 Bs[64][72];
    int tid = threadIdx.x;
    int wave = tid >> 6, lane = tid & 63;
    int quad = lane >> 4, r = lane & 15;
    int wm = wave >> 1, wn = wave & 1;
    int row0 = blockIdx.x * 64, col0 = blockIdx.y * 64;

    floatx4 acc[2][2];
    #pragma unroll
    for (int i = 0; i < 2; i++)
        #pragma unroll
        for (int j = 0; j < 2; j++) acc[i][j] = (floatx4){0.f, 0.f, 0.f, 0.f};

    for (int k0 = 0; k0 < K; k0 += 64) {
        #pragma unroll
        for (int u = 0; u < 2; u++) {
            int idx = tid + u * 256;           // 0..511
            int row = idx >> 3;                // 0..63
            int seg = (idx & 7) * 8;           // 0..56
            *(half8v*)&As[row][seg] = *(const half8v*)(A + (size_t)(row0 + row) * K + k0 + seg);
            *(half8v*)&Bs[row][seg] = *(const half8v*)(Bt + (size_t)(col0 + row) * K + k0 + seg);
        }
        __syncthreads();
        #pragma unroll
        for (int ks = 0; ks < 2; ks++) {
            half8v af[2], bf[2];
            #pragma unroll
            for (int mt = 0; mt < 2; mt++)
                af[mt] = *(const half8v*)&As[wm * 32 + mt * 16 + r][ks * 32 + quad * 8];
            #pragma unroll
            for (int nt = 0; nt < 2; nt++)
                bf[nt] = *(const half8v*)&Bs[wn * 32 + nt * 16 + r][ks * 32 + quad * 8];
            #pragma unroll
            for (int mt = 0; mt < 2; mt++)
                #pragma unroll
                for (int nt = 0; nt < 2; nt++)
                    acc[mt][nt] = __builtin_amdgcn_mfma_f32_16x16x32_f16(af[mt], bf[nt],
                                                                         acc[mt][nt], 0, 0, 0);
        }
        __syncthreads();
    }

    #pragma unroll
    for (int mt = 0; mt < 2; mt++) {
        #pragma unroll
        for (int i = 0; i < 4; i++) {
            int grow = row0 + wm * 32 + mt * 16 + quad * 4 + i;
            #pragma unroll
            for (int nt = 0; nt < 2; nt++) {
                int gcol = col0 + wn * 32 + nt * 16 + r;
                float v = acc[mt][nt][i] + bias[gcol];
                if (relu) v = fmaxf(v, 0.f);
                if (f32out) ((float*)Cout)[(size_t)grow * N + gcol] = v;
                else ((_Float16*)Cout)[(size_t)grow * N + gcol] = (_Float16)v;
            }
        }
    }
}

// ---------------------------------------------------------------------------
// Fused conv2-aggregate + mean-pool, WAVE-granular partials (R11).
// Grid (kG*kPP/4, 2); assignment a = blockIdx.x*4 + wave -> g = a>>3,
// slot pI = a&7. Wave strides graph nodes by kPP (~6 nodes), accumulates
// h4 rows in regs, writes its own fp32 partial. NO LDS, NO barriers.
// ---------------------------------------------------------------------------
__global__ void aggpoolw_kernel(const unsigned char* __restrict__ hs, const float* __restrict__ dinv,
                                const int* __restrict__ counts,
                                const unsigned short* __restrict__ col_ell,
                                const float* __restrict__ bias,
                                const int* __restrict__ gstart,
                                float* __restrict__ ppart) {
    int side = blockIdx.y;
    int a = blockIdx.x * 4 + (threadIdx.x >> 6);
    int g = a >> 3;
    int pI = a & 7;
    const unsigned char* hb = hs + (size_t)side * kN * kGH;
    const float* dv_ = dinv + side * kN;
    const int* deg = counts + side * kN;
    const unsigned short* ci = col_ell + (size_t)side * kN * kMD;

    int start = gstart[side * (kG + 1) + g];
    int end   = gstart[side * (kG + 1) + g + 1];

    int lane = threadIdx.x & 63;
    int c = lane * 4;
    float4 bia = *(const float4*)(bias + c);
    float p0 = 0.f, p1 = 0.f, p2 = 0.f, p3 = 0.f;

    for (int v = start + pI; v < end; v += kPP) {
        float dv = dv_[v];
        float a0 = 0.f, a1 = 0.f, a2 = 0.f, a3 = 0.f;
        acc_fp8x4(*(const unsigned int*)(hb + (size_t)v * kGH + c), a0, a1, a2, a3); // self
        int cnt = min(deg[v], kMD);
        int idxl = (lane < cnt) ? (int)ci[(size_t)v * kMD + lane] : 0;
        int j = 0;
        for (; j + 16 <= cnt; j += 16) {
            unsigned int w[16];
            #pragma unroll
            for (int u = 0; u < 16; u++)
                w[u] = *(const unsigned int*)(hb + (size_t)__shfl(idxl, j + u) * kGH + c);
            #pragma unroll
            for (int u = 0; u < 16; u++) acc_fp8x4(w[u], a0, a1, a2, a3);
        }
        for (; j + 8 <= cnt; j += 8) {
            unsigned int w[8];
            #pragma unroll
            for (int u = 0; u < 8; u++)
                w[u] = *(const unsigned int*)(hb + (size_t)__shfl(idxl, j + u) * kGH + c);
            #pragma unroll
            for (int u = 0; u < 8; u++) acc_fp8x4(w[u], a0, a1, a2, a3);
        }
        for (; j < cnt; j++)
            acc_fp8x4(*(const unsigned int*)(hb + (size_t)__shfl(idxl, j) * kGH + c),
                      a0, a1, a2, a3);
        float f = dv * HS_INV;
        p0 += fmaxf(f * a0 + bia.x, 0.f);
        p1 += fmaxf(f * a1 + bia.y, 0.f);
        p2 += fmaxf(f * a2 + bia.z, 0.f);
        p3 += fmaxf(f * a3 + bia.w, 0.f);
    }

    // Wave-private partial: 64 lanes x float4 = coalesced 1KB.
    *(float4*)(ppart + (((size_t)side * kG + g) * kPP + pI) * kGH + c) =
        make_float4(p0, p1, p2, p3);
}

// preduce: sum the kPP partials, divide by graph size -> pooled16.
__global__ void preduce_kernel(const float* __restrict__ ppart,
                               const int* __restrict__ gstart,
                               _Float16* __restrict__ pooled16) {
    int side = blockIdx.y;
    int g = blockIdx.x;
    int start = gstart[side * (kG + 1) + g];
    int end   = gstart[side * (kG + 1) + g + 1];
    int t = threadIdx.x;
    const float* pb = ppart + (((size_t)side * kG + g) * kPP) * kGH;
    float s = 0.f;
    #pragma unroll
    for (int p = 0; p < kPP; p++) s += pb[p * kGH + t];
    float inv = 1.0f / fmaxf((float)(end - start), 1.0f);
    pooled16[(size_t)(side * kG + g) * kGH + t] = (_Float16)(s * inv);
}

// entity gather: e16[r][k] = fp16(relu(emb[ent[r]][k])), r in [0,2G)
__global__ void egather_kernel(const float* __restrict__ emb,
                               const int* __restrict__ ent1, const int* __restrict__ ent2,
                               _Float16* __restrict__ e16) {
    int rr = blockIdx.x;
    int idx = (rr < kG) ? ent1[rr] : ent2[rr - kG];
    int k = threadIdx.x;   // 128
    e16[(size_t)rr * kEMB + k] = (_Float16)fmaxf(emb[(size_t)idx * kEMB + k], 0.f);
}

// egs prep: egs16[g][k] = fp16(relu(eg1[g][k] + eg2[g][k]))
__global__ void egsprep_kernel(const _Float16* __restrict__ gfc16,
                               const _Float16* __restrict__ ento16,
                               _Float16* __restrict__ egs16) {
    int idx = blockIdx.x * 256 + threadIdx.x;   // 0..65535
    int g = idx >> 6;                            // 0..1023
    int k8 = (idx & 63) * 8;                     // 0..504
    const _Float16* src = (k8 < kGH) ? gfc16 : ento16;
    int kk = (k8 < kGH) ? k8 : k8 - kGH;
    half8v a = *(const half8v*)(src + (size_t)g * kGH + kk);
    half8v b = *(const half8v*)(src + (size_t)(g + kG) * kGH + kk);
    half8v o;
    #pragma unroll
    for (int u = 0; u < 8; u++) o[u] = (_Float16)fmaxf((float)a[u] + (float)b[u], 0.f);
    *(half8v*)(egs16 + (size_t)g * kHID + k8) = o;
}

// ---------------------------------------------------------------------------
// Host launch
// ---------------------------------------------------------------------------
static inline char* carve(char*& p, size_t bytes) {
    char* r = p;
    p += (bytes + 255) & ~(size_t)255;
    return r;
}

extern "C" void kernel_launch(void* const* d_in, const int* in_sizes, int n_in,
                              void* d_out, int out_size, void* d_ws, size_t ws_size,
                              hipStream_t stream) {
    const int*   x1       = (const int*)d_in[0];
    const int*   ei1      = (const int*)d_in[1];
    const int*   ent1     = (const int*)d_in[2];
    const int*   batch1   = (const int*)d_in[3];
    const int*   x2       = (const int*)d_in[4];
    const int*   ei2      = (const int*)d_in[5];
    const int*   ent2     = (const int*)d_in[6];
    const int*   batch2   = (const int*)d_in[7];
    const float* atom_emb = (const float*)d_in[8];
    const float* gW1      = (const float*)d_in[9];
    const float* gb1      = (const float*)d_in[10];
    const float* gW2      = (const float*)d_in[11];
    const float* gb2      = (const float*)d_in[12];
    const float* fcW      = (const float*)d_in[13];
    const float* fcb      = (const float*)d_in[14];
    const float* ent_emb  = (const float*)d_in[15];
    const float* eW1      = (const float*)d_in[16];
    const float* eb1      = (const float*)d_in[17];
    const float* eW2      = (const float*)d_in[18];
    const float* eb2      = (const float*)d_in[19];
    const float* dW1      = (const float*)d_in[20];
    const float* db1      = (const float*)d_in[21];
    const float* dW2      = (const float*)d_in[22];
    const float* db2      = (const float*)d_in[23];
    const float* dW3      = (const float*)d_in[24];
    const float* db3      = (const float*)d_in[25];
    float* out = (float*)d_out;

    // Workspace carve (no zeroed spans needed — binp3 writes all counts).
    char* p = (char*)d_ws;
    _Float16* h2_h   = (_Float16*)carve(p, (size_t)2 * kN * kGH * 2);
    unsigned char* hs8 = (unsigned char*)carve(p, (size_t)2 * kN * kGH); // fp8 hs
    unsigned short* col_ell = (unsigned short*)carve(p, (size_t)2 * kN * kMD * 2);
    unsigned int* ebuf = (unsigned int*)carve(p, (size_t)2 * kE * 4);
    int*   poff    = (int*)  carve(p, (size_t)2 * kNBKT * 256 * 4);
    int*   btot    = (int*)  carve(p, (size_t)2 * kNBKT * 4);
    int*   bbase   = (int*)  carve(p, (size_t)2 * (kNBKT + 1) * 4);
    int*   counts  = (int*)  carve(p, (size_t)2 * kN * 4);
    float* dinv    = (float*)carve(p, (size_t)2 * kN * 4);
    int2*  xd      = (int2*) carve(p, (size_t)2 * kN * 8);
    int*   gstart  = (int*)  carve(p, (size_t)2 * (kG + 1) * 4);
    float* M11     = (float*)carve(p, 11 * kGH * 4);
    _Float16* w2t  = (_Float16*)carve(p, (size_t)kGH * kGH * 2);
    float* ppart   = (float*)carve(p, (size_t)2 * kG * kPP * kGH * 4);
    // fp16 tail buffers
    _Float16* pooled16 = (_Float16*)carve(p, (size_t)2 * kG * kGH * 2);
    _Float16* gfc16    = (_Float16*)carve(p, (size_t)2 * kG * kGH * 2);
    _Float16* e16      = (_Float16*)carve(p, (size_t)2 * kG * kEMB * 2);
    _Float16* etmp16   = (_Float16*)carve(p, (size_t)2 * kG * kEH * 2);
    _Float16* ento16   = (_Float16*)carve(p, (size_t)2 * kG * kEH * 2);
    _Float16* egs16    = (_Float16*)carve(p, (size_t)kG * kHID * 2);
    _Float16* dh1_16   = (_Float16*)carve(p, (size_t)kG * kHID * 2);
    _Float16* dh2_16   = (_Float16*)carve(p, (size_t)kG * kHID * 2);
    // fp16 transposed tail weights
    _Float16* dW1t = (_Float16*)carve(p, (size_t)kHID * kHID * 2);
    _Float16* dW2t = (_Float16*)carve(p, (size_t)kHID * kHID * 2);
    _Float16* dW3t = (_Float16*)carve(p, (size_t)kOUT * kHID * 2);
    _Float16* fcWt = (_Float16*)carve(p, (size_t)kGH * kGH * 2);
    _Float16* eW1t = (_Float16*)carve(p, (size_t)kEH * kEMB * 2);
    _Float16* eW2t = (_Float16*)carve(p, (size_t)kEH * kEH * 2);

    // --- Graph structure via LDS binning (zero global atomics) + conv1 ---
    prep_kernel<<<267, 256, 0, stream>>>(atom_emb, gW1, gW2, M11, w2t);
    wtrans_kernel<<<2944, 256, 0, stream>>>(dW1, dW2, dW3, fcW, eW1, eW2,
                                            dW1t, dW2t, dW3t, fcWt, eW1t, eW2t);
    gbounds_kernel<<<dim3((kG + 256) / 256, 2), 256, 0, stream>>>(batch1, batch2, gstart);
    binp1_kernel<<<dim3(kPBLK, 2), 256, 0, stream>>>(ei1, ei2, poff);
    scanA_kernel<<<dim3(kNBKT, 2), 256, 0, stream>>>(poff, btot);
    scanB_kernel<<<2, 256, 0, stream>>>(btot, bbase);
    binp2_kernel<<<dim3(kPBLK, 2), 256, 0, stream>>>(ei1, ei2, poff, bbase, ebuf);
    binp3_kernel<<<dim3(kNBKT, 2), 256, 0, stream>>>(ebuf, bbase, col_ell, counts,
                                                     dinv, xd, x1, x2);
    conv1_combine_kernel<<<dim3(kN / 16, 2), 256, 0, stream>>>(xd, counts, col_ell,
                                                               M11, gb1, h2_h);

    // --- Conv2 GEMM (MFMA f16): hs8 = fp8(128 * dinv ⊙ (h2 @ W2)) ---
    gemm2_mfma_kernel<<<dim3((kN + 127) / 128, kGH / 128, 2), 256, 0, stream>>>(h2_h, w2t,
                                                                                dinv, hs8);
    // --- Fused aggregate + mean-pool, wave-granular partials (no barriers) ---
    aggpoolw_kernel<<<dim3(kG * kPP / 4, 2), 256, 0, stream>>>(hs8, dinv, counts, col_ell,
                                                               gb2, gstart, ppart);
    preduce_kernel<<<dim3(kG, 2), 256, 0, stream>>>(ppart, gstart, pooled16);
    // --- Entity gather (fp16) ---
    egather_kernel<<<2 * kG, 128, 0, stream>>>(ent_emb, ent1, ent2, e16);

    // --- Tail GEMMs, all fp16 MFMA (fp32 accum) ---
    gemm_tail_kernel<<<dim3(2 * kG / 64, kGH / 64), 256, 0, stream>>>(
        pooled16, fcWt, gfc16, kGH, kGH, fcb, 0, 0);
    gemm_tail_kernel<<<dim3(2 * kG / 64, kEH / 64), 256, 0, stream>>>(
        e16, eW1t, etmp16, kEH, kEMB, eb1, 1, 0);
    gemm_tail_kernel<<<dim3(2 * kG / 64, kEH / 64), 256, 0, stream>>>(
        etmp16, eW2t, ento16, kEH, kEH, eb2, 1, 0);
    egsprep_kernel<<<kG * kHID / 8 / 256, 256, 0, stream>>>(gfc16, ento16, egs16);
    gemm_tail_kernel<<<dim3(kG / 64, kHID / 64), 256, 0, stream>>>(
        egs16, dW1t, dh1_16, kHID, kHID, db1, 1, 0);
    gemm_tail_kernel<<<dim3(kG / 64, kHID / 64), 256, 0, stream>>>(
        dh1_16, dW2t, dh2_16, kHID, kHID, db2, 1, 0);
    gemm_tail_kernel<<<dim3(kG / 64, kOUT / 64), 256, 0, stream>>>(
        dh2_16, dW3t, out, kOUT, kHID, db3, 0, 1);
}

// Round 12
// 398.074 us; speedup vs baseline: 1.1485x; 1.0615x over previous
//
#include <hip/hip_runtime.h>
#include <hip/hip_fp16.h>

// Problem constants
static constexpr int kN = 50000;      // nodes per side
static constexpr int kE = 800000;     // edges per side
static constexpr int kG = 1024;       // graphs per batch
static constexpr int kEMB = 128;
static constexpr int kGH = 256;
static constexpr int kEH = 256;
static constexpr int kOUT = 128;
static constexpr int kHID = 512;
static constexpr int kNB = (kN + 255) / 256;   // 196 chunks per side
static constexpr int kMD = 64;        // ELL stride; deg ~ Poisson(16), P(deg>=64)~e^-125
static constexpr int kNBKT = 196;     // dst buckets of 256 nodes (50000 -> 196)
static constexpr int kEPB = 3125;     // edges per bin block; 256 blocks exactly
static constexpr int kPBLK = 256;     // bin blocks per side (256*3125 = 800000)

typedef __attribute__((ext_vector_type(8))) _Float16 half8v;
typedef __attribute__((ext_vector_type(4))) _Float16 half4v;
typedef __attribute__((ext_vector_type(4))) float floatx4;
typedef __attribute__((ext_vector_type(2))) float floatx2;

// NOTE (R6): cross-XCD plain-data handoff through grid.sync() gave stale reads.
// NOTE (R7/R12): device atomics memory-side; floor is OP-COUNT ~21/ns.
// (R2) fp8 hs: 659->616us. (R3) conv1 DPP groups ->596us. (R4) NEUTRAL.
// (R5) ELL fusion regressed rank (atomics+random stores share mem-op pipe).
// (R6) LDS bucket binning, zero global atomics: 585->523us.
// (R7) fp16-MFMA unified tail: 523->439us. aggregate2 measured 60.5us
// (1 wave/node, no barriers) — the PROVEN gather structure.
// (R8-R11) aggregate+pool fusion arc: 102 -> 113 -> 82 -> 77us. Lesson:
// multi-node serial wave loops never recover R7's 3.6TB/s; fusion saves the
// h4 round-trip but loses more in the gather. REVERTED this round (R12):
// R7-exact aggregate2 + fast parallel pool (gstart + 4-wave vectorized).
// Also (R12): conv1 epilogue is algebraically a [100K x 16]@[16 x 256] GEMM
// (wt'[t] = dv*wt[t] + dv^2*delta(x=t)) -> split into conv1_wt (gather only)
// + gemm1 (MFMA K=32), killing the per-node M11 re-read loop.

// fp8 fixed scale: |hs| <~ 0.2 typ; x128 keeps values in e4m3 normal range.
#define HS_SCALE 128.0f
#define HS_INV   (1.0f / 128.0f)

__device__ inline void acc_fp8x4(unsigned int w, float& a0, float& a1, float& a2, float& a3) {
    floatx2 lo = __builtin_amdgcn_cvt_pk_f32_fp8(w, false);
    floatx2 hi = __builtin_amdgcn_cvt_pk_f32_fp8(w, true);
    a0 += lo[0]; a1 += lo[1]; a2 += hi[0]; a3 += hi[1];
}

// 16-lane group sum via DPP row_ror rotations (1,2,4,8).
__device__ inline float grp16_reduce(float v) {
    int x;
    x = __builtin_amdgcn_update_dpp(0, __float_as_int(v), 0x121, 0xF, 0xF, true);
    v += __int_as_float(x);
    x = __builtin_amdgcn_update_dpp(0, __float_as_int(v), 0x122, 0xF, 0xF, true);
    v += __int_as_float(x);
    x = __builtin_amdgcn_update_dpp(0, __float_as_int(v), 0x124, 0xF, 0xF, true);
    v += __int_as_float(x);
    x = __builtin_amdgcn_update_dpp(0, __float_as_int(v), 0x128, 0xF, 0xF, true);
    v += __int_as_float(x);
    return v;
}

// ---------------------------------------------------------------------------
// prep: w2t = fp16(gW2^T) (blocks 0..255), M11 = atom_emb@gW1 (blocks 256..266),
// m11t = fp16(M11^T padded to K=32) (blocks 267..298; recomputed directly to
// avoid intra-kernel dependence on M11).
// ---------------------------------------------------------------------------
__global__ void prep_kernel(const float* __restrict__ atom_emb, const float* __restrict__ gW1,
                            const float* __restrict__ gW2,
                            float* __restrict__ M11, _Float16* __restrict__ w2t,
                            _Float16* __restrict__ m11t) {
    int i = blockIdx.x * 256 + threadIdx.x;
    if (blockIdx.x < 256) {
        int k = i >> 8, n = i & 255;
        w2t[(size_t)n * kGH + k] = (_Float16)gW2[(size_t)k * kGH + n];
    } else {
        int j = i - 65536;
        if (j < 11 * kGH) {
            int r = j >> 8, c = j & 255;
            float s = 0.f;
            for (int k = 0; k < kEMB; k++) s += atom_emb[r * kEMB + k] * gW1[k * kGH + c];
            M11[j] = s;
        } else if (j < 11 * kGH + 256 * 32) {
            int j2 = j - 11 * kGH;
            int n = j2 >> 5, k = j2 & 31;     // m11t[n][k] = M11[k][n], 0 for k>=11
            float s = 0.f;
            if (k < 11)
                for (int p = 0; p < kEMB; p++) s += atom_emb[k * kEMB + p] * gW1[p * kGH + n];
            m11t[j2] = (_Float16)s;
        }
    }
}

// ---------------------------------------------------------------------------
// wtrans: all tail weights -> fp16 transposed ([N][K] from [K][N]).
// ---------------------------------------------------------------------------
__global__ void wtrans_kernel(const float* __restrict__ dW1, const float* __restrict__ dW2,
                              const float* __restrict__ dW3, const float* __restrict__ fcW,
                              const float* __restrict__ eW1, const float* __restrict__ eW2,
                              _Float16* __restrict__ dW1t, _Float16* __restrict__ dW2t,
                              _Float16* __restrict__ dW3t, _Float16* __restrict__ fcWt,
                              _Float16* __restrict__ eW1t, _Float16* __restrict__ eW2t) {
    int b = blockIdx.x;
    const float* src; _Float16* dst; int K, N, j0;
    if (b < 1024)      { src = dW1; dst = dW1t; K = 512; N = 512; j0 = b * 256; }
    else if (b < 2048) { src = dW2; dst = dW2t; K = 512; N = 512; j0 = (b - 1024) * 256; }
    else if (b < 2304) { src = dW3; dst = dW3t; K = 512; N = 128; j0 = (b - 2048) * 256; }
    else if (b < 2560) { src = fcW; dst = fcWt; K = 256; N = 256; j0 = (b - 2304) * 256; }
    else if (b < 2688) { src = eW1; dst = eW1t; K = 128; N = 256; j0 = (b - 2560) * 256; }
    else               { src = eW2; dst = eW2t; K = 256; N = 256; j0 = (b - 2688) * 256; }
    int j = j0 + threadIdx.x;            // dst linear: n*K + k
    int n = j / K, k = j - n * K;
    dst[j] = (_Float16)src[(size_t)k * N + n];
}

// ---------------------------------------------------------------------------
// gbounds: gstart[side][g] = lower_bound(batch, g), parallel per thread.
// ---------------------------------------------------------------------------
__global__ void gbounds_kernel(const int* __restrict__ batch1, const int* __restrict__ batch2,
                               int* __restrict__ gstart) {
    int side = blockIdx.y;
    const int* batch = side ? batch2 : batch1;
    int g = blockIdx.x * 256 + threadIdx.x;
    if (g > kG) return;
    int lo = 0, hi = kN;
    while (lo < hi) { int mid = (lo + hi) >> 1; if (batch[mid] < g) lo = mid + 1; else hi = mid; }
    gstart[side * (kG + 1) + g] = lo;
}

// ---------------------------------------------------------------------------
// binp1: per-block LDS histogram over 196 dst-buckets.
// ---------------------------------------------------------------------------
__global__ void binp1_kernel(const int* __restrict__ ei1, const int* __restrict__ ei2,
                             int* __restrict__ poff) {
    int side = blockIdx.y;
    const int* dst = (side ? ei2 : ei1) + kE;
    __shared__ int hist[kNBKT];
    int t = threadIdx.x;
    if (t < kNBKT) hist[t] = 0;
    __syncthreads();
    int base = blockIdx.x * kEPB;
    for (int j = t; j < kEPB; j += 256)
        atomicAdd(&hist[dst[base + j] >> 8], 1);
    __syncthreads();
    if (t < kNBKT) poff[((side * kNBKT + t) << 8) | blockIdx.x] = hist[t];
}

// scanA: per (side,bucket) exclusive scan over the 256 block counts.
__global__ void scanA_kernel(int* __restrict__ poff, int* __restrict__ btot) {
    int b = blockIdx.x, side = blockIdx.y, t = threadIdx.x;
    __shared__ int s[256];
    int idx = ((side * kNBKT + b) << 8) | t;
    int v = poff[idx];
    s[t] = v;
    __syncthreads();
    for (int o = 1; o < 256; o <<= 1) {
        int u = (t >= o) ? s[t - o] : 0;
        __syncthreads();
        s[t] += u;
        __syncthreads();
    }
    poff[idx] = s[t] - v;
    if (t == 255) btot[side * kNBKT + b] = s[255];
}

// scanB: exclusive scan of bucket totals -> bbase.
__global__ void scanB_kernel(const int* __restrict__ btot, int* __restrict__ bbase) {
    int side = blockIdx.x, t = threadIdx.x;
    __shared__ int s[256];
    int v = (t < kNBKT) ? btot[side * kNBKT + t] : 0;
    s[t] = v;
    __syncthreads();
    for (int o = 1; o < 256; o <<= 1) {
        int u = (t >= o) ? s[t - o] : 0;
        __syncthreads();
        s[t] += u;
        __syncthreads();
    }
    if (t < kNBKT) bbase[side * (kNBKT + 1) + t] = s[t] - v;
    if (t == 255) bbase[side * (kNBKT + 1) + kNBKT] = s[255];
}

// ---------------------------------------------------------------------------
// binp2: block-local LDS bucket-sort, coalesced bucket-major write-out.
// ---------------------------------------------------------------------------
__launch_bounds__(256)
__global__ void binp2_kernel(const int* __restrict__ ei1, const int* __restrict__ ei2,
                             const int* __restrict__ poff, const int* __restrict__ bbase,
                             unsigned int* __restrict__ ebuf) {
    int side = blockIdx.y, blk = blockIdx.x, t = threadIdx.x;
    const int* ei = side ? ei2 : ei1;
    __shared__ int hist[kNBKT], lb[kNBKT], gb[kNBKT], scanbuf[256];
    __shared__ unsigned int sorted[kEPB];
    if (t < kNBKT) hist[t] = 0;
    __syncthreads();
    int base = blk * kEPB;
    for (int j = t; j < kEPB; j += 256)
        atomicAdd(&hist[ei[kE + base + j] >> 8], 1);
    __syncthreads();
    int v = (t < kNBKT) ? hist[t] : 0;
    scanbuf[t] = v;
    __syncthreads();
    for (int o = 1; o < 256; o <<= 1) {
        int u = (t >= o) ? scanbuf[t - o] : 0;
        __syncthreads();
        scanbuf[t] += u;
        __syncthreads();
    }
    if (t < kNBKT) {
        lb[t] = scanbuf[t] - v;
        gb[t] = bbase[side * (kNBKT + 1) + t] + poff[((side * kNBKT + t) << 8) | blk];
        hist[t] = 0;
    }
    __syncthreads();
    for (int j = t; j < kEPB; j += 256) {
        int s_ = ei[base + j];
        int d  = ei[kE + base + j];
        int b  = d >> 8;
        int r  = atomicAdd(&hist[b], 1);
        sorted[lb[b] + r] = ((unsigned int)d << 16) | (unsigned int)s_;
    }
    __syncthreads();
    for (int j = t; j < kEPB; j += 256) {
        unsigned int val = sorted[j];
        int b = val >> 24;
        int gpos = gb[b] + (j - lb[b]);
        ebuf[(size_t)side * kE + gpos] = val;
    }
}

// ---------------------------------------------------------------------------
// binp3: one block per bucket; LDS slot counters; col_ell stores in a 32KB
// window. Fused epilogue: degrees->counts, dinv, xd.
// ---------------------------------------------------------------------------
__global__ void binp3_kernel(const unsigned int* __restrict__ ebuf, const int* __restrict__ bbase,
                             unsigned short* __restrict__ col_ell, int* __restrict__ counts,
                             float* __restrict__ dinv, int2* __restrict__ xd,
                             const int* __restrict__ x1, const int* __restrict__ x2) {
    int b = blockIdx.x, side = blockIdx.y, t = threadIdx.x;
    __shared__ int cnt[256];
    cnt[t] = 0;
    __syncthreads();
    int start = bbase[side * (kNBKT + 1) + b];
    int end   = bbase[side * (kNBKT + 1) + b + 1];
    for (int k = start + t; k < end; k += 256) {
        unsigned int v = ebuf[(size_t)side * kE + k];
        int d8 = (v >> 16) & 255;
        int slot = atomicAdd(&cnt[d8], 1);
        if (slot > kMD - 1) slot = kMD - 1;
        int node = (b << 8) | d8;
        col_ell[((size_t)side * kN + node) * kMD + slot] = (unsigned short)(v & 0xFFFFu);
    }
    __syncthreads();
    int node = (b << 8) | t;
    if (node < kN) {
        int d = cnt[t];
        counts[side * kN + node] = d;
        float dv = rsqrtf((float)(d + 1));           // +1 self-loop
        dinv[side * kN + node] = dv;
        const int* x = side ? x2 : x1;
        xd[side * kN + node] = make_int2(x[node], __float_as_int(dv));
    }
}

// ---------------------------------------------------------------------------
// Conv1 histogram only (R12): 16-lane groups, DPP reduce, then emit
// wt16[v][32] fp16: wt'[t] = dv*wt[t] + dv^2*delta(x[v]=t) for t<11, 0 else.
// Lane sub selects wt[sub] via compile-time cndmask chain (no runtime reg
// indexing -> no scratch). Epilogue GEMM moved to gemm1 (MFMA).
// ---------------------------------------------------------------------------
__global__ void conv1_wt_kernel(const int2* __restrict__ xd,
                                const int* __restrict__ counts,
                                const unsigned short* __restrict__ col_ell,
                                _Float16* __restrict__ wt16) {
    int side = blockIdx.y;
    const int2* xdb = xd + (size_t)side * kN;
    const int* deg = counts + side * kN;
    const unsigned short* ci = col_ell + (size_t)side * kN * kMD;
    _Float16* wb = wt16 + (size_t)side * kN * 32;

    int tid = threadIdx.x;
    int sub = tid & 15;
    int v = blockIdx.x * 16 + (tid >> 4);   // exact: 3125*16 = 50000

    int cnt = min(deg[v], kMD);
    const unsigned short* cv = ci + (size_t)v * kMD;
    float wt[11];
    #pragma unroll
    for (int t = 0; t < 11; t++) wt[t] = 0.f;
    for (int base = 0; base < cnt; base += 16) {
        int e = base + sub;
        int xs = 15; float ds = 0.f;
        if (e < cnt) {
            int2 t = xdb[(int)cv[e]];
            xs = t.x; ds = __int_as_float(t.y);
        }
        #pragma unroll
        for (int t = 0; t < 11; t++) wt[t] += (xs == t) ? ds : 0.f;
    }
    #pragma unroll
    for (int t = 0; t < 11; t++) wt[t] = grp16_reduce(wt[t]);

    int2 xv = xdb[v];
    float dv = __int_as_float(xv.y);
    float dv2 = dv * dv;
    // lane sub picks wt[sub] without runtime register indexing
    float mywt = 0.f;
    #pragma unroll
    for (int t = 0; t < 11; t++) mywt = (sub == t) ? wt[t] : mywt;
    float wp = dv * mywt + dv2 * ((xv.x == sub) ? 1.f : 0.f);   // sub>=11 -> 0
    wb[(size_t)v * 32 + sub] = (_Float16)wp;
    wb[(size_t)v * 32 + 16 + sub] = (_Float16)0.f;              // zero pad 16..31
}

// ---------------------------------------------------------------------------
// gemm1 (R12): h2 = relu(wt16 @ M11 + b1) via MFMA f16, K=32 (single step).
// BM=BN=64, 4 waves 2x2 (wave 32x32) — gemm_tail fragment layout + row clamp.
// ---------------------------------------------------------------------------
__launch_bounds__(256)
__global__ void gemm1_kernel(const _Float16* __restrict__ wt16,
                             const _Float16* __restrict__ m11t,
                             const float* __restrict__ bias,
                             _Float16* __restrict__ h2) {
    __shared__ _Float16 As[64][40];
    __shared__ _Float16 Bs[64][40];
    int side = blockIdx.z;
    const _Float16* Ab = wt16 + (size_t)side * kN * 32;
    _Float16* Ob = h2 + (size_t)side * kN * kGH;
    int tid = threadIdx.x;
    int wave = tid >> 6, lane = tid & 63;
    int quad = lane >> 4, r = lane & 15;
    int wm = wave >> 1, wn = wave & 1;
    int row0 = blockIdx.x * 64, col0 = blockIdx.y * 64;

    {   // stage: 64 rows x 32 each for A and Bt (256 threads, one pass each)
        int row = tid >> 2, seg = (tid & 3) * 8;
        int gr = row0 + row;
        if (gr >= kN) gr = kN - 1;
        *(half8v*)&As[row][seg] = *(const half8v*)(Ab + (size_t)gr * 32 + seg);
        *(half8v*)&Bs[row][seg] = *(const half8v*)(m11t + (size_t)(col0 + row) * 32 + seg);
    }
    __syncthreads();

    floatx4 acc[2][2];
    #pragma unroll
    for (int i = 0; i < 2; i++)
        #pragma unroll
        for (int j = 0; j < 2; j++) acc[i][j] = (floatx4){0.f, 0.f, 0.f, 0.f};
    half8v af[2], bf[2];
    #pragma unroll
    for (int mt = 0; mt < 2; mt++)
        af[mt] = *(const half8v*)&As[wm * 32 + mt * 16 + r][quad * 8];
    #pragma unroll
    for (int nt = 0; nt < 2; nt++)
        bf[nt] = *(const half8v*)&Bs[wn * 32 + nt * 16 + r][quad * 8];
    #pragma unroll
    for (int mt = 0; mt < 2; mt++)
        #pragma unroll
        for (int nt = 0; nt < 2; nt++)
            acc[mt][nt] = __builtin_amdgcn_mfma_f32_16x16x32_f16(af[mt], bf[nt],
                                                                 acc[mt][nt], 0, 0, 0);

    #pragma unroll
    for (int mt = 0; mt < 2; mt++) {
        #pragma unroll
        for (int i = 0; i < 4; i++) {
            int grow = row0 + wm * 32 + mt * 16 + quad * 4 + i;
            if (grow >= kN) continue;
            #pragma unroll
            for (int nt = 0; nt < 2; nt++) {
                int gcol = col0 + wn * 32 + nt * 16 + r;
                float v = acc[mt][nt][i] + bias[gcol];
                Ob[(size_t)grow * kGH + gcol] = (_Float16)fmaxf(v, 0.f);
            }
        }
    }
}

// ---------------------------------------------------------------------------
// Conv2 GEMM via MFMA f16, LDS-tiled: hs = fp8(HS_SCALE * dinv ⊙ (h2 @ W2))
// BM=128, BN=128, BK=64. 4 waves (2x2); wave = 64x64.
// ---------------------------------------------------------------------------
__launch_bounds__(256)
__global__ void gemm2_mfma_kernel(const _Float16* __restrict__ A,
                                  const _Float16* __restrict__ Bt,
                                  const float* __restrict__ dinv,
                                  unsigned char* __restrict__ C) {
    __shared__ _Float16 As[128][72];
    __shared__ _Float16 Bs[128][72];

    int side = blockIdx.z;
    const _Float16* Ab = A + (size_t)side * kN * kGH;
    const float* db = dinv + (size_t)side * kN;
    unsigned char* Cb = C + (size_t)side * kN * kGH;

    int tid = threadIdx.x;
    int wave = tid >> 6, lane = tid & 63;
    int quad = lane >> 4, r = lane & 15;
    int wm = wave >> 1, wn = wave & 1;
    int row0 = blockIdx.x * 128;
    int col0 = blockIdx.y * 128;

    floatx4 acc[4][4];
    #pragma unroll
    for (int i = 0; i < 4; i++)
        #pragma unroll
        for (int j = 0; j < 4; j++) acc[i][j] = (floatx4){0.f, 0.f, 0.f, 0.f};

    for (int k0 = 0; k0 < kGH; k0 += 64) {
        #pragma unroll
        for (int u = 0; u < 4; u++) {
            int idx = tid + u * 256;
            int row = idx >> 3;
            int seg = (idx & 7) * 8;
            int gr = row0 + row;
            if (gr >= kN) gr = kN - 1;
            *(half8v*)&As[row][seg] = *(const half8v*)(Ab + (size_t)gr * kGH + k0 + seg);
            *(half8v*)&Bs[row][seg] = *(const half8v*)(Bt + (size_t)(col0 + row) * kGH + k0 + seg);
        }
        __syncthreads();
        #pragma unroll
        for (int ks = 0; ks < 2; ks++) {
            half8v af[4], bf[4];
            #pragma unroll
            for (int mt = 0; mt < 4; mt++)
                af[mt] = *(const half8v*)&As[wm * 64 + mt * 16 + r][ks * 32 + quad * 8];
            #pragma unroll
            for (int nt = 0; nt < 4; nt++)
                bf[nt] = *(const half8v*)&Bs[wn * 64 + nt * 16 + r][ks * 32 + quad * 8];
            #pragma unroll
            for (int mt = 0; mt < 4; mt++)
                #pragma unroll
                for (int nt = 0; nt < 4; nt++)
                    acc[mt][nt] = __builtin_amdgcn_mfma_f32_16x16x32_f16(af[mt], bf[nt],
                                                                         acc[mt][nt], 0, 0, 0);
        }
        __syncthreads();
    }

    #pragma unroll
    for (int mt = 0; mt < 4; mt++) {
        #pragma unroll
        for (int i = 0; i < 4; i++) {
            int grow = row0 + wm * 64 + mt * 16 + quad * 4 + i;
            if (grow >= kN) continue;
            float rsq = db[grow] * HS_SCALE;
            #pragma unroll
            for (int nt = 0; nt < 4; nt++) {
                int gcol = col0 + wn * 64 + nt * 16 + r;
                float q = acc[mt][nt][i] * rsq;
                Cb[(size_t)grow * kGH + gcol] =
                    (unsigned char)__builtin_amdgcn_cvt_pk_fp8_f32(q, q, 0, false);
            }
        }
    }
}

// ---------------------------------------------------------------------------
// Unified tail GEMM via MFMA f16 (fp32 accum): C = [relu](A @ B + bias)
// ---------------------------------------------------------------------------
__launch_bounds__(256)
__global__ void gemm_tail_kernel(const _Float16* __restrict__ A,
                                 const _Float16* __restrict__ Bt,
                                 void* __restrict__ Cout,
                                 int N, int K,
                                 const float* __restrict__ bias,
                                 int relu, int f32out) {
    __shared__ _Float16 As[64][72];
    __shared__ _Float16 Bs[64][72];
    int tid = threadIdx.x;
    int wave = tid >> 6, lane = tid & 63;
    int quad = lane >> 4, r = lane & 15;
    int wm = wave >> 1, wn = wave & 1;
    int row0 = blockIdx.x * 64, col0 = blockIdx.y * 64;

    floatx4 acc[2][2];
    #pragma unroll
    for (int i = 0; i < 2; i++)
        #pragma unroll
        for (int j = 0; j < 2; j++) acc[i][j] = (floatx4){0.f, 0.f, 0.f, 0.f};

    for (int k0 = 0; k0 < K; k0 += 64) {
        #pragma unroll
        for (int u = 0; u < 2; u++) {
            int idx = tid + u * 256;           // 0..511
            int row = idx >> 3;                // 0..63
            int seg = (idx & 7) * 8;           // 0..56
            *(half8v*)&As[row][seg] = *(const half8v*)(A + (size_t)(row0 + row) * K + k0 + seg);
            *(half8v*)&Bs[row][seg] = *(const half8v*)(Bt + (size_t)(col0 + row) * K + k0 + seg);
        }
        __syncthreads();
        #pragma unroll
        for (int ks = 0; ks < 2; ks++) {
            half8v af[2], bf[2];
            #pragma unroll
            for (int mt = 0; mt < 2; mt++)
                af[mt] = *(const half8v*)&As[wm * 32 + mt * 16 + r][ks * 32 + quad * 8];
            #pragma unroll
            for (int nt = 0; nt < 2; nt++)
                bf[nt] = *(const half8v*)&Bs[wn * 32 + nt * 16 + r][ks * 32 + quad * 8];
            #pragma unroll
            for (int mt = 0; mt < 2; mt++)
                #pragma unroll
                for (int nt = 0; nt < 2; nt++)
                    acc[mt][nt] = __builtin_amdgcn_mfma_f32_16x16x32_f16(af[mt], bf[nt],
                                                                         acc[mt][nt], 0, 0, 0);
        }
        __syncthreads();
    }

    #pragma unroll
    for (int mt = 0; mt < 2; mt++) {
        #pragma unroll
        for (int i = 0; i < 4; i++) {
            int grow = row0 + wm * 32 + mt * 16 + quad * 4 + i;
            #pragma unroll
            for (int nt = 0; nt < 2; nt++) {
                int gcol = col0 + wn * 32 + nt * 16 + r;
                float v = acc[mt][nt][i] + bias[gcol];
                if (relu) v = fmaxf(v, 0.f);
                if (f32out) ((float*)Cout)[(size_t)grow * N + gcol] = v;
                else ((_Float16*)Cout)[(size_t)grow * N + gcol] = (_Float16)v;
            }
        }
    }
}

// ---------------------------------------------------------------------------
// Conv2 aggregate (R7-exact, proven 60.5us): one wave per node, no barriers.
// h4[v] = relu(dinv[v]*(hs[v] + sum_s hs[s])/HS_SCALE + b2); NT fp16 store.
// ---------------------------------------------------------------------------
__global__ void aggregate2_kernel(const unsigned char* __restrict__ hs, const float* __restrict__ dinv,
                                  const int* __restrict__ counts,
                                  const unsigned short* __restrict__ col_ell,
                                  const float* __restrict__ bias, _Float16* __restrict__ out) {
    int side = blockIdx.y;
    const unsigned char* hb = hs + (size_t)side * kN * kGH;
    const float* dv_ = dinv + side * kN;
    const int* deg = counts + side * kN;
    const unsigned short* ci = col_ell + (size_t)side * kN * kMD;
    _Float16* ob = out + (size_t)side * kN * kGH;

    int wave = threadIdx.x >> 6;
    int lane = threadIdx.x & 63;
    int v = blockIdx.x * 4 + wave;
    if (v >= kN) return;
    int c = lane * 4;
    float4 bia = *(const float4*)(bias + c);
    float dv = dv_[v];
    float a0 = 0.f, a1 = 0.f, a2 = 0.f, a3 = 0.f;
    acc_fp8x4(*(const unsigned int*)(hb + (size_t)v * kGH + c), a0, a1, a2, a3);  // self-loop
    int cnt = min(deg[v], kMD);
    int idxl = (lane < cnt) ? (int)ci[(size_t)v * kMD + lane] : 0;
    int j = 0;
    for (; j + 16 <= cnt; j += 16) {
        unsigned int w[16];
        #pragma unroll
        for (int u = 0; u < 16; u++)
            w[u] = *(const unsigned int*)(hb + (size_t)__shfl(idxl, j + u) * kGH + c);
        #pragma unroll
        for (int u = 0; u < 16; u++) acc_fp8x4(w[u], a0, a1, a2, a3);
    }
    for (; j + 8 <= cnt; j += 8) {
        unsigned int w[8];
        #pragma unroll
        for (int u = 0; u < 8; u++)
            w[u] = *(const unsigned int*)(hb + (size_t)__shfl(idxl, j + u) * kGH + c);
        #pragma unroll
        for (int u = 0; u < 8; u++) acc_fp8x4(w[u], a0, a1, a2, a3);
    }
    for (; j < cnt; j++)
        acc_fp8x4(*(const unsigned int*)(hb + (size_t)__shfl(idxl, j) * kGH + c),
                  a0, a1, a2, a3);
    float f = dv * HS_INV;
    half4v o;
    o[0] = (_Float16)fmaxf(f * a0 + bia.x, 0.f);
    o[1] = (_Float16)fmaxf(f * a1 + bia.y, 0.f);
    o[2] = (_Float16)fmaxf(f * a2 + bia.z, 0.f);
    o[3] = (_Float16)fmaxf(f * a3 + bia.w, 0.f);
    __builtin_nontemporal_store(o, (half4v*)(ob + (size_t)v * kGH + c));
}

// ---------------------------------------------------------------------------
// Fast parallel mean-pool (R12): grid (kG,2), 4 waves; wave w covers rows
// start+w+4k with half4v loads (coalesced 512B/row); one LDS reduce.
// ---------------------------------------------------------------------------
__global__ void poolfast_kernel(const _Float16* __restrict__ h,
                                const int* __restrict__ gstart,
                                _Float16* __restrict__ pooled16) {
    int side = blockIdx.y;
    int g = blockIdx.x;
    const _Float16* hb = h + (size_t)side * kN * kGH;
    int start = gstart[side * (kG + 1) + g];
    int end   = gstart[side * (kG + 1) + g + 1];
    int wave = threadIdx.x >> 6, lane = threadIdx.x & 63;
    int c = lane * 4;
    float a0 = 0.f, a1 = 0.f, a2 = 0.f, a3 = 0.f;
    for (int v = start + wave; v < end; v += 4) {
        half4v hv = *(const half4v*)(hb + (size_t)v * kGH + c);
        a0 += (float)hv[0]; a1 += (float)hv[1];
        a2 += (float)hv[2]; a3 += (float)hv[3];
    }
    __shared__ float ps[4][256];
    *(float4*)&ps[wave][c] = make_float4(a0, a1, a2, a3);
    __syncthreads();
    int t = threadIdx.x;
    float s = ps[0][t] + ps[1][t] + ps[2][t] + ps[3][t];
    float inv = 1.0f / fmaxf((float)(end - start), 1.0f);
    pooled16[(size_t)(side * kG + g) * kGH + t] = (_Float16)(s * inv);
}

// entity gather: e16[r][k] = fp16(relu(emb[ent[r]][k])), r in [0,2G)
__global__ void egather_kernel(const float* __restrict__ emb,
                               const int* __restrict__ ent1, const int* __restrict__ ent2,
                               _Float16* __restrict__ e16) {
    int rr = blockIdx.x;
    int idx = (rr < kG) ? ent1[rr] : ent2[rr - kG];
    int k = threadIdx.x;   // 128
    e16[(size_t)rr * kEMB + k] = (_Float16)fmaxf(emb[(size_t)idx * kEMB + k], 0.f);
}

// egs prep: egs16[g][k] = fp16(relu(eg1[g][k] + eg2[g][k]))
__global__ void egsprep_kernel(const _Float16* __restrict__ gfc16,
                               const _Float16* __restrict__ ento16,
                               _Float16* __restrict__ egs16) {
    int idx = blockIdx.x * 256 + threadIdx.x;   // 0..65535
    int g = idx >> 6;                            // 0..1023
    int k8 = (idx & 63) * 8;                     // 0..504
    const _Float16* src = (k8 < kGH) ? gfc16 : ento16;
    int kk = (k8 < kGH) ? k8 : k8 - kGH;
    half8v a = *(const half8v*)(src + (size_t)g * kGH + kk);
    half8v b = *(const half8v*)(src + (size_t)(g + kG) * kGH + kk);
    half8v o;
    #pragma unroll
    for (int u = 0; u < 8; u++) o[u] = (_Float16)fmaxf((float)a[u] + (float)b[u], 0.f);
    *(half8v*)(egs16 + (size_t)g * kHID + k8) = o;
}

// ---------------------------------------------------------------------------
// Host launch
// ---------------------------------------------------------------------------
static inline char* carve(char*& p, size_t bytes) {
    char* r = p;
    p += (bytes + 255) & ~(size_t)255;
    return r;
}

extern "C" void kernel_launch(void* const* d_in, const int* in_sizes, int n_in,
                              void* d_out, int out_size, void* d_ws, size_t ws_size,
                              hipStream_t stream) {
    const int*   x1       = (const int*)d_in[0];
    const int*   ei1      = (const int*)d_in[1];
    const int*   ent1     = (const int*)d_in[2];
    const int*   batch1   = (const int*)d_in[3];
    const int*   x2       = (const int*)d_in[4];
    const int*   ei2      = (const int*)d_in[5];
    const int*   ent2     = (const int*)d_in[6];
    const int*   batch2   = (const int*)d_in[7];
    const float* atom_emb = (const float*)d_in[8];
    const float* gW1      = (const float*)d_in[9];
    const float* gb1      = (const float*)d_in[10];
    const float* gW2      = (const float*)d_in[11];
    const float* gb2      = (const float*)d_in[12];
    const float* fcW      = (const float*)d_in[13];
    const float* fcb      = (const float*)d_in[14];
    const float* ent_emb  = (const float*)d_in[15];
    const float* eW1      = (const float*)d_in[16];
    const float* eb1      = (const float*)d_in[17];
    const float* eW2      = (const float*)d_in[18];
    const float* eb2      = (const float*)d_in[19];
    const float* dW1      = (const float*)d_in[20];
    const float* db1      = (const float*)d_in[21];
    const float* dW2      = (const float*)d_in[22];
    const float* db2      = (const float*)d_in[23];
    const float* dW3      = (const float*)d_in[24];
    const float* db3      = (const float*)d_in[25];
    float* out = (float*)d_out;

    // Workspace carve (no zeroed spans needed — binp3 writes all counts).
    char* p = (char*)d_ws;
    _Float16* h2_h   = (_Float16*)carve(p, (size_t)2 * kN * kGH * 2);  // h2, later h4
    unsigned char* hs8 = (unsigned char*)carve(p, (size_t)2 * kN * kGH); // fp8 hs
    unsigned short* col_ell = (unsigned short*)carve(p, (size_t)2 * kN * kMD * 2);
    unsigned int* ebuf = (unsigned int*)carve(p, (size_t)2 * kE * 4);
    int*   poff    = (int*)  carve(p, (size_t)2 * kNBKT * 256 * 4);
    int*   btot    = (int*)  carve(p, (size_t)2 * kNBKT * 4);
    int*   bbase   = (int*)  carve(p, (size_t)2 * (kNBKT + 1) * 4);
    int*   counts  = (int*)  carve(p, (size_t)2 * kN * 4);
    float* dinv    = (float*)carve(p, (size_t)2 * kN * 4);
    int2*  xd      = (int2*) carve(p, (size_t)2 * kN * 8);
    int*   gstart  = (int*)  carve(p, (size_t)2 * (kG + 1) * 4);
    float* M11     = (float*)carve(p, 11 * kGH * 4);
    _Float16* w2t  = (_Float16*)carve(p, (size_t)kGH * kGH * 2);
    _Float16* m11t = (_Float16*)carve(p, (size_t)256 * 32 * 2);
    _Float16* wt16 = (_Float16*)carve(p, (size_t)2 * kN * 32 * 2);
    // fp16 tail buffers
    _Float16* pooled16 = (_Float16*)carve(p, (size_t)2 * kG * kGH * 2);
    _Float16* gfc16    = (_Float16*)carve(p, (size_t)2 * kG * kGH * 2);
    _Float16* e16      = (_Float16*)carve(p, (size_t)2 * kG * kEMB * 2);
    _Float16* etmp16   = (_Float16*)carve(p, (size_t)2 * kG * kEH * 2);
    _Float16* ento16   = (_Float16*)carve(p, (size_t)2 * kG * kEH * 2);
    _Float16* egs16    = (_Float16*)carve(p, (size_t)kG * kHID * 2);
    _Float16* dh1_16   = (_Float16*)carve(p, (size_t)kG * kHID * 2);
    _Float16* dh2_16   = (_Float16*)carve(p, (size_t)kG * kHID * 2);
    // fp16 transposed tail weights
    _Float16* dW1t = (_Float16*)carve(p, (size_t)kHID * kHID * 2);
    _Float16* dW2t = (_Float16*)carve(p, (size_t)kHID * kHID * 2);
    _Float16* dW3t = (_Float16*)carve(p, (size_t)kOUT * kHID * 2);
    _Float16* fcWt = (_Float16*)carve(p, (size_t)kGH * kGH * 2);
    _Float16* eW1t = (_Float16*)carve(p, (size_t)kEH * kEMB * 2);
    _Float16* eW2t = (_Float16*)carve(p, (size_t)kEH * kEH * 2);

    // --- Graph structure via LDS binning (zero global atomics) ---
    prep_kernel<<<299, 256, 0, stream>>>(atom_emb, gW1, gW2, M11, w2t, m11t);
    wtrans_kernel<<<2944, 256, 0, stream>>>(dW1, dW2, dW3, fcW, eW1, eW2,
                                            dW1t, dW2t, dW3t, fcWt, eW1t, eW2t);
    gbounds_kernel<<<dim3((kG + 256) / 256, 2), 256, 0, stream>>>(batch1, batch2, gstart);
    binp1_kernel<<<dim3(kPBLK, 2), 256, 0, stream>>>(ei1, ei2, poff);
    scanA_kernel<<<dim3(kNBKT, 2), 256, 0, stream>>>(poff, btot);
    scanB_kernel<<<2, 256, 0, stream>>>(btot, bbase);
    binp2_kernel<<<dim3(kPBLK, 2), 256, 0, stream>>>(ei1, ei2, poff, bbase, ebuf);
    binp3_kernel<<<dim3(kNBKT, 2), 256, 0, stream>>>(ebuf, bbase, col_ell, counts,
                                                     dinv, xd, x1, x2);
    // --- Conv1 = histogram (gather) + MFMA GEMM [100K,32]@[32,256] ---
    conv1_wt_kernel<<<dim3(kN / 16, 2), 256, 0, stream>>>(xd, counts, col_ell, wt16);
    gemm1_kernel<<<dim3((kN + 63) / 64, kGH / 64, 2), 256, 0, stream>>>(wt16, m11t,
                                                                        gb1, h2_h);
    // --- Conv2 GEMM (MFMA f16): hs8 = fp8(128 * dinv ⊙ (h2 @ W2)) ---
    gemm2_mfma_kernel<<<dim3((kN + 127) / 128, kGH / 128, 2), 256, 0, stream>>>(h2_h, w2t,
                                                                                dinv, hs8);
    // --- Conv2 aggregate (R7-proven) -> h4 (reuses h2 buffer) ---
    aggregate2_kernel<<<dim3((kN + 3) / 4, 2), 256, 0, stream>>>(hs8, dinv, counts, col_ell,
                                                                 gb2, h2_h);
    // --- Fast parallel mean-pool -> pooled16 ---
    poolfast_kernel<<<dim3(kG, 2), 256, 0, stream>>>(h2_h, gstart, pooled16);
    // --- Entity gather (fp16) ---
    egather_kernel<<<2 * kG, 128, 0, stream>>>(ent_emb, ent1, ent2, e16);

    // --- Tail GEMMs, all fp16 MFMA (fp32 accum) ---
    gemm_tail_kernel<<<dim3(2 * kG / 64, kGH / 64), 256, 0, stream>>>(
        pooled16, fcWt, gfc16, kGH, kGH, fcb, 0, 0);
    gemm_tail_kernel<<<dim3(2 * kG / 64, kEH / 64), 256, 0, stream>>>(
        e16, eW1t, etmp16, kEH, kEMB, eb1, 1, 0);
    gemm_tail_kernel<<<dim3(2 * kG / 64, kEH / 64), 256, 0, stream>>>(
        etmp16, eW2t, ento16, kEH, kEH, eb2, 1, 0);
    egsprep_kernel<<<kG * kHID / 8 / 256, 256, 0, stream>>>(gfc16, ento16, egs16);
    gemm_tail_kernel<<<dim3(kG / 64, kHID / 64), 256, 0, stream>>>(
        egs16, dW1t, dh1_16, kHID, kHID, db1, 1, 0);
    gemm_tail_kernel<<<dim3(kG / 64, kHID / 64), 256, 0, stream>>>(
        dh1_16, dW2t, dh2_16, kHID, kHID, db2, 1, 0);
    gemm_tail_kernel<<<dim3(kG / 64, kOUT / 64), 256, 0, stream>>>(
        dh2_16, dW3t, out, kOUT, kHID, db3, 0, 1);
}

// Round 13
// 395.051 us; speedup vs baseline: 1.1573x; 1.0077x over previous
//
#include <hip/hip_runtime.h>
#include <hip/hip_fp16.h>

// Problem constants
static constexpr int kN = 50000;      // nodes per side
static constexpr int kE = 800000;     // edges per side
static constexpr int kG = 1024;       // graphs per batch
static constexpr int kEMB = 128;
static constexpr int kGH = 256;
static constexpr int kEH = 256;
static constexpr int kOUT = 128;
static constexpr int kHID = 512;
static constexpr int kNB = (kN + 255) / 256;   // 196 chunks per side
static constexpr int kMD = 64;        // ELL stride; deg ~ Poisson(16), P(deg>=64)~e^-125
static constexpr int kNBKT = 196;     // dst buckets of 256 nodes (50000 -> 196)
static constexpr int kEPB = 3125;     // edges per bin block; 256 blocks exactly
static constexpr int kPBLK = 256;     // bin blocks per side (256*3125 = 800000)

typedef __attribute__((ext_vector_type(8))) _Float16 half8v;
typedef __attribute__((ext_vector_type(4))) _Float16 half4v;
typedef __attribute__((ext_vector_type(4))) float floatx4;
typedef __attribute__((ext_vector_type(2))) float floatx2;

// NOTE (R6): cross-XCD plain-data handoff through grid.sync() gave stale reads.
// NOTE (R7/R12): device atomics memory-side; floor is OP-COUNT ~21/ns.
// (R2) fp8 hs: 659->616us. (R3) conv1 DPP groups ->596us. (R4) NEUTRAL.
// (R5) ELL fusion regressed rank (atomics+random stores share mem-op pipe).
// (R6) LDS bucket binning, zero global atomics: 585->523us.
// (R7) fp16-MFMA unified tail: 523->439us. aggregate2 60.5us = proven gather
// floor (1 wave/node, no barriers). (R8-R11) agg+pool fusion arc regressed;
// reverted. (R12) conv1 -> conv1_wt + gemm1 MFMA split; R7 aggregate restored;
// 422.6->398.1us; aggregate2 back at floor (62us, HBM 44%).
// This revision (R13): fuse gemm1 INTO gemm2 — per k0-step, compute the h2
// A-tile on the fly with swapped-operand mfma(bf_m11, af_wt) (transposed
// fragment -> 4 k-consecutive values/lane -> single b64 LDS write, bias+relu
// +fp16 round in fp32 = bit-identical to gemm1). Kills h2 entirely:
// -51MB write, -102MB read (A-tiles read x2 col-blocks), -1 dispatch.

// fp8 fixed scale: |hs| <~ 0.2 typ; x128 keeps values in e4m3 normal range.
#define HS_SCALE 128.0f
#define HS_INV   (1.0f / 128.0f)

__device__ inline void acc_fp8x4(unsigned int w, float& a0, float& a1, float& a2, float& a3) {
    floatx2 lo = __builtin_amdgcn_cvt_pk_f32_fp8(w, false);
    floatx2 hi = __builtin_amdgcn_cvt_pk_f32_fp8(w, true);
    a0 += lo[0]; a1 += lo[1]; a2 += hi[0]; a3 += hi[1];
}

// 16-lane group sum via DPP row_ror rotations (1,2,4,8).
__device__ inline float grp16_reduce(float v) {
    int x;
    x = __builtin_amdgcn_update_dpp(0, __float_as_int(v), 0x121, 0xF, 0xF, true);
    v += __int_as_float(x);
    x = __builtin_amdgcn_update_dpp(0, __float_as_int(v), 0x122, 0xF, 0xF, true);
    v += __int_as_float(x);
    x = __builtin_amdgcn_update_dpp(0, __float_as_int(v), 0x124, 0xF, 0xF, true);
    v += __int_as_float(x);
    x = __builtin_amdgcn_update_dpp(0, __float_as_int(v), 0x128, 0xF, 0xF, true);
    v += __int_as_float(x);
    return v;
}

// ---------------------------------------------------------------------------
// prep: w2t = fp16(gW2^T) (blocks 0..255), M11 = atom_emb@gW1 (blocks 256..266),
// m11t = fp16(M11^T padded to K=32) (blocks 267..298).
// ---------------------------------------------------------------------------
__global__ void prep_kernel(const float* __restrict__ atom_emb, const float* __restrict__ gW1,
                            const float* __restrict__ gW2,
                            float* __restrict__ M11, _Float16* __restrict__ w2t,
                            _Float16* __restrict__ m11t) {
    int i = blockIdx.x * 256 + threadIdx.x;
    if (blockIdx.x < 256) {
        int k = i >> 8, n = i & 255;
        w2t[(size_t)n * kGH + k] = (_Float16)gW2[(size_t)k * kGH + n];
    } else {
        int j = i - 65536;
        if (j < 11 * kGH) {
            int r = j >> 8, c = j & 255;
            float s = 0.f;
            for (int k = 0; k < kEMB; k++) s += atom_emb[r * kEMB + k] * gW1[k * kGH + c];
            M11[j] = s;
        } else if (j < 11 * kGH + 256 * 32) {
            int j2 = j - 11 * kGH;
            int n = j2 >> 5, k = j2 & 31;     // m11t[n][k] = M11[k][n], 0 for k>=11
            float s = 0.f;
            if (k < 11)
                for (int p = 0; p < kEMB; p++) s += atom_emb[k * kEMB + p] * gW1[p * kGH + n];
            m11t[j2] = (_Float16)s;
        }
    }
}

// ---------------------------------------------------------------------------
// wtrans: all tail weights -> fp16 transposed ([N][K] from [K][N]).
// ---------------------------------------------------------------------------
__global__ void wtrans_kernel(const float* __restrict__ dW1, const float* __restrict__ dW2,
                              const float* __restrict__ dW3, const float* __restrict__ fcW,
                              const float* __restrict__ eW1, const float* __restrict__ eW2,
                              _Float16* __restrict__ dW1t, _Float16* __restrict__ dW2t,
                              _Float16* __restrict__ dW3t, _Float16* __restrict__ fcWt,
                              _Float16* __restrict__ eW1t, _Float16* __restrict__ eW2t) {
    int b = blockIdx.x;
    const float* src; _Float16* dst; int K, N, j0;
    if (b < 1024)      { src = dW1; dst = dW1t; K = 512; N = 512; j0 = b * 256; }
    else if (b < 2048) { src = dW2; dst = dW2t; K = 512; N = 512; j0 = (b - 1024) * 256; }
    else if (b < 2304) { src = dW3; dst = dW3t; K = 512; N = 128; j0 = (b - 2048) * 256; }
    else if (b < 2560) { src = fcW; dst = fcWt; K = 256; N = 256; j0 = (b - 2304) * 256; }
    else if (b < 2688) { src = eW1; dst = eW1t; K = 128; N = 256; j0 = (b - 2560) * 256; }
    else               { src = eW2; dst = eW2t; K = 256; N = 256; j0 = (b - 2688) * 256; }
    int j = j0 + threadIdx.x;            // dst linear: n*K + k
    int n = j / K, k = j - n * K;
    dst[j] = (_Float16)src[(size_t)k * N + n];
}

// ---------------------------------------------------------------------------
// gbounds: gstart[side][g] = lower_bound(batch, g), parallel per thread.
// ---------------------------------------------------------------------------
__global__ void gbounds_kernel(const int* __restrict__ batch1, const int* __restrict__ batch2,
                               int* __restrict__ gstart) {
    int side = blockIdx.y;
    const int* batch = side ? batch2 : batch1;
    int g = blockIdx.x * 256 + threadIdx.x;
    if (g > kG) return;
    int lo = 0, hi = kN;
    while (lo < hi) { int mid = (lo + hi) >> 1; if (batch[mid] < g) lo = mid + 1; else hi = mid; }
    gstart[side * (kG + 1) + g] = lo;
}

// ---------------------------------------------------------------------------
// binp1: per-block LDS histogram over 196 dst-buckets.
// ---------------------------------------------------------------------------
__global__ void binp1_kernel(const int* __restrict__ ei1, const int* __restrict__ ei2,
                             int* __restrict__ poff) {
    int side = blockIdx.y;
    const int* dst = (side ? ei2 : ei1) + kE;
    __shared__ int hist[kNBKT];
    int t = threadIdx.x;
    if (t < kNBKT) hist[t] = 0;
    __syncthreads();
    int base = blockIdx.x * kEPB;
    for (int j = t; j < kEPB; j += 256)
        atomicAdd(&hist[dst[base + j] >> 8], 1);
    __syncthreads();
    if (t < kNBKT) poff[((side * kNBKT + t) << 8) | blockIdx.x] = hist[t];
}

// scanA: per (side,bucket) exclusive scan over the 256 block counts.
__global__ void scanA_kernel(int* __restrict__ poff, int* __restrict__ btot) {
    int b = blockIdx.x, side = blockIdx.y, t = threadIdx.x;
    __shared__ int s[256];
    int idx = ((side * kNBKT + b) << 8) | t;
    int v = poff[idx];
    s[t] = v;
    __syncthreads();
    for (int o = 1; o < 256; o <<= 1) {
        int u = (t >= o) ? s[t - o] : 0;
        __syncthreads();
        s[t] += u;
        __syncthreads();
    }
    poff[idx] = s[t] - v;
    if (t == 255) btot[side * kNBKT + b] = s[255];
}

// scanB: exclusive scan of bucket totals -> bbase.
__global__ void scanB_kernel(const int* __restrict__ btot, int* __restrict__ bbase) {
    int side = blockIdx.x, t = threadIdx.x;
    __shared__ int s[256];
    int v = (t < kNBKT) ? btot[side * kNBKT + t] : 0;
    s[t] = v;
    __syncthreads();
    for (int o = 1; o < 256; o <<= 1) {
        int u = (t >= o) ? s[t - o] : 0;
        __syncthreads();
        s[t] += u;
        __syncthreads();
    }
    if (t < kNBKT) bbase[side * (kNBKT + 1) + t] = s[t] - v;
    if (t == 255) bbase[side * (kNBKT + 1) + kNBKT] = s[255];
}

// ---------------------------------------------------------------------------
// binp2: block-local LDS bucket-sort, coalesced bucket-major write-out.
// ---------------------------------------------------------------------------
__launch_bounds__(256)
__global__ void binp2_kernel(const int* __restrict__ ei1, const int* __restrict__ ei2,
                             const int* __restrict__ poff, const int* __restrict__ bbase,
                             unsigned int* __restrict__ ebuf) {
    int side = blockIdx.y, blk = blockIdx.x, t = threadIdx.x;
    const int* ei = side ? ei2 : ei1;
    __shared__ int hist[kNBKT], lb[kNBKT], gb[kNBKT], scanbuf[256];
    __shared__ unsigned int sorted[kEPB];
    if (t < kNBKT) hist[t] = 0;
    __syncthreads();
    int base = blk * kEPB;
    for (int j = t; j < kEPB; j += 256)
        atomicAdd(&hist[ei[kE + base + j] >> 8], 1);
    __syncthreads();
    int v = (t < kNBKT) ? hist[t] : 0;
    scanbuf[t] = v;
    __syncthreads();
    for (int o = 1; o < 256; o <<= 1) {
        int u = (t >= o) ? scanbuf[t - o] : 0;
        __syncthreads();
        scanbuf[t] += u;
        __syncthreads();
    }
    if (t < kNBKT) {
        lb[t] = scanbuf[t] - v;
        gb[t] = bbase[side * (kNBKT + 1) + t] + poff[((side * kNBKT + t) << 8) | blk];
        hist[t] = 0;
    }
    __syncthreads();
    for (int j = t; j < kEPB; j += 256) {
        int s_ = ei[base + j];
        int d  = ei[kE + base + j];
        int b  = d >> 8;
        int r  = atomicAdd(&hist[b], 1);
        sorted[lb[b] + r] = ((unsigned int)d << 16) | (unsigned int)s_;
    }
    __syncthreads();
    for (int j = t; j < kEPB; j += 256) {
        unsigned int val = sorted[j];
        int b = val >> 24;
        int gpos = gb[b] + (j - lb[b]);
        ebuf[(size_t)side * kE + gpos] = val;
    }
}

// ---------------------------------------------------------------------------
// binp3: one block per bucket; LDS slot counters; col_ell stores in a 32KB
// window. Fused epilogue: degrees->counts, dinv, xd.
// ---------------------------------------------------------------------------
__global__ void binp3_kernel(const unsigned int* __restrict__ ebuf, const int* __restrict__ bbase,
                             unsigned short* __restrict__ col_ell, int* __restrict__ counts,
                             float* __restrict__ dinv, int2* __restrict__ xd,
                             const int* __restrict__ x1, const int* __restrict__ x2) {
    int b = blockIdx.x, side = blockIdx.y, t = threadIdx.x;
    __shared__ int cnt[256];
    cnt[t] = 0;
    __syncthreads();
    int start = bbase[side * (kNBKT + 1) + b];
    int end   = bbase[side * (kNBKT + 1) + b + 1];
    for (int k = start + t; k < end; k += 256) {
        unsigned int v = ebuf[(size_t)side * kE + k];
        int d8 = (v >> 16) & 255;
        int slot = atomicAdd(&cnt[d8], 1);
        if (slot > kMD - 1) slot = kMD - 1;
        int node = (b << 8) | d8;
        col_ell[((size_t)side * kN + node) * kMD + slot] = (unsigned short)(v & 0xFFFFu);
    }
    __syncthreads();
    int node = (b << 8) | t;
    if (node < kN) {
        int d = cnt[t];
        counts[side * kN + node] = d;
        float dv = rsqrtf((float)(d + 1));           // +1 self-loop
        dinv[side * kN + node] = dv;
        const int* x = side ? x2 : x1;
        xd[side * kN + node] = make_int2(x[node], __float_as_int(dv));
    }
}

// ---------------------------------------------------------------------------
// Conv1 histogram only: 16-lane groups, DPP reduce, emit wt16[v][32] fp16:
// wt'[t] = dv*wt[t] + dv^2*delta(x[v]=t) for t<11, 0 else.
// ---------------------------------------------------------------------------
__global__ void conv1_wt_kernel(const int2* __restrict__ xd,
                                const int* __restrict__ counts,
                                const unsigned short* __restrict__ col_ell,
                                _Float16* __restrict__ wt16) {
    int side = blockIdx.y;
    const int2* xdb = xd + (size_t)side * kN;
    const int* deg = counts + side * kN;
    const unsigned short* ci = col_ell + (size_t)side * kN * kMD;
    _Float16* wb = wt16 + (size_t)side * kN * 32;

    int tid = threadIdx.x;
    int sub = tid & 15;
    int v = blockIdx.x * 16 + (tid >> 4);   // exact: 3125*16 = 50000

    int cnt = min(deg[v], kMD);
    const unsigned short* cv = ci + (size_t)v * kMD;
    float wt[11];
    #pragma unroll
    for (int t = 0; t < 11; t++) wt[t] = 0.f;
    for (int base = 0; base < cnt; base += 16) {
        int e = base + sub;
        int xs = 15; float ds = 0.f;
        if (e < cnt) {
            int2 t = xdb[(int)cv[e]];
            xs = t.x; ds = __int_as_float(t.y);
        }
        #pragma unroll
        for (int t = 0; t < 11; t++) wt[t] += (xs == t) ? ds : 0.f;
    }
    #pragma unroll
    for (int t = 0; t < 11; t++) wt[t] = grp16_reduce(wt[t]);

    int2 xv = xdb[v];
    float dv = __int_as_float(xv.y);
    float dv2 = dv * dv;
    float mywt = 0.f;
    #pragma unroll
    for (int t = 0; t < 11; t++) mywt = (sub == t) ? wt[t] : mywt;
    float wp = dv * mywt + dv2 * ((xv.x == sub) ? 1.f : 0.f);   // sub>=11 -> 0
    wb[(size_t)v * 32 + sub] = (_Float16)wp;
    wb[(size_t)v * 32 + 16 + sub] = (_Float16)0.f;              // zero pad 16..31
}

// ---------------------------------------------------------------------------
// Fused conv1-GEMM + conv2-GEMM (R13): hs8 = fp8(128*dinv ⊙ (h2 @ W2)) where
// h2 = relu(wt16 @ M11 + b1) is computed ON THE FLY per k0-step via
// swapped-operand mfma(bf_m11, af_wt): transposed fragment gives each lane
// 4 k-consecutive h2 values -> one b64 LDS write (bias+relu+fp16 in fp32,
// bit-identical to the old gemm1). h2 never touches HBM.
// BM=128, BN=128, BK=64; 4 waves (2x2); wave = 64x64 in the main loop.
// ---------------------------------------------------------------------------
__launch_bounds__(256)
__global__ void gemm2f_kernel(const _Float16* __restrict__ wt16,
                              const _Float16* __restrict__ m11t,
                              const float* __restrict__ b1,
                              const _Float16* __restrict__ Bt,
                              const float* __restrict__ dinv,
                              unsigned char* __restrict__ C) {
    __shared__ _Float16 As[128][72];
    __shared__ _Float16 Bs[128][72];

    int side = blockIdx.z;
    const _Float16* Aw = wt16 + (size_t)side * kN * 32;
    const float* db = dinv + (size_t)side * kN;
    unsigned char* Cb = C + (size_t)side * kN * kGH;

    int tid = threadIdx.x;
    int wave = tid >> 6, lane = tid & 63;
    int quad = lane >> 4, r = lane & 15;
    int wm = wave >> 1, wn = wave & 1;
    int row0 = blockIdx.x * 128;
    int col0 = blockIdx.y * 128;

    floatx4 acc[4][4];
    #pragma unroll
    for (int i = 0; i < 4; i++)
        #pragma unroll
        for (int j = 0; j < 4; j++) acc[i][j] = (floatx4){0.f, 0.f, 0.f, 0.f};

    // wt16 fragments are k0-invariant (K=32 covers all of conv1's K): load once.
    half8v afw[2];
    #pragma unroll
    for (int mt = 0; mt < 2; mt++) {
        int gr = row0 + wave * 32 + mt * 16 + r;
        if (gr >= kN) gr = kN - 1;
        afw[mt] = *(const half8v*)(Aw + (size_t)gr * 32 + quad * 8);
    }

    for (int k0 = 0; k0 < kGH; k0 += 64) {
        // Stage Bs: w2t rows col0..col0+128, cols k0..k0+64.
        #pragma unroll
        for (int u = 0; u < 4; u++) {
            int idx = tid + u * 256;           // 0..1023
            int row = idx >> 3;                // 0..127
            int seg = (idx & 7) * 8;           // 0..56
            *(half8v*)&Bs[row][seg] = *(const half8v*)(Bt + (size_t)(col0 + row) * kGH + k0 + seg);
        }
        // Compute As = h2[row0..row0+128][k0..k0+64] on the fly.
        // Wave handles rows wave*32..wave*32+31; mt over 16-row halves,
        // nt over 4 k-subtiles. Swapped operands -> transposed fragment.
        #pragma unroll
        for (int nt = 0; nt < 4; nt++) {
            half8v bfw = *(const half8v*)(m11t + (size_t)(k0 + nt * 16 + r) * 32 + quad * 8);
            float4 bia = *(const float4*)(b1 + k0 + nt * 16 + quad * 4);
            #pragma unroll
            for (int mt = 0; mt < 2; mt++) {
                floatx4 d = (floatx4){0.f, 0.f, 0.f, 0.f};
                d = __builtin_amdgcn_mfma_f32_16x16x32_f16(bfw, afw[mt], d, 0, 0, 0);
                half4v o;
                o[0] = (_Float16)fmaxf(d[0] + bia.x, 0.f);
                o[1] = (_Float16)fmaxf(d[1] + bia.y, 0.f);
                o[2] = (_Float16)fmaxf(d[2] + bia.z, 0.f);
                o[3] = (_Float16)fmaxf(d[3] + bia.w, 0.f);
                *(half4v*)&As[wave * 32 + mt * 16 + r][nt * 16 + quad * 4] = o;
            }
        }
        __syncthreads();
        #pragma unroll
        for (int ks = 0; ks < 2; ks++) {
            half8v af[4], bf[4];
            #pragma unroll
            for (int mt = 0; mt < 4; mt++)
                af[mt] = *(const half8v*)&As[wm * 64 + mt * 16 + r][ks * 32 + quad * 8];
            #pragma unroll
            for (int nt = 0; nt < 4; nt++)
                bf[nt] = *(const half8v*)&Bs[wn * 64 + nt * 16 + r][ks * 32 + quad * 8];
            #pragma unroll
            for (int mt = 0; mt < 4; mt++)
                #pragma unroll
                for (int nt = 0; nt < 4; nt++)
                    acc[mt][nt] = __builtin_amdgcn_mfma_f32_16x16x32_f16(af[mt], bf[nt],
                                                                         acc[mt][nt], 0, 0, 0);
        }
        __syncthreads();
    }

    #pragma unroll
    for (int mt = 0; mt < 4; mt++) {
        #pragma unroll
        for (int i = 0; i < 4; i++) {
            int grow = row0 + wm * 64 + mt * 16 + quad * 4 + i;
            if (grow >= kN) continue;
            float rsq = db[grow] * HS_SCALE;
            #pragma unroll
            for (int nt = 0; nt < 4; nt++) {
                int gcol = col0 + wn * 64 + nt * 16 + r;
                float q = acc[mt][nt][i] * rsq;
                Cb[(size_t)grow * kGH + gcol] =
                    (unsigned char)__builtin_amdgcn_cvt_pk_fp8_f32(q, q, 0, false);
            }
        }
    }
}

// ---------------------------------------------------------------------------
// Unified tail GEMM via MFMA f16 (fp32 accum): C = [relu](A @ B + bias)
// ---------------------------------------------------------------------------
__launch_bounds__(256)
__global__ void gemm_tail_kernel(const _Float16* __restrict__ A,
                                 const _Float16* __restrict__ Bt,
                                 void* __restrict__ Cout,
                                 int N, int K,
                                 const float* __restrict__ bias,
                                 int relu, int f32out) {
    __shared__ _Float16 As[64][72];
    __shared__ _Float16 Bs[64][72];
    int tid = threadIdx.x;
    int wave = tid >> 6, lane = tid & 63;
    int quad = lane >> 4, r = lane & 15;
    int wm = wave >> 1, wn = wave & 1;
    int row0 = blockIdx.x * 64, col0 = blockIdx.y * 64;

    floatx4 acc[2][2];
    #pragma unroll
    for (int i = 0; i < 2; i++)
        #pragma unroll
        for (int j = 0; j < 2; j++) acc[i][j] = (floatx4){0.f, 0.f, 0.f, 0.f};

    for (int k0 = 0; k0 < K; k0 += 64) {
        #pragma unroll
        for (int u = 0; u < 2; u++) {
            int idx = tid + u * 256;           // 0..511
            int row = idx >> 3;                // 0..63
            int seg = (idx & 7) * 8;           // 0..56
            *(half8v*)&As[row][seg] = *(const half8v*)(A + (size_t)(row0 + row) * K + k0 + seg);
            *(half8v*)&Bs[row][seg] = *(const half8v*)(Bt + (size_t)(col0 + row) * K + k0 + seg);
        }
        __syncthreads();
        #pragma unroll
        for (int ks = 0; ks < 2; ks++) {
            half8v af[2], bf[2];
            #pragma unroll
            for (int mt = 0; mt < 2; mt++)
                af[mt] = *(const half8v*)&As[wm * 32 + mt * 16 + r][ks * 32 + quad * 8];
            #pragma unroll
            for (int nt = 0; nt < 2; nt++)
                bf[nt] = *(const half8v*)&Bs[wn * 32 + nt * 16 + r][ks * 32 + quad * 8];
            #pragma unroll
            for (int mt = 0; mt < 2; mt++)
                #pragma unroll
                for (int nt = 0; nt < 2; nt++)
                    acc[mt][nt] = __builtin_amdgcn_mfma_f32_16x16x32_f16(af[mt], bf[nt],
                                                                         acc[mt][nt], 0, 0, 0);
        }
        __syncthreads();
    }

    #pragma unroll
    for (int mt = 0; mt < 2; mt++) {
        #pragma unroll
        for (int i = 0; i < 4; i++) {
            int grow = row0 + wm * 32 + mt * 16 + quad * 4 + i;
            #pragma unroll
            for (int nt = 0; nt < 2; nt++) {
                int gcol = col0 + wn * 32 + nt * 16 + r;
                float v = acc[mt][nt][i] + bias[gcol];
                if (relu) v = fmaxf(v, 0.f);
                if (f32out) ((float*)Cout)[(size_t)grow * N + gcol] = v;
                else ((_Float16*)Cout)[(size_t)grow * N + gcol] = (_Float16)v;
            }
        }
    }
}

// ---------------------------------------------------------------------------
// Conv2 aggregate (R7-exact, proven floor): one wave per node, no barriers.
// h4[v] = relu(dinv[v]*(hs[v] + sum_s hs[s])/HS_SCALE + b2); NT fp16 store.
// ---------------------------------------------------------------------------
__global__ void aggregate2_kernel(const unsigned char* __restrict__ hs, const float* __restrict__ dinv,
                                  const int* __restrict__ counts,
                                  const unsigned short* __restrict__ col_ell,
                                  const float* __restrict__ bias, _Float16* __restrict__ out) {
    int side = blockIdx.y;
    const unsigned char* hb = hs + (size_t)side * kN * kGH;
    const float* dv_ = dinv + side * kN;
    const int* deg = counts + side * kN;
    const unsigned short* ci = col_ell + (size_t)side * kN * kMD;
    _Float16* ob = out + (size_t)side * kN * kGH;

    int wave = threadIdx.x >> 6;
    int lane = threadIdx.x & 63;
    int v = blockIdx.x * 4 + wave;
    if (v >= kN) return;
    int c = lane * 4;
    float4 bia = *(const float4*)(bias + c);
    float dv = dv_[v];
    float a0 = 0.f, a1 = 0.f, a2 = 0.f, a3 = 0.f;
    acc_fp8x4(*(const unsigned int*)(hb + (size_t)v * kGH + c), a0, a1, a2, a3);  // self-loop
    int cnt = min(deg[v], kMD);
    int idxl = (lane < cnt) ? (int)ci[(size_t)v * kMD + lane] : 0;
    int j = 0;
    for (; j + 16 <= cnt; j += 16) {
        unsigned int w[16];
        #pragma unroll
        for (int u = 0; u < 16; u++)
            w[u] = *(const unsigned int*)(hb + (size_t)__shfl(idxl, j + u) * kGH + c);
        #pragma unroll
        for (int u = 0; u < 16; u++) acc_fp8x4(w[u], a0, a1, a2, a3);
    }
    for (; j + 8 <= cnt; j += 8) {
        unsigned int w[8];
        #pragma unroll
        for (int u = 0; u < 8; u++)
            w[u] = *(const unsigned int*)(hb + (size_t)__shfl(idxl, j + u) * kGH + c);
        #pragma unroll
        for (int u = 0; u < 8; u++) acc_fp8x4(w[u], a0, a1, a2, a3);
    }
    for (; j < cnt; j++)
        acc_fp8x4(*(const unsigned int*)(hb + (size_t)__shfl(idxl, j) * kGH + c),
                  a0, a1, a2, a3);
    float f = dv * HS_INV;
    half4v o;
    o[0] = (_Float16)fmaxf(f * a0 + bia.x, 0.f);
    o[1] = (_Float16)fmaxf(f * a1 + bia.y, 0.f);
    o[2] = (_Float16)fmaxf(f * a2 + bia.z, 0.f);
    o[3] = (_Float16)fmaxf(f * a3 + bia.w, 0.f);
    __builtin_nontemporal_store(o, (half4v*)(ob + (size_t)v * kGH + c));
}

// ---------------------------------------------------------------------------
// Fast parallel mean-pool: grid (kG,2), 4 waves; wave w covers rows
// start+w+4k with half4v loads; one LDS reduce.
// ---------------------------------------------------------------------------
__global__ void poolfast_kernel(const _Float16* __restrict__ h,
                                const int* __restrict__ gstart,
                                _Float16* __restrict__ pooled16) {
    int side = blockIdx.y;
    int g = blockIdx.x;
    const _Float16* hb = h + (size_t)side * kN * kGH;
    int start = gstart[side * (kG + 1) + g];
    int end   = gstart[side * (kG + 1) + g + 1];
    int wave = threadIdx.x >> 6, lane = threadIdx.x & 63;
    int c = lane * 4;
    float a0 = 0.f, a1 = 0.f, a2 = 0.f, a3 = 0.f;
    for (int v = start + wave; v < end; v += 4) {
        half4v hv = *(const half4v*)(hb + (size_t)v * kGH + c);
        a0 += (float)hv[0]; a1 += (float)hv[1];
        a2 += (float)hv[2]; a3 += (float)hv[3];
    }
    __shared__ float ps[4][256];
    *(float4*)&ps[wave][c] = make_float4(a0, a1, a2, a3);
    __syncthreads();
    int t = threadIdx.x;
    float s = ps[0][t] + ps[1][t] + ps[2][t] + ps[3][t];
    float inv = 1.0f / fmaxf((float)(end - start), 1.0f);
    pooled16[(size_t)(side * kG + g) * kGH + t] = (_Float16)(s * inv);
}

// entity gather: e16[r][k] = fp16(relu(emb[ent[r]][k])), r in [0,2G)
__global__ void egather_kernel(const float* __restrict__ emb,
                               const int* __restrict__ ent1, const int* __restrict__ ent2,
                               _Float16* __restrict__ e16) {
    int rr = blockIdx.x;
    int idx = (rr < kG) ? ent1[rr] : ent2[rr - kG];
    int k = threadIdx.x;   // 128
    e16[(size_t)rr * kEMB + k] = (_Float16)fmaxf(emb[(size_t)idx * kEMB + k], 0.f);
}

// egs prep: egs16[g][k] = fp16(relu(eg1[g][k] + eg2[g][k]))
__global__ void egsprep_kernel(const _Float16* __restrict__ gfc16,
                               const _Float16* __restrict__ ento16,
                               _Float16* __restrict__ egs16) {
    int idx = blockIdx.x * 256 + threadIdx.x;   // 0..65535
    int g = idx >> 6;                            // 0..1023
    int k8 = (idx & 63) * 8;                     // 0..504
    const _Float16* src = (k8 < kGH) ? gfc16 : ento16;
    int kk = (k8 < kGH) ? k8 : k8 - kGH;
    half8v a = *(const half8v*)(src + (size_t)g * kGH + kk);
    half8v b = *(const half8v*)(src + (size_t)(g + kG) * kGH + kk);
    half8v o;
    #pragma unroll
    for (int u = 0; u < 8; u++) o[u] = (_Float16)fmaxf((float)a[u] + (float)b[u], 0.f);
    *(half8v*)(egs16 + (size_t)g * kHID + k8) = o;
}

// ---------------------------------------------------------------------------
// Host launch
// ---------------------------------------------------------------------------
static inline char* carve(char*& p, size_t bytes) {
    char* r = p;
    p += (bytes + 255) & ~(size_t)255;
    return r;
}

extern "C" void kernel_launch(void* const* d_in, const int* in_sizes, int n_in,
                              void* d_out, int out_size, void* d_ws, size_t ws_size,
                              hipStream_t stream) {
    const int*   x1       = (const int*)d_in[0];
    const int*   ei1      = (const int*)d_in[1];
    const int*   ent1     = (const int*)d_in[2];
    const int*   batch1   = (const int*)d_in[3];
    const int*   x2       = (const int*)d_in[4];
    const int*   ei2      = (const int*)d_in[5];
    const int*   ent2     = (const int*)d_in[6];
    const int*   batch2   = (const int*)d_in[7];
    const float* atom_emb = (const float*)d_in[8];
    const float* gW1      = (const float*)d_in[9];
    const float* gb1      = (const float*)d_in[10];
    const float* gW2      = (const float*)d_in[11];
    const float* gb2      = (const float*)d_in[12];
    const float* fcW      = (const float*)d_in[13];
    const float* fcb      = (const float*)d_in[14];
    const float* ent_emb  = (const float*)d_in[15];
    const float* eW1      = (const float*)d_in[16];
    const float* eb1      = (const float*)d_in[17];
    const float* eW2      = (const float*)d_in[18];
    const float* eb2      = (const float*)d_in[19];
    const float* dW1      = (const float*)d_in[20];
    const float* db1      = (const float*)d_in[21];
    const float* dW2      = (const float*)d_in[22];
    const float* db2      = (const float*)d_in[23];
    const float* dW3      = (const float*)d_in[24];
    const float* db3      = (const float*)d_in[25];
    float* out = (float*)d_out;

    // Workspace carve (no zeroed spans needed — binp3 writes all counts).
    char* p = (char*)d_ws;
    _Float16* h4_h   = (_Float16*)carve(p, (size_t)2 * kN * kGH * 2);  // h4 only now
    unsigned char* hs8 = (unsigned char*)carve(p, (size_t)2 * kN * kGH); // fp8 hs
    unsigned short* col_ell = (unsigned short*)carve(p, (size_t)2 * kN * kMD * 2);
    unsigned int* ebuf = (unsigned int*)carve(p, (size_t)2 * kE * 4);
    int*   poff    = (int*)  carve(p, (size_t)2 * kNBKT * 256 * 4);
    int*   btot    = (int*)  carve(p, (size_t)2 * kNBKT * 4);
    int*   bbase   = (int*)  carve(p, (size_t)2 * (kNBKT + 1) * 4);
    int*   counts  = (int*)  carve(p, (size_t)2 * kN * 4);
    float* dinv    = (float*)carve(p, (size_t)2 * kN * 4);
    int2*  xd      = (int2*) carve(p, (size_t)2 * kN * 8);
    int*   gstart  = (int*)  carve(p, (size_t)2 * (kG + 1) * 4);
    float* M11     = (float*)carve(p, 11 * kGH * 4);
    _Float16* w2t  = (_Float16*)carve(p, (size_t)kGH * kGH * 2);
    _Float16* m11t = (_Float16*)carve(p, (size_t)256 * 32 * 2);
    _Float16* wt16 = (_Float16*)carve(p, (size_t)2 * kN * 32 * 2);
    // fp16 tail buffers
    _Float16* pooled16 = (_Float16*)carve(p, (size_t)2 * kG * kGH * 2);
    _Float16* gfc16    = (_Float16*)carve(p, (size_t)2 * kG * kGH * 2);
    _Float16* e16      = (_Float16*)carve(p, (size_t)2 * kG * kEMB * 2);
    _Float16* etmp16   = (_Float16*)carve(p, (size_t)2 * kG * kEH * 2);
    _Float16* ento16   = (_Float16*)carve(p, (size_t)2 * kG * kEH * 2);
    _Float16* egs16    = (_Float16*)carve(p, (size_t)kG * kHID * 2);
    _Float16* dh1_16   = (_Float16*)carve(p, (size_t)kG * kHID * 2);
    _Float16* dh2_16   = (_Float16*)carve(p, (size_t)kG * kHID * 2);
    // fp16 transposed tail weights
    _Float16* dW1t = (_Float16*)carve(p, (size_t)kHID * kHID * 2);
    _Float16* dW2t = (_Float16*)carve(p, (size_t)kHID * kHID * 2);
    _Float16* dW3t = (_Float16*)carve(p, (size_t)kOUT * kHID * 2);
    _Float16* fcWt = (_Float16*)carve(p, (size_t)kGH * kGH * 2);
    _Float16* eW1t = (_Float16*)carve(p, (size_t)kEH * kEMB * 2);
    _Float16* eW2t = (_Float16*)carve(p, (size_t)kEH * kEH * 2);

    // --- Graph structure via LDS binning (zero global atomics) ---
    prep_kernel<<<299, 256, 0, stream>>>(atom_emb, gW1, gW2, M11, w2t, m11t);
    wtrans_kernel<<<2944, 256, 0, stream>>>(dW1, dW2, dW3, fcW, eW1, eW2,
                                            dW1t, dW2t, dW3t, fcWt, eW1t, eW2t);
    gbounds_kernel<<<dim3((kG + 256) / 256, 2), 256, 0, stream>>>(batch1, batch2, gstart);
    binp1_kernel<<<dim3(kPBLK, 2), 256, 0, stream>>>(ei1, ei2, poff);
    scanA_kernel<<<dim3(kNBKT, 2), 256, 0, stream>>>(poff, btot);
    scanB_kernel<<<2, 256, 0, stream>>>(btot, bbase);
    binp2_kernel<<<dim3(kPBLK, 2), 256, 0, stream>>>(ei1, ei2, poff, bbase, ebuf);
    binp3_kernel<<<dim3(kNBKT, 2), 256, 0, stream>>>(ebuf, bbase, col_ell, counts,
                                                     dinv, xd, x1, x2);
    // --- Conv1 histogram -> wt16 ---
    conv1_wt_kernel<<<dim3(kN / 16, 2), 256, 0, stream>>>(xd, counts, col_ell, wt16);
    // --- Fused conv1-GEMM + conv2-GEMM: hs8 directly from wt16 (no h2) ---
    gemm2f_kernel<<<dim3((kN + 127) / 128, kGH / 128, 2), 256, 0, stream>>>(
        wt16, m11t, gb1, w2t, dinv, hs8);
    // --- Conv2 aggregate (R7-proven) -> h4 ---
    aggregate2_kernel<<<dim3((kN + 3) / 4, 2), 256, 0, stream>>>(hs8, dinv, counts, col_ell,
                                                                 gb2, h4_h);
    // --- Fast parallel mean-pool -> pooled16 ---
    poolfast_kernel<<<dim3(kG, 2), 256, 0, stream>>>(h4_h, gstart, pooled16);
    // --- Entity gather (fp16) ---
    egather_kernel<<<2 * kG, 128, 0, stream>>>(ent_emb, ent1, ent2, e16);

    // --- Tail GEMMs, all fp16 MFMA (fp32 accum) ---
    gemm_tail_kernel<<<dim3(2 * kG / 64, kGH / 64), 256, 0, stream>>>(
        pooled16, fcWt, gfc16, kGH, kGH, fcb, 0, 0);
    gemm_tail_kernel<<<dim3(2 * kG / 64, kEH / 64), 256, 0, stream>>>(
        e16, eW1t, etmp16, kEH, kEMB, eb1, 1, 0);
    gemm_tail_kernel<<<dim3(2 * kG / 64, kEH / 64), 256, 0, stream>>>(
        etmp16, eW2t, ento16, kEH, kEH, eb2, 1, 0);
    egsprep_kernel<<<kG * kHID / 8 / 256, 256, 0, stream>>>(gfc16, ento16, egs16);
    gemm_tail_kernel<<<dim3(kG / 64, kHID / 64), 256, 0, stream>>>(
        egs16, dW1t, dh1_16, kHID, kHID, db1, 1, 0);
    gemm_tail_kernel<<<dim3(kG / 64, kHID / 64), 256, 0, stream>>>(
        dh1_16, dW2t, dh2_16, kHID, kHID, db2, 1, 0);
    gemm_tail_kernel<<<dim3(kG / 64, kOUT / 64), 256, 0, stream>>>(
        dh2_16, dW3t, out, kOUT, kHID, db3, 0, 1);
}

// Round 14
// 387.683 us; speedup vs baseline: 1.1792x; 1.0190x over previous
//
#include <hip/hip_runtime.h>
#include <hip/hip_fp16.h>

// Problem constants
static constexpr int kN = 50000;      // nodes per side
static constexpr int kE = 800000;     // edges per side
static constexpr int kG = 1024;       // graphs per batch
static constexpr int kEMB = 128;
static constexpr int kGH = 256;
static constexpr int kEH = 256;
static constexpr int kOUT = 128;
static constexpr int kHID = 512;
static constexpr int kNB = (kN + 255) / 256;   // 196 chunks per side
static constexpr int kMD = 64;        // ELL stride; deg ~ Poisson(16), P(deg>=64)~e^-125
static constexpr int kNBKT = 196;     // dst buckets of 256 nodes (50000 -> 196)
static constexpr int kEPB = 3125;     // edges per bin block; 256 blocks exactly
static constexpr int kPBLK = 256;     // bin blocks per side (256*3125 = 800000)

typedef __attribute__((ext_vector_type(8))) _Float16 half8v;
typedef __attribute__((ext_vector_type(4))) _Float16 half4v;
typedef __attribute__((ext_vector_type(4))) float floatx4;
typedef __attribute__((ext_vector_type(2))) float floatx2;

// NOTE (R6): cross-XCD plain-data handoff through grid.sync() gave stale reads.
// NOTE (R7/R12): device atomics memory-side; floor is OP-COUNT ~21/ns.
// (R2) fp8 hs: 659->616us, absmax UNCHANGED. (R3) conv1 DPP groups ->596us.
// (R5) ELL fusion regressed rank (atomics+random stores share mem-op pipe).
// (R6) LDS bucket binning, zero global atomics: 585->523us.
// (R7) fp16-MFMA tail: 523->439us. aggregate2 ~61us = proven gather floor.
// (R8-R11) agg+pool fusion arc regressed; reverted R12 (398.1us).
// (R13) gemm1 fused into gemm2 (h2 never hits HBM): only -3us — the pipeline
// below aggregate2 is latency-bound mid-kernels, not byte-bound.
// This revision (R14): (a) conv1_wt DELETED — wt is computed edge-centrically
// in binp4 (walk ebuf bucket-major, 1 LDS float atomicAdd/edge into
// wtl[256][16], epilogue emits wt16) — replaces ~11 VALU/edge + DPP with
// 1 LDS atomic; (b) h4 stored fp8 (same x128 scheme): aggregate2 write
// 50->25MB, poolfast read 51->26MB.

// fp8 fixed scale: |hs| <~ 0.2 typ; x128 keeps values in e4m3 normal range.
#define HS_SCALE 128.0f
#define HS_INV   (1.0f / 128.0f)

__device__ inline void acc_fp8x4(unsigned int w, float& a0, float& a1, float& a2, float& a3) {
    floatx2 lo = __builtin_amdgcn_cvt_pk_f32_fp8(w, false);
    floatx2 hi = __builtin_amdgcn_cvt_pk_f32_fp8(w, true);
    a0 += lo[0]; a1 += lo[1]; a2 += hi[0]; a3 += hi[1];
}

// ---------------------------------------------------------------------------
// prep: w2t = fp16(gW2^T) (blocks 0..255), M11 = atom_emb@gW1 (blocks 256..266),
// m11t = fp16(M11^T padded to K=32) (blocks 267..298).
// ---------------------------------------------------------------------------
__global__ void prep_kernel(const float* __restrict__ atom_emb, const float* __restrict__ gW1,
                            const float* __restrict__ gW2,
                            float* __restrict__ M11, _Float16* __restrict__ w2t,
                            _Float16* __restrict__ m11t) {
    int i = blockIdx.x * 256 + threadIdx.x;
    if (blockIdx.x < 256) {
        int k = i >> 8, n = i & 255;
        w2t[(size_t)n * kGH + k] = (_Float16)gW2[(size_t)k * kGH + n];
    } else {
        int j = i - 65536;
        if (j < 11 * kGH) {
            int r = j >> 8, c = j & 255;
            float s = 0.f;
            for (int k = 0; k < kEMB; k++) s += atom_emb[r * kEMB + k] * gW1[k * kGH + c];
            M11[j] = s;
        } else if (j < 11 * kGH + 256 * 32) {
            int j2 = j - 11 * kGH;
            int n = j2 >> 5, k = j2 & 31;     // m11t[n][k] = M11[k][n], 0 for k>=11
            float s = 0.f;
            if (k < 11)
                for (int p = 0; p < kEMB; p++) s += atom_emb[k * kEMB + p] * gW1[p * kGH + n];
            m11t[j2] = (_Float16)s;
        }
    }
}

// ---------------------------------------------------------------------------
// wtrans: all tail weights -> fp16 transposed ([N][K] from [K][N]).
// ---------------------------------------------------------------------------
__global__ void wtrans_kernel(const float* __restrict__ dW1, const float* __restrict__ dW2,
                              const float* __restrict__ dW3, const float* __restrict__ fcW,
                              const float* __restrict__ eW1, const float* __restrict__ eW2,
                              _Float16* __restrict__ dW1t, _Float16* __restrict__ dW2t,
                              _Float16* __restrict__ dW3t, _Float16* __restrict__ fcWt,
                              _Float16* __restrict__ eW1t, _Float16* __restrict__ eW2t) {
    int b = blockIdx.x;
    const float* src; _Float16* dst; int K, N, j0;
    if (b < 1024)      { src = dW1; dst = dW1t; K = 512; N = 512; j0 = b * 256; }
    else if (b < 2048) { src = dW2; dst = dW2t; K = 512; N = 512; j0 = (b - 1024) * 256; }
    else if (b < 2304) { src = dW3; dst = dW3t; K = 512; N = 128; j0 = (b - 2048) * 256; }
    else if (b < 2560) { src = fcW; dst = fcWt; K = 256; N = 256; j0 = (b - 2304) * 256; }
    else if (b < 2688) { src = eW1; dst = eW1t; K = 128; N = 256; j0 = (b - 2560) * 256; }
    else               { src = eW2; dst = eW2t; K = 256; N = 256; j0 = (b - 2688) * 256; }
    int j = j0 + threadIdx.x;            // dst linear: n*K + k
    int n = j / K, k = j - n * K;
    dst[j] = (_Float16)src[(size_t)k * N + n];
}

// ---------------------------------------------------------------------------
// gbounds: gstart[side][g] = lower_bound(batch, g), parallel per thread.
// ---------------------------------------------------------------------------
__global__ void gbounds_kernel(const int* __restrict__ batch1, const int* __restrict__ batch2,
                               int* __restrict__ gstart) {
    int side = blockIdx.y;
    const int* batch = side ? batch2 : batch1;
    int g = blockIdx.x * 256 + threadIdx.x;
    if (g > kG) return;
    int lo = 0, hi = kN;
    while (lo < hi) { int mid = (lo + hi) >> 1; if (batch[mid] < g) lo = mid + 1; else hi = mid; }
    gstart[side * (kG + 1) + g] = lo;
}

// ---------------------------------------------------------------------------
// binp1: per-block LDS histogram over 196 dst-buckets.
// ---------------------------------------------------------------------------
__global__ void binp1_kernel(const int* __restrict__ ei1, const int* __restrict__ ei2,
                             int* __restrict__ poff) {
    int side = blockIdx.y;
    const int* dst = (side ? ei2 : ei1) + kE;
    __shared__ int hist[kNBKT];
    int t = threadIdx.x;
    if (t < kNBKT) hist[t] = 0;
    __syncthreads();
    int base = blockIdx.x * kEPB;
    for (int j = t; j < kEPB; j += 256)
        atomicAdd(&hist[dst[base + j] >> 8], 1);
    __syncthreads();
    if (t < kNBKT) poff[((side * kNBKT + t) << 8) | blockIdx.x] = hist[t];
}

// scanA: per (side,bucket) exclusive scan over the 256 block counts.
__global__ void scanA_kernel(int* __restrict__ poff, int* __restrict__ btot) {
    int b = blockIdx.x, side = blockIdx.y, t = threadIdx.x;
    __shared__ int s[256];
    int idx = ((side * kNBKT + b) << 8) | t;
    int v = poff[idx];
    s[t] = v;
    __syncthreads();
    for (int o = 1; o < 256; o <<= 1) {
        int u = (t >= o) ? s[t - o] : 0;
        __syncthreads();
        s[t] += u;
        __syncthreads();
    }
    poff[idx] = s[t] - v;
    if (t == 255) btot[side * kNBKT + b] = s[255];
}

// scanB: exclusive scan of bucket totals -> bbase.
__global__ void scanB_kernel(const int* __restrict__ btot, int* __restrict__ bbase) {
    int side = blockIdx.x, t = threadIdx.x;
    __shared__ int s[256];
    int v = (t < kNBKT) ? btot[side * kNBKT + t] : 0;
    s[t] = v;
    __syncthreads();
    for (int o = 1; o < 256; o <<= 1) {
        int u = (t >= o) ? s[t - o] : 0;
        __syncthreads();
        s[t] += u;
        __syncthreads();
    }
    if (t < kNBKT) bbase[side * (kNBKT + 1) + t] = s[t] - v;
    if (t == 255) bbase[side * (kNBKT + 1) + kNBKT] = s[255];
}

// ---------------------------------------------------------------------------
// binp2: block-local LDS bucket-sort, coalesced bucket-major write-out.
// ---------------------------------------------------------------------------
__launch_bounds__(256)
__global__ void binp2_kernel(const int* __restrict__ ei1, const int* __restrict__ ei2,
                             const int* __restrict__ poff, const int* __restrict__ bbase,
                             unsigned int* __restrict__ ebuf) {
    int side = blockIdx.y, blk = blockIdx.x, t = threadIdx.x;
    const int* ei = side ? ei2 : ei1;
    __shared__ int hist[kNBKT], lb[kNBKT], gb[kNBKT], scanbuf[256];
    __shared__ unsigned int sorted[kEPB];
    if (t < kNBKT) hist[t] = 0;
    __syncthreads();
    int base = blk * kEPB;
    for (int j = t; j < kEPB; j += 256)
        atomicAdd(&hist[ei[kE + base + j] >> 8], 1);
    __syncthreads();
    int v = (t < kNBKT) ? hist[t] : 0;
    scanbuf[t] = v;
    __syncthreads();
    for (int o = 1; o < 256; o <<= 1) {
        int u = (t >= o) ? scanbuf[t - o] : 0;
        __syncthreads();
        scanbuf[t] += u;
        __syncthreads();
    }
    if (t < kNBKT) {
        lb[t] = scanbuf[t] - v;
        gb[t] = bbase[side * (kNBKT + 1) + t] + poff[((side * kNBKT + t) << 8) | blk];
        hist[t] = 0;
    }
    __syncthreads();
    for (int j = t; j < kEPB; j += 256) {
        int s_ = ei[base + j];
        int d  = ei[kE + base + j];
        int b  = d >> 8;
        int r  = atomicAdd(&hist[b], 1);
        sorted[lb[b] + r] = ((unsigned int)d << 16) | (unsigned int)s_;
    }
    __syncthreads();
    for (int j = t; j < kEPB; j += 256) {
        unsigned int val = sorted[j];
        int b = val >> 24;
        int gpos = gb[b] + (j - lb[b]);
        ebuf[(size_t)side * kE + gpos] = val;
    }
}

// ---------------------------------------------------------------------------
// binp3: one block per bucket; LDS slot counters; col_ell stores in a 32KB
// window. Fused epilogue: degrees->counts, dinv, xd.
// ---------------------------------------------------------------------------
__global__ void binp3_kernel(const unsigned int* __restrict__ ebuf, const int* __restrict__ bbase,
                             unsigned short* __restrict__ col_ell, int* __restrict__ counts,
                             float* __restrict__ dinv, int2* __restrict__ xd,
                             const int* __restrict__ x1, const int* __restrict__ x2) {
    int b = blockIdx.x, side = blockIdx.y, t = threadIdx.x;
    __shared__ int cnt[256];
    cnt[t] = 0;
    __syncthreads();
    int start = bbase[side * (kNBKT + 1) + b];
    int end   = bbase[side * (kNBKT + 1) + b + 1];
    for (int k = start + t; k < end; k += 256) {
        unsigned int v = ebuf[(size_t)side * kE + k];
        int d8 = (v >> 16) & 255;
        int slot = atomicAdd(&cnt[d8], 1);
        if (slot > kMD - 1) slot = kMD - 1;
        int node = (b << 8) | d8;
        col_ell[((size_t)side * kN + node) * kMD + slot] = (unsigned short)(v & 0xFFFFu);
    }
    __syncthreads();
    int node = (b << 8) | t;
    if (node < kN) {
        int d = cnt[t];
        counts[side * kN + node] = d;
        float dv = rsqrtf((float)(d + 1));           // +1 self-loop
        dinv[side * kN + node] = dv;
        const int* x = side ? x2 : x1;
        xd[side * kN + node] = make_int2(x[node], __float_as_int(dv));
    }
}

// ---------------------------------------------------------------------------
// binp4 (R14): edge-centric conv1 histogram. One block per bucket; walk ebuf
// coalesced; wtl[dst&255][x[src]] += dinv[src] via LDS float atomics (one 8B
// xd gather per edge, L2-resident). Epilogue emits wt16[v][32]:
// wt'[s] = dv*wtl[s] + dv^2*delta(x[v]=s) for s<16 (s>=11 slots stay 0),
// zero pad 16..31. Replaces the node-centric conv1_wt entirely.
// ---------------------------------------------------------------------------
__global__ void binp4_kernel(const unsigned int* __restrict__ ebuf, const int* __restrict__ bbase,
                             const int2* __restrict__ xd, _Float16* __restrict__ wt16) {
    int b = blockIdx.x, side = blockIdx.y, t = threadIdx.x;
    const int2* xdb = xd + (size_t)side * kN;
    __shared__ float wtl[256][16];
    #pragma unroll
    for (int s = 0; s < 16; s++) wtl[t][s] = 0.f;
    __syncthreads();
    int start = bbase[side * (kNBKT + 1) + b];
    int end   = bbase[side * (kNBKT + 1) + b + 1];
    for (int k = start + t; k < end; k += 256) {
        unsigned int v = ebuf[(size_t)side * kE + k];
        int src = v & 0xFFFFu;
        int d8 = (v >> 16) & 255;
        int2 xs = xdb[src];
        atomicAdd(&wtl[d8][xs.x], __int_as_float(xs.y));
    }
    __syncthreads();
    int node = (b << 8) | t;
    if (node < kN) {
        int2 xv = xdb[node];
        float dv = __int_as_float(xv.y);
        float dv2 = dv * dv;
        _Float16* wb = wt16 + ((size_t)side * kN + node) * 32;
        half8v o0, o1, z;
        #pragma unroll
        for (int s = 0; s < 8; s++) {
            o0[s] = (_Float16)(dv * wtl[t][s] + ((xv.x == s) ? dv2 : 0.f));
            o1[s] = (_Float16)(dv * wtl[t][s + 8] + ((xv.x == s + 8) ? dv2 : 0.f));
            z[s] = (_Float16)0.f;
        }
        *(half8v*)(wb) = o0;
        *(half8v*)(wb + 8) = o1;
        *(half8v*)(wb + 16) = z;
        *(half8v*)(wb + 24) = z;
    }
}

// ---------------------------------------------------------------------------
// Fused conv1-GEMM + conv2-GEMM: hs8 = fp8(128*dinv ⊙ (relu(wt16@M11+b1) @ W2))
// h2 computed on the fly per k0-step via swapped-operand mfma.
// BM=128, BN=128, BK=64; 4 waves (2x2); wave = 64x64 in the main loop.
// ---------------------------------------------------------------------------
__launch_bounds__(256)
__global__ void gemm2f_kernel(const _Float16* __restrict__ wt16,
                              const _Float16* __restrict__ m11t,
                              const float* __restrict__ b1,
                              const _Float16* __restrict__ Bt,
                              const float* __restrict__ dinv,
                              unsigned char* __restrict__ C) {
    __shared__ _Float16 As[128][72];
    __shared__ _Float16 Bs[128][72];

    int side = blockIdx.z;
    const _Float16* Aw = wt16 + (size_t)side * kN * 32;
    const float* db = dinv + (size_t)side * kN;
    unsigned char* Cb = C + (size_t)side * kN * kGH;

    int tid = threadIdx.x;
    int wave = tid >> 6, lane = tid & 63;
    int quad = lane >> 4, r = lane & 15;
    int wm = wave >> 1, wn = wave & 1;
    int row0 = blockIdx.x * 128;
    int col0 = blockIdx.y * 128;

    floatx4 acc[4][4];
    #pragma unroll
    for (int i = 0; i < 4; i++)
        #pragma unroll
        for (int j = 0; j < 4; j++) acc[i][j] = (floatx4){0.f, 0.f, 0.f, 0.f};

    // wt16 fragments are k0-invariant (K=32 covers all of conv1's K): load once.
    half8v afw[2];
    #pragma unroll
    for (int mt = 0; mt < 2; mt++) {
        int gr = row0 + wave * 32 + mt * 16 + r;
        if (gr >= kN) gr = kN - 1;
        afw[mt] = *(const half8v*)(Aw + (size_t)gr * 32 + quad * 8);
    }

    for (int k0 = 0; k0 < kGH; k0 += 64) {
        // Stage Bs: w2t rows col0..col0+128, cols k0..k0+64.
        #pragma unroll
        for (int u = 0; u < 4; u++) {
            int idx = tid + u * 256;           // 0..1023
            int row = idx >> 3;                // 0..127
            int seg = (idx & 7) * 8;           // 0..56
            *(half8v*)&Bs[row][seg] = *(const half8v*)(Bt + (size_t)(col0 + row) * kGH + k0 + seg);
        }
        // Compute As = h2[row0..row0+128][k0..k0+64] on the fly.
        #pragma unroll
        for (int nt = 0; nt < 4; nt++) {
            half8v bfw = *(const half8v*)(m11t + (size_t)(k0 + nt * 16 + r) * 32 + quad * 8);
            float4 bia = *(const float4*)(b1 + k0 + nt * 16 + quad * 4);
            #pragma unroll
            for (int mt = 0; mt < 2; mt++) {
                floatx4 d = (floatx4){0.f, 0.f, 0.f, 0.f};
                d = __builtin_amdgcn_mfma_f32_16x16x32_f16(bfw, afw[mt], d, 0, 0, 0);
                half4v o;
                o[0] = (_Float16)fmaxf(d[0] + bia.x, 0.f);
                o[1] = (_Float16)fmaxf(d[1] + bia.y, 0.f);
                o[2] = (_Float16)fmaxf(d[2] + bia.z, 0.f);
                o[3] = (_Float16)fmaxf(d[3] + bia.w, 0.f);
                *(half4v*)&As[wave * 32 + mt * 16 + r][nt * 16 + quad * 4] = o;
            }
        }
        __syncthreads();
        #pragma unroll
        for (int ks = 0; ks < 2; ks++) {
            half8v af[4], bf[4];
            #pragma unroll
            for (int mt = 0; mt < 4; mt++)
                af[mt] = *(const half8v*)&As[wm * 64 + mt * 16 + r][ks * 32 + quad * 8];
            #pragma unroll
            for (int nt = 0; nt < 4; nt++)
                bf[nt] = *(const half8v*)&Bs[wn * 64 + nt * 16 + r][ks * 32 + quad * 8];
            #pragma unroll
            for (int mt = 0; mt < 4; mt++)
                #pragma unroll
                for (int nt = 0; nt < 4; nt++)
                    acc[mt][nt] = __builtin_amdgcn_mfma_f32_16x16x32_f16(af[mt], bf[nt],
                                                                         acc[mt][nt], 0, 0, 0);
        }
        __syncthreads();
    }

    #pragma unroll
    for (int mt = 0; mt < 4; mt++) {
        #pragma unroll
        for (int i = 0; i < 4; i++) {
            int grow = row0 + wm * 64 + mt * 16 + quad * 4 + i;
            if (grow >= kN) continue;
            float rsq = db[grow] * HS_SCALE;
            #pragma unroll
            for (int nt = 0; nt < 4; nt++) {
                int gcol = col0 + wn * 64 + nt * 16 + r;
                float q = acc[mt][nt][i] * rsq;
                Cb[(size_t)grow * kGH + gcol] =
                    (unsigned char)__builtin_amdgcn_cvt_pk_fp8_f32(q, q, 0, false);
            }
        }
    }
}

// ---------------------------------------------------------------------------
// Unified tail GEMM via MFMA f16 (fp32 accum): C = [relu](A @ B + bias)
// ---------------------------------------------------------------------------
__launch_bounds__(256)
__global__ void gemm_tail_kernel(const _Float16* __restrict__ A,
                                 const _Float16* __restrict__ Bt,
                                 void* __restrict__ Cout,
                                 int N, int K,
                                 const float* __restrict__ bias,
                                 int relu, int f32out) {
    __shared__ _Float16 As[64][72];
    __shared__ _Float16 Bs[64][72];
    int tid = threadIdx.x;
    int wave = tid >> 6, lane = tid & 63;
    int quad = lane >> 4, r = lane & 15;
    int wm = wave >> 1, wn = wave & 1;
    int row0 = blockIdx.x * 64, col0 = blockIdx.y * 64;

    floatx4 acc[2][2];
    #pragma unroll
    for (int i = 0; i < 2; i++)
        #pragma unroll
        for (int j = 0; j < 2; j++) acc[i][j] = (floatx4){0.f, 0.f, 0.f, 0.f};

    for (int k0 = 0; k0 < K; k0 += 64) {
        #pragma unroll
        for (int u = 0; u < 2; u++) {
            int idx = tid + u * 256;           // 0..511
            int row = idx >> 3;                // 0..63
            int seg = (idx & 7) * 8;           // 0..56
            *(half8v*)&As[row][seg] = *(const half8v*)(A + (size_t)(row0 + row) * K + k0 + seg);
            *(half8v*)&Bs[row][seg] = *(const half8v*)(Bt + (size_t)(col0 + row) * K + k0 + seg);
        }
        __syncthreads();
        #pragma unroll
        for (int ks = 0; ks < 2; ks++) {
            half8v af[2], bf[2];
            #pragma unroll
            for (int mt = 0; mt < 2; mt++)
                af[mt] = *(const half8v*)&As[wm * 32 + mt * 16 + r][ks * 32 + quad * 8];
            #pragma unroll
            for (int nt = 0; nt < 2; nt++)
                bf[nt] = *(const half8v*)&Bs[wn * 32 + nt * 16 + r][ks * 32 + quad * 8];
            #pragma unroll
            for (int mt = 0; mt < 2; mt++)
                #pragma unroll
                for (int nt = 0; nt < 2; nt++)
                    acc[mt][nt] = __builtin_amdgcn_mfma_f32_16x16x32_f16(af[mt], bf[nt],
                                                                         acc[mt][nt], 0, 0, 0);
        }
        __syncthreads();
    }

    #pragma unroll
    for (int mt = 0; mt < 2; mt++) {
        #pragma unroll
        for (int i = 0; i < 4; i++) {
            int grow = row0 + wm * 32 + mt * 16 + quad * 4 + i;
            #pragma unroll
            for (int nt = 0; nt < 2; nt++) {
                int gcol = col0 + wn * 32 + nt * 16 + r;
                float v = acc[mt][nt][i] + bias[gcol];
                if (relu) v = fmaxf(v, 0.f);
                if (f32out) ((float*)Cout)[(size_t)grow * N + gcol] = v;
                else ((_Float16*)Cout)[(size_t)grow * N + gcol] = (_Float16)v;
            }
        }
    }
}

// ---------------------------------------------------------------------------
// Conv2 aggregate (R7 structure, proven floor): one wave per node, no barriers.
// h4 now stored fp8 (x128): halves the write + pool's re-read.
// ---------------------------------------------------------------------------
__global__ void aggregate2_kernel(const unsigned char* __restrict__ hs, const float* __restrict__ dinv,
                                  const int* __restrict__ counts,
                                  const unsigned short* __restrict__ col_ell,
                                  const float* __restrict__ bias, unsigned char* __restrict__ out) {
    int side = blockIdx.y;
    const unsigned char* hb = hs + (size_t)side * kN * kGH;
    const float* dv_ = dinv + side * kN;
    const int* deg = counts + side * kN;
    const unsigned short* ci = col_ell + (size_t)side * kN * kMD;
    unsigned char* ob = out + (size_t)side * kN * kGH;

    int wave = threadIdx.x >> 6;
    int lane = threadIdx.x & 63;
    int v = blockIdx.x * 4 + wave;
    if (v >= kN) return;
    int c = lane * 4;
    float4 bia = *(const float4*)(bias + c);
    float dv = dv_[v];
    float a0 = 0.f, a1 = 0.f, a2 = 0.f, a3 = 0.f;
    acc_fp8x4(*(const unsigned int*)(hb + (size_t)v * kGH + c), a0, a1, a2, a3);  // self-loop
    int cnt = min(deg[v], kMD);
    int idxl = (lane < cnt) ? (int)ci[(size_t)v * kMD + lane] : 0;
    int j = 0;
    for (; j + 16 <= cnt; j += 16) {
        unsigned int w[16];
        #pragma unroll
        for (int u = 0; u < 16; u++)
            w[u] = *(const unsigned int*)(hb + (size_t)__shfl(idxl, j + u) * kGH + c);
        #pragma unroll
        for (int u = 0; u < 16; u++) acc_fp8x4(w[u], a0, a1, a2, a3);
    }
    for (; j + 8 <= cnt; j += 8) {
        unsigned int w[8];
        #pragma unroll
        for (int u = 0; u < 8; u++)
            w[u] = *(const unsigned int*)(hb + (size_t)__shfl(idxl, j + u) * kGH + c);
        #pragma unroll
        for (int u = 0; u < 8; u++) acc_fp8x4(w[u], a0, a1, a2, a3);
    }
    for (; j < cnt; j++)
        acc_fp8x4(*(const unsigned int*)(hb + (size_t)__shfl(idxl, j) * kGH + c),
                  a0, a1, a2, a3);
    float f = dv * HS_INV;
    float q0 = fmaxf(f * a0 + bia.x, 0.f) * HS_SCALE;
    float q1 = fmaxf(f * a1 + bia.y, 0.f) * HS_SCALE;
    float q2 = fmaxf(f * a2 + bia.z, 0.f) * HS_SCALE;
    float q3 = fmaxf(f * a3 + bia.w, 0.f) * HS_SCALE;
    unsigned int w = __builtin_amdgcn_cvt_pk_fp8_f32(q0, q1, 0, false);
    w = __builtin_amdgcn_cvt_pk_fp8_f32(q2, q3, w, true);
    __builtin_nontemporal_store(w, (unsigned int*)(ob + (size_t)v * kGH + c));
}

// ---------------------------------------------------------------------------
// Fast parallel mean-pool over fp8 h4: grid (kG,2), 4 waves; LDS reduce.
// ---------------------------------------------------------------------------
__global__ void poolfast_kernel(const unsigned char* __restrict__ h,
                                const int* __restrict__ gstart,
                                _Float16* __restrict__ pooled16) {
    int side = blockIdx.y;
    int g = blockIdx.x;
    const unsigned char* hb = h + (size_t)side * kN * kGH;
    int start = gstart[side * (kG + 1) + g];
    int end   = gstart[side * (kG + 1) + g + 1];
    int wave = threadIdx.x >> 6, lane = threadIdx.x & 63;
    int c = lane * 4;
    float a0 = 0.f, a1 = 0.f, a2 = 0.f, a3 = 0.f;
    for (int v = start + wave; v < end; v += 4)
        acc_fp8x4(*(const unsigned int*)(hb + (size_t)v * kGH + c), a0, a1, a2, a3);
    __shared__ float ps[4][256];
    *(float4*)&ps[wave][c] = make_float4(a0, a1, a2, a3);
    __syncthreads();
    int t = threadIdx.x;
    float s = ps[0][t] + ps[1][t] + ps[2][t] + ps[3][t];
    float inv = HS_INV / fmaxf((float)(end - start), 1.0f);
    pooled16[(size_t)(side * kG + g) * kGH + t] = (_Float16)(s * inv);
}

// entity gather: e16[r][k] = fp16(relu(emb[ent[r]][k])), r in [0,2G)
__global__ void egather_kernel(const float* __restrict__ emb,
                               const int* __restrict__ ent1, const int* __restrict__ ent2,
                               _Float16* __restrict__ e16) {
    int rr = blockIdx.x;
    int idx = (rr < kG) ? ent1[rr] : ent2[rr - kG];
    int k = threadIdx.x;   // 128
    e16[(size_t)rr * kEMB + k] = (_Float16)fmaxf(emb[(size_t)idx * kEMB + k], 0.f);
}

// egs prep: egs16[g][k] = fp16(relu(eg1[g][k] + eg2[g][k]))
__global__ void egsprep_kernel(const _Float16* __restrict__ gfc16,
                               const _Float16* __restrict__ ento16,
                               _Float16* __restrict__ egs16) {
    int idx = blockIdx.x * 256 + threadIdx.x;   // 0..65535
    int g = idx >> 6;                            // 0..1023
    int k8 = (idx & 63) * 8;                     // 0..504
    const _Float16* src = (k8 < kGH) ? gfc16 : ento16;
    int kk = (k8 < kGH) ? k8 : k8 - kGH;
    half8v a = *(const half8v*)(src + (size_t)g * kGH + kk);
    half8v b = *(const half8v*)(src + (size_t)(g + kG) * kGH + kk);
    half8v o;
    #pragma unroll
    for (int u = 0; u < 8; u++) o[u] = (_Float16)fmaxf((float)a[u] + (float)b[u], 0.f);
    *(half8v*)(egs16 + (size_t)g * kHID + k8) = o;
}

// ---------------------------------------------------------------------------
// Host launch
// ---------------------------------------------------------------------------
static inline char* carve(char*& p, size_t bytes) {
    char* r = p;
    p += (bytes + 255) & ~(size_t)255;
    return r;
}

extern "C" void kernel_launch(void* const* d_in, const int* in_sizes, int n_in,
                              void* d_out, int out_size, void* d_ws, size_t ws_size,
                              hipStream_t stream) {
    const int*   x1       = (const int*)d_in[0];
    const int*   ei1      = (const int*)d_in[1];
    const int*   ent1     = (const int*)d_in[2];
    const int*   batch1   = (const int*)d_in[3];
    const int*   x2       = (const int*)d_in[4];
    const int*   ei2      = (const int*)d_in[5];
    const int*   ent2     = (const int*)d_in[6];
    const int*   batch2   = (const int*)d_in[7];
    const float* atom_emb = (const float*)d_in[8];
    const float* gW1      = (const float*)d_in[9];
    const float* gb1      = (const float*)d_in[10];
    const float* gW2      = (const float*)d_in[11];
    const float* gb2      = (const float*)d_in[12];
    const float* fcW      = (const float*)d_in[13];
    const float* fcb      = (const float*)d_in[14];
    const float* ent_emb  = (const float*)d_in[15];
    const float* eW1      = (const float*)d_in[16];
    const float* eb1      = (const float*)d_in[17];
    const float* eW2      = (const float*)d_in[18];
    const float* eb2      = (const float*)d_in[19];
    const float* dW1      = (const float*)d_in[20];
    const float* db1      = (const float*)d_in[21];
    const float* dW2      = (const float*)d_in[22];
    const float* db2      = (const float*)d_in[23];
    const float* dW3      = (const float*)d_in[24];
    const float* db3      = (const float*)d_in[25];
    float* out = (float*)d_out;

    // Workspace carve (no zeroed spans needed — binp3 writes all counts).
    char* p = (char*)d_ws;
    unsigned char* h4_8 = (unsigned char*)carve(p, (size_t)2 * kN * kGH);  // fp8 h4
    unsigned char* hs8  = (unsigned char*)carve(p, (size_t)2 * kN * kGH);  // fp8 hs
    unsigned short* col_ell = (unsigned short*)carve(p, (size_t)2 * kN * kMD * 2);
    unsigned int* ebuf = (unsigned int*)carve(p, (size_t)2 * kE * 4);
    int*   poff    = (int*)  carve(p, (size_t)2 * kNBKT * 256 * 4);
    int*   btot    = (int*)  carve(p, (size_t)2 * kNBKT * 4);
    int*   bbase   = (int*)  carve(p, (size_t)2 * (kNBKT + 1) * 4);
    int*   counts  = (int*)  carve(p, (size_t)2 * kN * 4);
    float* dinv    = (float*)carve(p, (size_t)2 * kN * 4);
    int2*  xd      = (int2*) carve(p, (size_t)2 * kN * 8);
    int*   gstart  = (int*)  carve(p, (size_t)2 * (kG + 1) * 4);
    float* M11     = (float*)carve(p, 11 * kGH * 4);
    _Float16* w2t  = (_Float16*)carve(p, (size_t)kGH * kGH * 2);
    _Float16* m11t = (_Float16*)carve(p, (size_t)256 * 32 * 2);
    _Float16* wt16 = (_Float16*)carve(p, (size_t)2 * kN * 32 * 2);
    // fp16 tail buffers
    _Float16* pooled16 = (_Float16*)carve(p, (size_t)2 * kG * kGH * 2);
    _Float16* gfc16    = (_Float16*)carve(p, (size_t)2 * kG * kGH * 2);
    _Float16* e16      = (_Float16*)carve(p, (size_t)2 * kG * kEMB * 2);
    _Float16* etmp16   = (_Float16*)carve(p, (size_t)2 * kG * kEH * 2);
    _Float16* ento16   = (_Float16*)carve(p, (size_t)2 * kG * kEH * 2);
    _Float16* egs16    = (_Float16*)carve(p, (size_t)kG * kHID * 2);
    _Float16* dh1_16   = (_Float16*)carve(p, (size_t)kG * kHID * 2);
    _Float16* dh2_16   = (_Float16*)carve(p, (size_t)kG * kHID * 2);
    // fp16 transposed tail weights
    _Float16* dW1t = (_Float16*)carve(p, (size_t)kHID * kHID * 2);
    _Float16* dW2t = (_Float16*)carve(p, (size_t)kHID * kHID * 2);
    _Float16* dW3t = (_Float16*)carve(p, (size_t)kOUT * kHID * 2);
    _Float16* fcWt = (_Float16*)carve(p, (size_t)kGH * kGH * 2);
    _Float16* eW1t = (_Float16*)carve(p, (size_t)kEH * kEMB * 2);
    _Float16* eW2t = (_Float16*)carve(p, (size_t)kEH * kEH * 2);

    // --- Graph structure via LDS binning (zero global atomics) ---
    prep_kernel<<<299, 256, 0, stream>>>(atom_emb, gW1, gW2, M11, w2t, m11t);
    wtrans_kernel<<<2944, 256, 0, stream>>>(dW1, dW2, dW3, fcW, eW1, eW2,
                                            dW1t, dW2t, dW3t, fcWt, eW1t, eW2t);
    gbounds_kernel<<<dim3((kG + 256) / 256, 2), 256, 0, stream>>>(batch1, batch2, gstart);
    binp1_kernel<<<dim3(kPBLK, 2), 256, 0, stream>>>(ei1, ei2, poff);
    scanA_kernel<<<dim3(kNBKT, 2), 256, 0, stream>>>(poff, btot);
    scanB_kernel<<<2, 256, 0, stream>>>(btot, bbase);
    binp2_kernel<<<dim3(kPBLK, 2), 256, 0, stream>>>(ei1, ei2, poff, bbase, ebuf);
    binp3_kernel<<<dim3(kNBKT, 2), 256, 0, stream>>>(ebuf, bbase, col_ell, counts,
                                                     dinv, xd, x1, x2);
    // --- Conv1 histogram, edge-centric (LDS float atomics) -> wt16 ---
    binp4_kernel<<<dim3(kNBKT, 2), 256, 0, stream>>>(ebuf, bbase, xd, wt16);
    // --- Fused conv1-GEMM + conv2-GEMM: hs8 directly from wt16 (no h2) ---
    gemm2f_kernel<<<dim3((kN + 127) / 128, kGH / 128, 2), 256, 0, stream>>>(
        wt16, m11t, gb1, w2t, dinv, hs8);
    // --- Conv2 aggregate (R7-proven) -> h4 (fp8) ---
    aggregate2_kernel<<<dim3((kN + 3) / 4, 2), 256, 0, stream>>>(hs8, dinv, counts, col_ell,
                                                                 gb2, h4_8);
    // --- Fast parallel mean-pool (fp8 in) -> pooled16 ---
    poolfast_kernel<<<dim3(kG, 2), 256, 0, stream>>>(h4_8, gstart, pooled16);
    // --- Entity gather (fp16) ---
    egather_kernel<<<2 * kG, 128, 0, stream>>>(ent_emb, ent1, ent2, e16);

    // --- Tail GEMMs, all fp16 MFMA (fp32 accum) ---
    gemm_tail_kernel<<<dim3(2 * kG / 64, kGH / 64), 256, 0, stream>>>(
        pooled16, fcWt, gfc16, kGH, kGH, fcb, 0, 0);
    gemm_tail_kernel<<<dim3(2 * kG / 64, kEH / 64), 256, 0, stream>>>(
        e16, eW1t, etmp16, kEH, kEMB, eb1, 1, 0);
    gemm_tail_kernel<<<dim3(2 * kG / 64, kEH / 64), 256, 0, stream>>>(
        etmp16, eW2t, ento16, kEH, kEH, eb2, 1, 0);
    egsprep_kernel<<<kG * kHID / 8 / 256, 256, 0, stream>>>(gfc16, ento16, egs16);
    gemm_tail_kernel<<<dim3(kG / 64, kHID / 64), 256, 0, stream>>>(
        egs16, dW1t, dh1_16, kHID, kHID, db1, 1, 0);
    gemm_tail_kernel<<<dim3(kG / 64, kHID / 64), 256, 0, stream>>>(
        dh1_16, dW2t, dh2_16, kHID, kHID, db2, 1, 0);
    gemm_tail_kernel<<<dim3(kG / 64, kOUT / 64), 256, 0, stream>>>(
        dh2_16, dW3t, out, kOUT, kHID, db3, 0, 1);
}

// Round 15
// 367.596 us; speedup vs baseline: 1.2437x; 1.0546x over previous
//
#include <hip/hip_runtime.h>
#include <hip/hip_fp16.h>

// Problem constants
static constexpr int kN = 50000;      // nodes per side
static constexpr int kE = 800000;     // edges per side
static constexpr int kG = 1024;       // graphs per batch
static constexpr int kEMB = 128;
static constexpr int kGH = 256;
static constexpr int kEH = 256;
static constexpr int kOUT = 128;
static constexpr int kHID = 512;
static constexpr int kNB = (kN + 255) / 256;   // 196 chunks per side
static constexpr int kMD = 64;        // ELL stride; deg ~ Poisson(16), P(deg>=64)~e^-125
static constexpr int kNBKT = 196;     // dst buckets of 256 nodes (50000 -> 196)
static constexpr int kEPB = 3125;     // edges per bin block; 256 blocks exactly
static constexpr int kPBLK = 256;     // bin blocks per side (256*3125 = 800000)

typedef __attribute__((ext_vector_type(8))) _Float16 half8v;
typedef __attribute__((ext_vector_type(4))) _Float16 half4v;
typedef __attribute__((ext_vector_type(4))) float floatx4;
typedef __attribute__((ext_vector_type(2))) float floatx2;

// NOTE (R6): cross-XCD plain-data handoff through grid.sync() gave stale reads.
// NOTE (R7/R12): device atomics memory-side; floor is OP-COUNT ~21/ns.
// (R2) fp8 hs: 659->616us, absmax UNCHANGED. (R6) LDS bucket binning: ->523us.
// (R7) fp16-MFMA tail: ->439us; aggregate2 ~61us = proven gather-FETCH floor
// (R14 confirmed: halving its write didn't move duration).
// (R8-R11) agg+pool fusion arc regressed; reverted R12 (398.1us).
// (R13) h2 eliminated via on-the-fly conv1 in gemm2f: -3us (mid-stack is
// latency/dispatch-bound, not byte-bound). (R14) binp4 edge-centric wt +
// fp8 h4: -7.4us.
// This revision (R15): DISPATCH REDUCTION, zero numeric change. 20->15:
// setup=prep+wtrans+gbounds (block-range merge); scanB/bbase deleted (binp2/
// binp3/binp4 re-derive bucket bases from btot via in-LDS 196-scan); pooleg=
// poolfast+egather (y==2); gemm_pair = fc & eW1 (independent) via blockIdx.z.
// binp3->binp4 boundary is fundamental (binp4 gathers xd[src] produced by
// binp3 across buckets).

// fp8 fixed scale: |hs| <~ 0.2 typ; x128 keeps values in e4m3 normal range.
#define HS_SCALE 128.0f
#define HS_INV   (1.0f / 128.0f)

__device__ inline void acc_fp8x4(unsigned int w, float& a0, float& a1, float& a2, float& a3) {
    floatx2 lo = __builtin_amdgcn_cvt_pk_f32_fp8(w, false);
    floatx2 hi = __builtin_amdgcn_cvt_pk_f32_fp8(w, true);
    a0 += lo[0]; a1 += lo[1]; a2 += hi[0]; a3 += hi[1];
}

// ---------------------------------------------------------------------------
// setup: prep (blocks 0..298) + wtrans (299..3242) + gbounds (3243..3252).
// ---------------------------------------------------------------------------
__global__ void setup_kernel(const float* __restrict__ atom_emb, const float* __restrict__ gW1,
                             const float* __restrict__ gW2,
                             float* __restrict__ M11, _Float16* __restrict__ w2t,
                             _Float16* __restrict__ m11t,
                             const float* __restrict__ dW1, const float* __restrict__ dW2,
                             const float* __restrict__ dW3, const float* __restrict__ fcW,
                             const float* __restrict__ eW1, const float* __restrict__ eW2,
                             _Float16* __restrict__ dW1t, _Float16* __restrict__ dW2t,
                             _Float16* __restrict__ dW3t, _Float16* __restrict__ fcWt,
                             _Float16* __restrict__ eW1t, _Float16* __restrict__ eW2t,
                             const int* __restrict__ batch1, const int* __restrict__ batch2,
                             int* __restrict__ gstart) {
    int blk = blockIdx.x;
    int tid = threadIdx.x;
    if (blk < 299) {
        int i = blk * 256 + tid;
        if (blk < 256) {
            int k = i >> 8, n = i & 255;
            w2t[(size_t)n * kGH + k] = (_Float16)gW2[(size_t)k * kGH + n];
        } else {
            int j = i - 65536;
            if (j < 11 * kGH) {
                int r = j >> 8, c = j & 255;
                float s = 0.f;
                for (int k = 0; k < kEMB; k++) s += atom_emb[r * kEMB + k] * gW1[k * kGH + c];
                M11[j] = s;
            } else if (j < 11 * kGH + 256 * 32) {
                int j2 = j - 11 * kGH;
                int n = j2 >> 5, k = j2 & 31;     // m11t[n][k] = M11[k][n], 0 for k>=11
                float s = 0.f;
                if (k < 11)
                    for (int p = 0; p < kEMB; p++) s += atom_emb[k * kEMB + p] * gW1[p * kGH + n];
                m11t[j2] = (_Float16)s;
            }
        }
    } else if (blk < 299 + 2944) {
        int b = blk - 299;
        const float* src; _Float16* dst; int K, N, j0;
        if (b < 1024)      { src = dW1; dst = dW1t; K = 512; N = 512; j0 = b * 256; }
        else if (b < 2048) { src = dW2; dst = dW2t; K = 512; N = 512; j0 = (b - 1024) * 256; }
        else if (b < 2304) { src = dW3; dst = dW3t; K = 512; N = 128; j0 = (b - 2048) * 256; }
        else if (b < 2560) { src = fcW; dst = fcWt; K = 256; N = 256; j0 = (b - 2304) * 256; }
        else if (b < 2688) { src = eW1; dst = eW1t; K = 128; N = 256; j0 = (b - 2560) * 256; }
        else               { src = eW2; dst = eW2t; K = 256; N = 256; j0 = (b - 2688) * 256; }
        int j = j0 + tid;                    // dst linear: n*K + k
        int n = j / K, k = j - n * K;
        dst[j] = (_Float16)src[(size_t)k * N + n];
    } else {
        int b2 = blk - (299 + 2944);         // 0..9
        int side = b2 / 5;
        int g = (b2 % 5) * 256 + tid;
        if (g <= kG) {
            const int* batch = side ? batch2 : batch1;
            int lo = 0, hi = kN;
            while (lo < hi) { int mid = (lo + hi) >> 1; if (batch[mid] < g) lo = mid + 1; else hi = mid; }
            gstart[side * (kG + 1) + g] = lo;
        }
    }
}

// ---------------------------------------------------------------------------
// binp1: per-block LDS histogram over 196 dst-buckets.
// ---------------------------------------------------------------------------
__global__ void binp1_kernel(const int* __restrict__ ei1, const int* __restrict__ ei2,
                             int* __restrict__ poff) {
    int side = blockIdx.y;
    const int* dst = (side ? ei2 : ei1) + kE;
    __shared__ int hist[kNBKT];
    int t = threadIdx.x;
    if (t < kNBKT) hist[t] = 0;
    __syncthreads();
    int base = blockIdx.x * kEPB;
    for (int j = t; j < kEPB; j += 256)
        atomicAdd(&hist[dst[base + j] >> 8], 1);
    __syncthreads();
    if (t < kNBKT) poff[((side * kNBKT + t) << 8) | blockIdx.x] = hist[t];
}

// scanA: per (side,bucket) exclusive scan over the 256 block counts; totals.
__global__ void scanA_kernel(int* __restrict__ poff, int* __restrict__ btot) {
    int b = blockIdx.x, side = blockIdx.y, t = threadIdx.x;
    __shared__ int s[256];
    int idx = ((side * kNBKT + b) << 8) | t;
    int v = poff[idx];
    s[t] = v;
    __syncthreads();
    for (int o = 1; o < 256; o <<= 1) {
        int u = (t >= o) ? s[t - o] : 0;
        __syncthreads();
        s[t] += u;
        __syncthreads();
    }
    poff[idx] = s[t] - v;
    if (t == 255) btot[side * kNBKT + b] = s[255];
}

// ---------------------------------------------------------------------------
// binp2: block-local LDS bucket-sort, coalesced bucket-major write-out.
// Bucket bases re-derived internally from btot (scanB deleted).
// ---------------------------------------------------------------------------
__launch_bounds__(256)
__global__ void binp2_kernel(const int* __restrict__ ei1, const int* __restrict__ ei2,
                             const int* __restrict__ poff, const int* __restrict__ btot,
                             unsigned int* __restrict__ ebuf) {
    int side = blockIdx.y, blk = blockIdx.x, t = threadIdx.x;
    const int* ei = side ? ei2 : ei1;
    __shared__ int hist[kNBKT], lb[kNBKT], gb[kNBKT], scanbuf[256];
    __shared__ unsigned int sorted[kEPB];
    // btot exclusive scan -> per-bucket global base (register gbb).
    int bv = (t < kNBKT) ? btot[side * kNBKT + t] : 0;
    scanbuf[t] = bv;
    __syncthreads();
    for (int o = 1; o < 256; o <<= 1) {
        int u = (t >= o) ? scanbuf[t - o] : 0;
        __syncthreads();
        scanbuf[t] += u;
        __syncthreads();
    }
    int gbb = scanbuf[t] - bv;
    __syncthreads();
    if (t < kNBKT) hist[t] = 0;
    __syncthreads();
    int base = blk * kEPB;
    for (int j = t; j < kEPB; j += 256)
        atomicAdd(&hist[ei[kE + base + j] >> 8], 1);
    __syncthreads();
    int v = (t < kNBKT) ? hist[t] : 0;
    scanbuf[t] = v;
    __syncthreads();
    for (int o = 1; o < 256; o <<= 1) {
        int u = (t >= o) ? scanbuf[t - o] : 0;
        __syncthreads();
        scanbuf[t] += u;
        __syncthreads();
    }
    if (t < kNBKT) {
        lb[t] = scanbuf[t] - v;
        gb[t] = gbb + poff[((side * kNBKT + t) << 8) | blk];
        hist[t] = 0;
    }
    __syncthreads();
    for (int j = t; j < kEPB; j += 256) {
        int s_ = ei[base + j];
        int d  = ei[kE + base + j];
        int b  = d >> 8;
        int r  = atomicAdd(&hist[b], 1);
        sorted[lb[b] + r] = ((unsigned int)d << 16) | (unsigned int)s_;
    }
    __syncthreads();
    for (int j = t; j < kEPB; j += 256) {
        unsigned int val = sorted[j];
        int b = val >> 24;
        int gpos = gb[b] + (j - lb[b]);
        ebuf[(size_t)side * kE + gpos] = val;
    }
}

// ---------------------------------------------------------------------------
// binp3: one block per bucket; LDS slot counters; col_ell stores in a 32KB
// window. Bucket range from internal btot scan. Epilogue: counts, dinv, xd.
// ---------------------------------------------------------------------------
__global__ void binp3_kernel(const unsigned int* __restrict__ ebuf, const int* __restrict__ btot,
                             unsigned short* __restrict__ col_ell, int* __restrict__ counts,
                             float* __restrict__ dinv, int2* __restrict__ xd,
                             const int* __restrict__ x1, const int* __restrict__ x2) {
    int b = blockIdx.x, side = blockIdx.y, t = threadIdx.x;
    __shared__ int s[256];
    __shared__ int cnt[256];
    int bv = (t < kNBKT) ? btot[side * kNBKT + t] : 0;
    s[t] = bv;
    cnt[t] = 0;
    __syncthreads();
    for (int o = 1; o < 256; o <<= 1) {
        int u = (t >= o) ? s[t - o] : 0;
        __syncthreads();
        s[t] += u;
        __syncthreads();
    }
    int start = (b > 0) ? s[b - 1] : 0;
    int end   = s[b];
    for (int k = start + t; k < end; k += 256) {
        unsigned int v = ebuf[(size_t)side * kE + k];
        int d8 = (v >> 16) & 255;
        int slot = atomicAdd(&cnt[d8], 1);
        if (slot > kMD - 1) slot = kMD - 1;
        int node = (b << 8) | d8;
        col_ell[((size_t)side * kN + node) * kMD + slot] = (unsigned short)(v & 0xFFFFu);
    }
    __syncthreads();
    int node = (b << 8) | t;
    if (node < kN) {
        int d = cnt[t];
        counts[side * kN + node] = d;
        float dv = rsqrtf((float)(d + 1));           // +1 self-loop
        dinv[side * kN + node] = dv;
        const int* x = side ? x2 : x1;
        xd[side * kN + node] = make_int2(x[node], __float_as_int(dv));
    }
}

// ---------------------------------------------------------------------------
// binp4: edge-centric conv1 histogram; bucket range from internal btot scan.
// wtl[dst&255][x[src]] += dinv[src] via LDS float atomics; epilogue emits
// wt16[v][32] (wt'[s] = dv*wtl[s] + dv^2*delta(x[v]=s), zero pad 16..31).
// ---------------------------------------------------------------------------
__global__ void binp4_kernel(const unsigned int* __restrict__ ebuf, const int* __restrict__ btot,
                             const int2* __restrict__ xd, _Float16* __restrict__ wt16) {
    int b = blockIdx.x, side = blockIdx.y, t = threadIdx.x;
    const int2* xdb = xd + (size_t)side * kN;
    __shared__ int s[256];
    __shared__ float wtl[256][16];
    int bv = (t < kNBKT) ? btot[side * kNBKT + t] : 0;
    s[t] = bv;
    #pragma unroll
    for (int q = 0; q < 16; q++) wtl[t][q] = 0.f;
    __syncthreads();
    for (int o = 1; o < 256; o <<= 1) {
        int u = (t >= o) ? s[t - o] : 0;
        __syncthreads();
        s[t] += u;
        __syncthreads();
    }
    int start = (b > 0) ? s[b - 1] : 0;
    int end   = s[b];
    for (int k = start + t; k < end; k += 256) {
        unsigned int v = ebuf[(size_t)side * kE + k];
        int src = v & 0xFFFFu;
        int d8 = (v >> 16) & 255;
        int2 xs = xdb[src];
        atomicAdd(&wtl[d8][xs.x], __int_as_float(xs.y));
    }
    __syncthreads();
    int node = (b << 8) | t;
    if (node < kN) {
        int2 xv = xdb[node];
        float dv = __int_as_float(xv.y);
        float dv2 = dv * dv;
        _Float16* wb = wt16 + ((size_t)side * kN + node) * 32;
        half8v o0, o1, z;
        #pragma unroll
        for (int q = 0; q < 8; q++) {
            o0[q] = (_Float16)(dv * wtl[t][q] + ((xv.x == q) ? dv2 : 0.f));
            o1[q] = (_Float16)(dv * wtl[t][q + 8] + ((xv.x == q + 8) ? dv2 : 0.f));
            z[q] = (_Float16)0.f;
        }
        *(half8v*)(wb) = o0;
        *(half8v*)(wb + 8) = o1;
        *(half8v*)(wb + 16) = z;
        *(half8v*)(wb + 24) = z;
    }
}

// ---------------------------------------------------------------------------
// Fused conv1-GEMM + conv2-GEMM: hs8 = fp8(128*dinv ⊙ (relu(wt16@M11+b1) @ W2))
// h2 computed on the fly per k0-step via swapped-operand mfma.
// ---------------------------------------------------------------------------
__launch_bounds__(256)
__global__ void gemm2f_kernel(const _Float16* __restrict__ wt16,
                              const _Float16* __restrict__ m11t,
                              const float* __restrict__ b1,
                              const _Float16* __restrict__ Bt,
                              const float* __restrict__ dinv,
                              unsigned char* __restrict__ C) {
    __shared__ _Float16 As[128][72];
    __shared__ _Float16 Bs[128][72];

    int side = blockIdx.z;
    const _Float16* Aw = wt16 + (size_t)side * kN * 32;
    const float* db = dinv + (size_t)side * kN;
    unsigned char* Cb = C + (size_t)side * kN * kGH;

    int tid = threadIdx.x;
    int wave = tid >> 6, lane = tid & 63;
    int quad = lane >> 4, r = lane & 15;
    int wm = wave >> 1, wn = wave & 1;
    int row0 = blockIdx.x * 128;
    int col0 = blockIdx.y * 128;

    floatx4 acc[4][4];
    #pragma unroll
    for (int i = 0; i < 4; i++)
        #pragma unroll
        for (int j = 0; j < 4; j++) acc[i][j] = (floatx4){0.f, 0.f, 0.f, 0.f};

    half8v afw[2];
    #pragma unroll
    for (int mt = 0; mt < 2; mt++) {
        int gr = row0 + wave * 32 + mt * 16 + r;
        if (gr >= kN) gr = kN - 1;
        afw[mt] = *(const half8v*)(Aw + (size_t)gr * 32 + quad * 8);
    }

    for (int k0 = 0; k0 < kGH; k0 += 64) {
        #pragma unroll
        for (int u = 0; u < 4; u++) {
            int idx = tid + u * 256;           // 0..1023
            int row = idx >> 3;                // 0..127
            int seg = (idx & 7) * 8;           // 0..56
            *(half8v*)&Bs[row][seg] = *(const half8v*)(Bt + (size_t)(col0 + row) * kGH + k0 + seg);
        }
        #pragma unroll
        for (int nt = 0; nt < 4; nt++) {
            half8v bfw = *(const half8v*)(m11t + (size_t)(k0 + nt * 16 + r) * 32 + quad * 8);
            float4 bia = *(const float4*)(b1 + k0 + nt * 16 + quad * 4);
            #pragma unroll
            for (int mt = 0; mt < 2; mt++) {
                floatx4 d = (floatx4){0.f, 0.f, 0.f, 0.f};
                d = __builtin_amdgcn_mfma_f32_16x16x32_f16(bfw, afw[mt], d, 0, 0, 0);
                half4v o;
                o[0] = (_Float16)fmaxf(d[0] + bia.x, 0.f);
                o[1] = (_Float16)fmaxf(d[1] + bia.y, 0.f);
                o[2] = (_Float16)fmaxf(d[2] + bia.z, 0.f);
                o[3] = (_Float16)fmaxf(d[3] + bia.w, 0.f);
                *(half4v*)&As[wave * 32 + mt * 16 + r][nt * 16 + quad * 4] = o;
            }
        }
        __syncthreads();
        #pragma unroll
        for (int ks = 0; ks < 2; ks++) {
            half8v af[4], bf[4];
            #pragma unroll
            for (int mt = 0; mt < 4; mt++)
                af[mt] = *(const half8v*)&As[wm * 64 + mt * 16 + r][ks * 32 + quad * 8];
            #pragma unroll
            for (int nt = 0; nt < 4; nt++)
                bf[nt] = *(const half8v*)&Bs[wn * 64 + nt * 16 + r][ks * 32 + quad * 8];
            #pragma unroll
            for (int mt = 0; mt < 4; mt++)
                #pragma unroll
                for (int nt = 0; nt < 4; nt++)
                    acc[mt][nt] = __builtin_amdgcn_mfma_f32_16x16x32_f16(af[mt], bf[nt],
                                                                         acc[mt][nt], 0, 0, 0);
        }
        __syncthreads();
    }

    #pragma unroll
    for (int mt = 0; mt < 4; mt++) {
        #pragma unroll
        for (int i = 0; i < 4; i++) {
            int grow = row0 + wm * 64 + mt * 16 + quad * 4 + i;
            if (grow >= kN) continue;
            float rsq = db[grow] * HS_SCALE;
            #pragma unroll
            for (int nt = 0; nt < 4; nt++) {
                int gcol = col0 + wn * 64 + nt * 16 + r;
                float q = acc[mt][nt][i] * rsq;
                Cb[(size_t)grow * kGH + gcol] =
                    (unsigned char)__builtin_amdgcn_cvt_pk_fp8_f32(q, q, 0, false);
            }
        }
    }
}

// ---------------------------------------------------------------------------
// Unified tail GEMM via MFMA f16 (fp32 accum): C = [relu](A @ B + bias)
// ---------------------------------------------------------------------------
__launch_bounds__(256)
__global__ void gemm_tail_kernel(const _Float16* __restrict__ A,
                                 const _Float16* __restrict__ Bt,
                                 void* __restrict__ Cout,
                                 int N, int K,
                                 const float* __restrict__ bias,
                                 int relu, int f32out) {
    __shared__ _Float16 As[64][72];
    __shared__ _Float16 Bs[64][72];
    int tid = threadIdx.x;
    int wave = tid >> 6, lane = tid & 63;
    int quad = lane >> 4, r = lane & 15;
    int wm = wave >> 1, wn = wave & 1;
    int row0 = blockIdx.x * 64, col0 = blockIdx.y * 64;

    floatx4 acc[2][2];
    #pragma unroll
    for (int i = 0; i < 2; i++)
        #pragma unroll
        for (int j = 0; j < 2; j++) acc[i][j] = (floatx4){0.f, 0.f, 0.f, 0.f};

    for (int k0 = 0; k0 < K; k0 += 64) {
        #pragma unroll
        for (int u = 0; u < 2; u++) {
            int idx = tid + u * 256;           // 0..511
            int row = idx >> 3;                // 0..63
            int seg = (idx & 7) * 8;           // 0..56
            *(half8v*)&As[row][seg] = *(const half8v*)(A + (size_t)(row0 + row) * K + k0 + seg);
            *(half8v*)&Bs[row][seg] = *(const half8v*)(Bt + (size_t)(col0 + row) * K + k0 + seg);
        }
        __syncthreads();
        #pragma unroll
        for (int ks = 0; ks < 2; ks++) {
            half8v af[2], bf[2];
            #pragma unroll
            for (int mt = 0; mt < 2; mt++)
                af[mt] = *(const half8v*)&As[wm * 32 + mt * 16 + r][ks * 32 + quad * 8];
            #pragma unroll
            for (int nt = 0; nt < 2; nt++)
                bf[nt] = *(const half8v*)&Bs[wn * 32 + nt * 16 + r][ks * 32 + quad * 8];
            #pragma unroll
            for (int mt = 0; mt < 2; mt++)
                #pragma unroll
                for (int nt = 0; nt < 2; nt++)
                    acc[mt][nt] = __builtin_amdgcn_mfma_f32_16x16x32_f16(af[mt], bf[nt],
                                                                         acc[mt][nt], 0, 0, 0);
        }
        __syncthreads();
    }

    #pragma unroll
    for (int mt = 0; mt < 2; mt++) {
        #pragma unroll
        for (int i = 0; i < 4; i++) {
            int grow = row0 + wm * 32 + mt * 16 + quad * 4 + i;
            #pragma unroll
            for (int nt = 0; nt < 2; nt++) {
                int gcol = col0 + wn * 32 + nt * 16 + r;
                float v = acc[mt][nt][i] + bias[gcol];
                if (relu) v = fmaxf(v, 0.f);
                if (f32out) ((float*)Cout)[(size_t)grow * N + gcol] = v;
                else ((_Float16*)Cout)[(size_t)grow * N + gcol] = (_Float16)v;
            }
        }
    }
}

// ---------------------------------------------------------------------------
// gemm_pair: the two INDEPENDENT first tail GEMMs in one launch (z=0: fc,
// z=1: eW1). Same M=2048, N=256; K/relu differ per z. Body = gemm_tail.
// ---------------------------------------------------------------------------
__launch_bounds__(256)
__global__ void gemm_pair_kernel(const _Float16* __restrict__ pooled16,
                                 const _Float16* __restrict__ fcWt,
                                 _Float16* __restrict__ gfc16,
                                 const float* __restrict__ fcb,
                                 const _Float16* __restrict__ e16,
                                 const _Float16* __restrict__ eW1t,
                                 _Float16* __restrict__ etmp16,
                                 const float* __restrict__ eb1) {
    const _Float16* A; const _Float16* Bt; _Float16* Cout; const float* bias;
    int K, relu;
    if (blockIdx.z == 0) { A = pooled16; Bt = fcWt; Cout = gfc16; bias = fcb; K = kGH; relu = 0; }
    else                 { A = e16; Bt = eW1t; Cout = etmp16; bias = eb1; K = kEMB; relu = 1; }
    const int N = kGH;

    __shared__ _Float16 As[64][72];
    __shared__ _Float16 Bs[64][72];
    int tid = threadIdx.x;
    int wave = tid >> 6, lane = tid & 63;
    int quad = lane >> 4, r = lane & 15;
    int wm = wave >> 1, wn = wave & 1;
    int row0 = blockIdx.x * 64, col0 = blockIdx.y * 64;

    floatx4 acc[2][2];
    #pragma unroll
    for (int i = 0; i < 2; i++)
        #pragma unroll
        for (int j = 0; j < 2; j++) acc[i][j] = (floatx4){0.f, 0.f, 0.f, 0.f};

    for (int k0 = 0; k0 < K; k0 += 64) {
        #pragma unroll
        for (int u = 0; u < 2; u++) {
            int idx = tid + u * 256;
            int row = idx >> 3;
            int seg = (idx & 7) * 8;
            *(half8v*)&As[row][seg] = *(const half8v*)(A + (size_t)(row0 + row) * K + k0 + seg);
            *(half8v*)&Bs[row][seg] = *(const half8v*)(Bt + (size_t)(col0 + row) * K + k0 + seg);
        }
        __syncthreads();
        #pragma unroll
        for (int ks = 0; ks < 2; ks++) {
            half8v af[2], bf[2];
            #pragma unroll
            for (int mt = 0; mt < 2; mt++)
                af[mt] = *(const half8v*)&As[wm * 32 + mt * 16 + r][ks * 32 + quad * 8];
            #pragma unroll
            for (int nt = 0; nt < 2; nt++)
                bf[nt] = *(const half8v*)&Bs[wn * 32 + nt * 16 + r][ks * 32 + quad * 8];
            #pragma unroll
            for (int mt = 0; mt < 2; mt++)
                #pragma unroll
                for (int nt = 0; nt < 2; nt++)
                    acc[mt][nt] = __builtin_amdgcn_mfma_f32_16x16x32_f16(af[mt], bf[nt],
                                                                         acc[mt][nt], 0, 0, 0);
        }
        __syncthreads();
    }

    #pragma unroll
    for (int mt = 0; mt < 2; mt++) {
        #pragma unroll
        for (int i = 0; i < 4; i++) {
            int grow = row0 + wm * 32 + mt * 16 + quad * 4 + i;
            #pragma unroll
            for (int nt = 0; nt < 2; nt++) {
                int gcol = col0 + wn * 32 + nt * 16 + r;
                float v = acc[mt][nt][i] + bias[gcol];
                if (relu) v = fmaxf(v, 0.f);
                Cout[(size_t)grow * N + gcol] = (_Float16)v;
            }
        }
    }
}

// ---------------------------------------------------------------------------
// Conv2 aggregate (proven floor): one wave per node, no barriers. fp8 h4 out.
// ---------------------------------------------------------------------------
__global__ void aggregate2_kernel(const unsigned char* __restrict__ hs, const float* __restrict__ dinv,
                                  const int* __restrict__ counts,
                                  const unsigned short* __restrict__ col_ell,
                                  const float* __restrict__ bias, unsigned char* __restrict__ out) {
    int side = blockIdx.y;
    const unsigned char* hb = hs + (size_t)side * kN * kGH;
    const float* dv_ = dinv + side * kN;
    const int* deg = counts + side * kN;
    const unsigned short* ci = col_ell + (size_t)side * kN * kMD;
    unsigned char* ob = out + (size_t)side * kN * kGH;

    int wave = threadIdx.x >> 6;
    int lane = threadIdx.x & 63;
    int v = blockIdx.x * 4 + wave;
    if (v >= kN) return;
    int c = lane * 4;
    float4 bia = *(const float4*)(bias + c);
    float dv = dv_[v];
    float a0 = 0.f, a1 = 0.f, a2 = 0.f, a3 = 0.f;
    acc_fp8x4(*(const unsigned int*)(hb + (size_t)v * kGH + c), a0, a1, a2, a3);  // self-loop
    int cnt = min(deg[v], kMD);
    int idxl = (lane < cnt) ? (int)ci[(size_t)v * kMD + lane] : 0;
    int j = 0;
    for (; j + 16 <= cnt; j += 16) {
        unsigned int w[16];
        #pragma unroll
        for (int u = 0; u < 16; u++)
            w[u] = *(const unsigned int*)(hb + (size_t)__shfl(idxl, j + u) * kGH + c);
        #pragma unroll
        for (int u = 0; u < 16; u++) acc_fp8x4(w[u], a0, a1, a2, a3);
    }
    for (; j + 8 <= cnt; j += 8) {
        unsigned int w[8];
        #pragma unroll
        for (int u = 0; u < 8; u++)
            w[u] = *(const unsigned int*)(hb + (size_t)__shfl(idxl, j + u) * kGH + c);
        #pragma unroll
        for (int u = 0; u < 8; u++) acc_fp8x4(w[u], a0, a1, a2, a3);
    }
    for (; j < cnt; j++)
        acc_fp8x4(*(const unsigned int*)(hb + (size_t)__shfl(idxl, j) * kGH + c),
                  a0, a1, a2, a3);
    float f = dv * HS_INV;
    float q0 = fmaxf(f * a0 + bia.x, 0.f) * HS_SCALE;
    float q1 = fmaxf(f * a1 + bia.y, 0.f) * HS_SCALE;
    float q2 = fmaxf(f * a2 + bia.z, 0.f) * HS_SCALE;
    float q3 = fmaxf(f * a3 + bia.w, 0.f) * HS_SCALE;
    unsigned int w = __builtin_amdgcn_cvt_pk_fp8_f32(q0, q1, 0, false);
    w = __builtin_amdgcn_cvt_pk_fp8_f32(q2, q3, w, true);
    __builtin_nontemporal_store(w, (unsigned int*)(ob + (size_t)v * kGH + c));
}

// ---------------------------------------------------------------------------
// pooleg: mean-pool (y<2) + entity gather (y==2) in one dispatch.
// ---------------------------------------------------------------------------
__global__ void pooleg_kernel(const unsigned char* __restrict__ h,
                              const int* __restrict__ gstart,
                              _Float16* __restrict__ pooled16,
                              const float* __restrict__ emb,
                              const int* __restrict__ ent1, const int* __restrict__ ent2,
                              _Float16* __restrict__ e16) {
    if (blockIdx.y == 2) {
        int rr = blockIdx.x * 2 + (threadIdx.x >> 7);   // 0..2047
        int k = threadIdx.x & 127;
        int idx = (rr < kG) ? ent1[rr] : ent2[rr - kG];
        e16[(size_t)rr * kEMB + k] = (_Float16)fmaxf(emb[(size_t)idx * kEMB + k], 0.f);
        return;
    }
    int side = blockIdx.y;
    int g = blockIdx.x;
    const unsigned char* hb = h + (size_t)side * kN * kGH;
    int start = gstart[side * (kG + 1) + g];
    int end   = gstart[side * (kG + 1) + g + 1];
    int wave = threadIdx.x >> 6, lane = threadIdx.x & 63;
    int c = lane * 4;
    float a0 = 0.f, a1 = 0.f, a2 = 0.f, a3 = 0.f;
    for (int v = start + wave; v < end; v += 4)
        acc_fp8x4(*(const unsigned int*)(hb + (size_t)v * kGH + c), a0, a1, a2, a3);
    __shared__ float ps[4][256];
    *(float4*)&ps[wave][c] = make_float4(a0, a1, a2, a3);
    __syncthreads();
    int t = threadIdx.x;
    float s = ps[0][t] + ps[1][t] + ps[2][t] + ps[3][t];
    float inv = HS_INV / fmaxf((float)(end - start), 1.0f);
    pooled16[(size_t)(side * kG + g) * kGH + t] = (_Float16)(s * inv);
}

// egs prep: egs16[g][k] = fp16(relu(eg1[g][k] + eg2[g][k]))
__global__ void egsprep_kernel(const _Float16* __restrict__ gfc16,
                               const _Float16* __restrict__ ento16,
                               _Float16* __restrict__ egs16) {
    int idx = blockIdx.x * 256 + threadIdx.x;   // 0..65535
    int g = idx >> 6;                            // 0..1023
    int k8 = (idx & 63) * 8;                     // 0..504
    const _Float16* src = (k8 < kGH) ? gfc16 : ento16;
    int kk = (k8 < kGH) ? k8 : k8 - kGH;
    half8v a = *(const half8v*)(src + (size_t)g * kGH + kk);
    half8v b = *(const half8v*)(src + (size_t)(g + kG) * kGH + kk);
    half8v o;
    #pragma unroll
    for (int u = 0; u < 8; u++) o[u] = (_Float16)fmaxf((float)a[u] + (float)b[u], 0.f);
    *(half8v*)(egs16 + (size_t)g * kHID + k8) = o;
}

// ---------------------------------------------------------------------------
// Host launch
// ---------------------------------------------------------------------------
static inline char* carve(char*& p, size_t bytes) {
    char* r = p;
    p += (bytes + 255) & ~(size_t)255;
    return r;
}

extern "C" void kernel_launch(void* const* d_in, const int* in_sizes, int n_in,
                              void* d_out, int out_size, void* d_ws, size_t ws_size,
                              hipStream_t stream) {
    const int*   x1       = (const int*)d_in[0];
    const int*   ei1      = (const int*)d_in[1];
    const int*   ent1     = (const int*)d_in[2];
    const int*   batch1   = (const int*)d_in[3];
    const int*   x2       = (const int*)d_in[4];
    const int*   ei2      = (const int*)d_in[5];
    const int*   ent2     = (const int*)d_in[6];
    const int*   batch2   = (const int*)d_in[7];
    const float* atom_emb = (const float*)d_in[8];
    const float* gW1      = (const float*)d_in[9];
    const float* gb1      = (const float*)d_in[10];
    const float* gW2      = (const float*)d_in[11];
    const float* gb2      = (const float*)d_in[12];
    const float* fcW      = (const float*)d_in[13];
    const float* fcb      = (const float*)d_in[14];
    const float* ent_emb  = (const float*)d_in[15];
    const float* eW1      = (const float*)d_in[16];
    const float* eb1      = (const float*)d_in[17];
    const float* eW2      = (const float*)d_in[18];
    const float* eb2      = (const float*)d_in[19];
    const float* dW1      = (const float*)d_in[20];
    const float* db1      = (const float*)d_in[21];
    const float* dW2      = (const float*)d_in[22];
    const float* db2      = (const float*)d_in[23];
    const float* dW3      = (const float*)d_in[24];
    const float* db3      = (const float*)d_in[25];
    float* out = (float*)d_out;

    // Workspace carve (no zeroed spans needed — binp3 writes all counts).
    char* p = (char*)d_ws;
    unsigned char* h4_8 = (unsigned char*)carve(p, (size_t)2 * kN * kGH);  // fp8 h4
    unsigned char* hs8  = (unsigned char*)carve(p, (size_t)2 * kN * kGH);  // fp8 hs
    unsigned short* col_ell = (unsigned short*)carve(p, (size_t)2 * kN * kMD * 2);
    unsigned int* ebuf = (unsigned int*)carve(p, (size_t)2 * kE * 4);
    int*   poff    = (int*)  carve(p, (size_t)2 * kNBKT * 256 * 4);
    int*   btot    = (int*)  carve(p, (size_t)2 * kNBKT * 4);
    int*   counts  = (int*)  carve(p, (size_t)2 * kN * 4);
    float* dinv    = (float*)carve(p, (size_t)2 * kN * 4);
    int2*  xd      = (int2*) carve(p, (size_t)2 * kN * 8);
    int*   gstart  = (int*)  carve(p, (size_t)2 * (kG + 1) * 4);
    float* M11     = (float*)carve(p, 11 * kGH * 4);
    _Float16* w2t  = (_Float16*)carve(p, (size_t)kGH * kGH * 2);
    _Float16* m11t = (_Float16*)carve(p, (size_t)256 * 32 * 2);
    _Float16* wt16 = (_Float16*)carve(p, (size_t)2 * kN * 32 * 2);
    // fp16 tail buffers
    _Float16* pooled16 = (_Float16*)carve(p, (size_t)2 * kG * kGH * 2);
    _Float16* gfc16    = (_Float16*)carve(p, (size_t)2 * kG * kGH * 2);
    _Float16* e16      = (_Float16*)carve(p, (size_t)2 * kG * kEMB * 2);
    _Float16* etmp16   = (_Float16*)carve(p, (size_t)2 * kG * kEH * 2);
    _Float16* ento16   = (_Float16*)carve(p, (size_t)2 * kG * kEH * 2);
    _Float16* egs16    = (_Float16*)carve(p, (size_t)kG * kHID * 2);
    _Float16* dh1_16   = (_Float16*)carve(p, (size_t)kG * kHID * 2);
    _Float16* dh2_16   = (_Float16*)carve(p, (size_t)kG * kHID * 2);
    // fp16 transposed tail weights
    _Float16* dW1t = (_Float16*)carve(p, (size_t)kHID * kHID * 2);
    _Float16* dW2t = (_Float16*)carve(p, (size_t)kHID * kHID * 2);
    _Float16* dW3t = (_Float16*)carve(p, (size_t)kOUT * kHID * 2);
    _Float16* fcWt = (_Float16*)carve(p, (size_t)kGH * kGH * 2);
    _Float16* eW1t = (_Float16*)carve(p, (size_t)kEH * kEMB * 2);
    _Float16* eW2t = (_Float16*)carve(p, (size_t)kEH * kEH * 2);

    // --- Setup (prep + wtrans + gbounds, one dispatch) ---
    setup_kernel<<<299 + 2944 + 10, 256, 0, stream>>>(
        atom_emb, gW1, gW2, M11, w2t, m11t,
        dW1, dW2, dW3, fcW, eW1, eW2,
        dW1t, dW2t, dW3t, fcWt, eW1t, eW2t,
        batch1, batch2, gstart);
    // --- Graph structure via LDS binning (zero global atomics) ---
    binp1_kernel<<<dim3(kPBLK, 2), 256, 0, stream>>>(ei1, ei2, poff);
    scanA_kernel<<<dim3(kNBKT, 2), 256, 0, stream>>>(poff, btot);
    binp2_kernel<<<dim3(kPBLK, 2), 256, 0, stream>>>(ei1, ei2, poff, btot, ebuf);
    binp3_kernel<<<dim3(kNBKT, 2), 256, 0, stream>>>(ebuf, btot, col_ell, counts,
                                                     dinv, xd, x1, x2);
    // --- Conv1 histogram, edge-centric (LDS float atomics) -> wt16 ---
    binp4_kernel<<<dim3(kNBKT, 2), 256, 0, stream>>>(ebuf, btot, xd, wt16);
    // --- Fused conv1-GEMM + conv2-GEMM: hs8 directly from wt16 (no h2) ---
    gemm2f_kernel<<<dim3((kN + 127) / 128, kGH / 128, 2), 256, 0, stream>>>(
        wt16, m11t, gb1, w2t, dinv, hs8);
    // --- Conv2 aggregate (proven floor) -> h4 (fp8) ---
    aggregate2_kernel<<<dim3((kN + 3) / 4, 2), 256, 0, stream>>>(hs8, dinv, counts, col_ell,
                                                                 gb2, h4_8);
    // --- Mean-pool + entity gather (one dispatch) ---
    pooleg_kernel<<<dim3(kG, 3), 256, 0, stream>>>(h4_8, gstart, pooled16,
                                                   ent_emb, ent1, ent2, e16);
    // --- fc & eW1 (independent) in one dispatch ---
    gemm_pair_kernel<<<dim3(2 * kG / 64, kGH / 64, 2), 256, 0, stream>>>(
        pooled16, fcWt, gfc16, fcb, e16, eW1t, etmp16, eb1);
    // --- Remaining tail (sequential deps) ---
    gemm_tail_kernel<<<dim3(2 * kG / 64, kEH / 64), 256, 0, stream>>>(
        etmp16, eW2t, ento16, kEH, kEH, eb2, 1, 0);
    egsprep_kernel<<<kG * kHID / 8 / 256, 256, 0, stream>>>(gfc16, ento16, egs16);
    gemm_tail_kernel<<<dim3(kG / 64, kHID / 64), 256, 0, stream>>>(
        egs16, dW1t, dh1_16, kHID, kHID, db1, 1, 0);
    gemm_tail_kernel<<<dim3(kG / 64, kHID / 64), 256, 0, stream>>>(
        dh1_16, dW2t, dh2_16, kHID, kHID, db2, 1, 0);
    gemm_tail_kernel<<<dim3(kG / 64, kOUT / 64), 256, 0, stream>>>(
        dh2_16, dW3t, out, kOUT, kHID, db3, 0, 1);
}

// Round 16
// 362.881 us; speedup vs baseline: 1.2598x; 1.0130x over previous
//
#include <hip/hip_runtime.h>
#include <hip/hip_fp16.h>

// Problem constants
static constexpr int kN = 50000;      // nodes per side
static constexpr int kE = 800000;     // edges per side
static constexpr int kG = 1024;       // graphs per batch
static constexpr int kEMB = 128;
static constexpr int kGH = 256;
static constexpr int kEH = 256;
static constexpr int kOUT = 128;
static constexpr int kHID = 512;
static constexpr int kNB = (kN + 255) / 256;   // 196 chunks per side
static constexpr int kMD = 64;        // ELL stride; deg ~ Poisson(16), P(deg>=64)~e^-125
static constexpr int kNBKT = 196;     // dst buckets of 256 nodes (50000 -> 196)
static constexpr int kEPB = 3125;     // edges per bin block; 256 blocks exactly
static constexpr int kPBLK = 256;     // bin blocks per side (256*3125 = 800000)

typedef __attribute__((ext_vector_type(8))) _Float16 half8v;
typedef __attribute__((ext_vector_type(4))) _Float16 half4v;
typedef __attribute__((ext_vector_type(4))) float floatx4;
typedef __attribute__((ext_vector_type(2))) float floatx2;

// NOTE (R6): cross-XCD plain-data handoff through grid.sync() gave stale reads.
// NOTE (R7/R12): device atomics memory-side; floor is OP-COUNT ~21/ns.
// (R2) fp8 hs: 659->616us, absmax UNCHANGED. (R6) LDS bucket binning: ->523us.
// (R7) fp16-MFMA tail: ->439us; aggregate2 ~59-61us = proven gather-FETCH
// floor (R14: halving its write didn't move duration; R8-R11 fusion regressed).
// (R13) h2 eliminated in gemm2f: -3us (mid-stack is latency/dispatch-bound).
// (R14) binp4 edge-centric wt + fp8 h4: -7.4us.
// (R15) dispatch merge 20->15: -20us => boundary cost ~3.4us MEASURED.
// This revision (R16): 15->13 dispatches + coalescing, all bit-identical.
// setup absorbs binp1 (independent); wtrans re-done as LDS-tiled 64x64
// transpose (both sides coalesced, 2944->184 blocks); egsprep fused into the
// dW1 GEMM's A-load (same fp32-add/relu/fp16-round order).

// fp8 fixed scale: |hs| <~ 0.2 typ; x128 keeps values in e4m3 normal range.
#define HS_SCALE 128.0f
#define HS_INV   (1.0f / 128.0f)

__device__ inline void acc_fp8x4(unsigned int w, float& a0, float& a1, float& a2, float& a3) {
    floatx2 lo = __builtin_amdgcn_cvt_pk_f32_fp8(w, false);
    floatx2 hi = __builtin_amdgcn_cvt_pk_f32_fp8(w, true);
    a0 += lo[0]; a1 += lo[1]; a2 += hi[0]; a3 += hi[1];
}

// ---------------------------------------------------------------------------
// setup: prep (blocks 0..298) + tiled weight transpose (299..482) +
// binp1 edge histogram (483..994) + gbounds (995..1004). One dispatch.
// ---------------------------------------------------------------------------
__global__ void setup_kernel(const float* __restrict__ atom_emb, const float* __restrict__ gW1,
                             const float* __restrict__ gW2,
                             float* __restrict__ M11, _Float16* __restrict__ w2t,
                             _Float16* __restrict__ m11t,
                             const float* __restrict__ dW1, const float* __restrict__ dW2,
                             const float* __restrict__ dW3, const float* __restrict__ fcW,
                             const float* __restrict__ eW1, const float* __restrict__ eW2,
                             _Float16* __restrict__ dW1t, _Float16* __restrict__ dW2t,
                             _Float16* __restrict__ dW3t, _Float16* __restrict__ fcWt,
                             _Float16* __restrict__ eW1t, _Float16* __restrict__ eW2t,
                             const int* __restrict__ batch1, const int* __restrict__ batch2,
                             int* __restrict__ gstart,
                             const int* __restrict__ ei1, const int* __restrict__ ei2,
                             int* __restrict__ poff) {
    __shared__ _Float16 tile[64][66];   // 66 pad: 132B row stride -> conflict-free transp. read
    __shared__ int hist[kNBKT];
    int blk = blockIdx.x;
    int tid = threadIdx.x;
    if (blk < 299) {
        int i = blk * 256 + tid;
        if (blk < 256) {
            int k = i >> 8, n = i & 255;
            w2t[(size_t)n * kGH + k] = (_Float16)gW2[(size_t)k * kGH + n];
        } else {
            int j = i - 65536;
            if (j < 11 * kGH) {
                int r = j >> 8, c = j & 255;
                float s = 0.f;
                for (int k = 0; k < kEMB; k++) s += atom_emb[r * kEMB + k] * gW1[k * kGH + c];
                M11[j] = s;
            } else if (j < 11 * kGH + 256 * 32) {
                int j2 = j - 11 * kGH;
                int n = j2 >> 5, k = j2 & 31;     // m11t[n][k] = M11[k][n], 0 for k>=11
                float s = 0.f;
                if (k < 11)
                    for (int p = 0; p < kEMB; p++) s += atom_emb[k * kEMB + p] * gW1[p * kGH + n];
                m11t[j2] = (_Float16)s;
            }
        }
    } else if (blk < 299 + 184) {
        // Tiled 64x64 transpose: coalesced fp32 read, coalesced fp16 write.
        int b = blk - 299;
        const float* src; _Float16* dst; int K, N, tt;
        if (b < 64)       { src = dW1; dst = dW1t; K = 512; N = 512; tt = b; }
        else if (b < 128) { src = dW2; dst = dW2t; K = 512; N = 512; tt = b - 64; }
        else if (b < 144) { src = dW3; dst = dW3t; K = 512; N = 128; tt = b - 128; }
        else if (b < 160) { src = fcW; dst = fcWt; K = 256; N = 256; tt = b - 144; }
        else if (b < 168) { src = eW1; dst = eW1t; K = 128; N = 256; tt = b - 160; }
        else              { src = eW2; dst = eW2t; K = 256; N = 256; tt = b - 168; }
        int tilesN = N >> 6;
        int tk = tt / tilesN, tn = tt - tk * tilesN;
        int k0 = tk * 64, n0 = tn * 64;
        #pragma unroll
        for (int it = 0; it < 16; it++) {
            int idx = tid + it * 256;
            int kk = idx >> 6, nn = idx & 63;
            tile[kk][nn] = (_Float16)src[(size_t)(k0 + kk) * N + n0 + nn];
        }
        __syncthreads();
        #pragma unroll
        for (int it = 0; it < 16; it++) {
            int idx = tid + it * 256;
            int nn = idx >> 6, kk = idx & 63;
            dst[(size_t)(n0 + nn) * K + k0 + kk] = tile[kk][nn];
        }
    } else if (blk < 299 + 184 + 512) {
        // binp1: per-block LDS histogram over 196 dst-buckets.
        int b = blk - (299 + 184);           // 0..511
        int side = b >> 8;
        int bb = b & 255;
        const int* dstp = (side ? ei2 : ei1) + kE;
        if (tid < kNBKT) hist[tid] = 0;
        __syncthreads();
        int base = bb * kEPB;
        for (int j = tid; j < kEPB; j += 256)
            atomicAdd(&hist[dstp[base + j] >> 8], 1);
        __syncthreads();
        if (tid < kNBKT) poff[((side * kNBKT + tid) << 8) | bb] = hist[tid];
    } else {
        int b2 = blk - (299 + 184 + 512);    // 0..9
        int side = b2 / 5;
        int g = (b2 % 5) * 256 + tid;
        if (g <= kG) {
            const int* batch = side ? batch2 : batch1;
            int lo = 0, hi = kN;
            while (lo < hi) { int mid = (lo + hi) >> 1; if (batch[mid] < g) lo = mid + 1; else hi = mid; }
            gstart[side * (kG + 1) + g] = lo;
        }
    }
}

// scanA: per (side,bucket) exclusive scan over the 256 block counts; totals.
__global__ void scanA_kernel(int* __restrict__ poff, int* __restrict__ btot) {
    int b = blockIdx.x, side = blockIdx.y, t = threadIdx.x;
    __shared__ int s[256];
    int idx = ((side * kNBKT + b) << 8) | t;
    int v = poff[idx];
    s[t] = v;
    __syncthreads();
    for (int o = 1; o < 256; o <<= 1) {
        int u = (t >= o) ? s[t - o] : 0;
        __syncthreads();
        s[t] += u;
        __syncthreads();
    }
    poff[idx] = s[t] - v;
    if (t == 255) btot[side * kNBKT + b] = s[255];
}

// ---------------------------------------------------------------------------
// binp2: block-local LDS bucket-sort, coalesced bucket-major write-out.
// Bucket bases re-derived internally from btot.
// ---------------------------------------------------------------------------
__launch_bounds__(256)
__global__ void binp2_kernel(const int* __restrict__ ei1, const int* __restrict__ ei2,
                             const int* __restrict__ poff, const int* __restrict__ btot,
                             unsigned int* __restrict__ ebuf) {
    int side = blockIdx.y, blk = blockIdx.x, t = threadIdx.x;
    const int* ei = side ? ei2 : ei1;
    __shared__ int hist[kNBKT], lb[kNBKT], gb[kNBKT], scanbuf[256];
    __shared__ unsigned int sorted[kEPB];
    // btot exclusive scan -> per-bucket global base (register gbb).
    int bv = (t < kNBKT) ? btot[side * kNBKT + t] : 0;
    scanbuf[t] = bv;
    __syncthreads();
    for (int o = 1; o < 256; o <<= 1) {
        int u = (t >= o) ? scanbuf[t - o] : 0;
        __syncthreads();
        scanbuf[t] += u;
        __syncthreads();
    }
    int gbb = scanbuf[t] - bv;
    __syncthreads();
    if (t < kNBKT) hist[t] = 0;
    __syncthreads();
    int base = blk * kEPB;
    for (int j = t; j < kEPB; j += 256)
        atomicAdd(&hist[ei[kE + base + j] >> 8], 1);
    __syncthreads();
    int v = (t < kNBKT) ? hist[t] : 0;
    scanbuf[t] = v;
    __syncthreads();
    for (int o = 1; o < 256; o <<= 1) {
        int u = (t >= o) ? scanbuf[t - o] : 0;
        __syncthreads();
        scanbuf[t] += u;
        __syncthreads();
    }
    if (t < kNBKT) {
        lb[t] = scanbuf[t] - v;
        gb[t] = gbb + poff[((side * kNBKT + t) << 8) | blk];
        hist[t] = 0;
    }
    __syncthreads();
    for (int j = t; j < kEPB; j += 256) {
        int s_ = ei[base + j];
        int d  = ei[kE + base + j];
        int b  = d >> 8;
        int r  = atomicAdd(&hist[b], 1);
        sorted[lb[b] + r] = ((unsigned int)d << 16) | (unsigned int)s_;
    }
    __syncthreads();
    for (int j = t; j < kEPB; j += 256) {
        unsigned int val = sorted[j];
        int b = val >> 24;
        int gpos = gb[b] + (j - lb[b]);
        ebuf[(size_t)side * kE + gpos] = val;
    }
}

// ---------------------------------------------------------------------------
// binp3: one block per bucket; LDS slot counters; col_ell stores in a 32KB
// window. Bucket range from internal btot scan. Epilogue: counts, dinv, xd.
// ---------------------------------------------------------------------------
__global__ void binp3_kernel(const unsigned int* __restrict__ ebuf, const int* __restrict__ btot,
                             unsigned short* __restrict__ col_ell, int* __restrict__ counts,
                             float* __restrict__ dinv, int2* __restrict__ xd,
                             const int* __restrict__ x1, const int* __restrict__ x2) {
    int b = blockIdx.x, side = blockIdx.y, t = threadIdx.x;
    __shared__ int s[256];
    __shared__ int cnt[256];
    int bv = (t < kNBKT) ? btot[side * kNBKT + t] : 0;
    s[t] = bv;
    cnt[t] = 0;
    __syncthreads();
    for (int o = 1; o < 256; o <<= 1) {
        int u = (t >= o) ? s[t - o] : 0;
        __syncthreads();
        s[t] += u;
        __syncthreads();
    }
    int start = (b > 0) ? s[b - 1] : 0;
    int end   = s[b];
    for (int k = start + t; k < end; k += 256) {
        unsigned int v = ebuf[(size_t)side * kE + k];
        int d8 = (v >> 16) & 255;
        int slot = atomicAdd(&cnt[d8], 1);
        if (slot > kMD - 1) slot = kMD - 1;
        int node = (b << 8) | d8;
        col_ell[((size_t)side * kN + node) * kMD + slot] = (unsigned short)(v & 0xFFFFu);
    }
    __syncthreads();
    int node = (b << 8) | t;
    if (node < kN) {
        int d = cnt[t];
        counts[side * kN + node] = d;
        float dv = rsqrtf((float)(d + 1));           // +1 self-loop
        dinv[side * kN + node] = dv;
        const int* x = side ? x2 : x1;
        xd[side * kN + node] = make_int2(x[node], __float_as_int(dv));
    }
}

// ---------------------------------------------------------------------------
// binp4: edge-centric conv1 histogram; bucket range from internal btot scan.
// wtl[dst&255][x[src]] += dinv[src] via LDS float atomics; epilogue emits
// wt16[v][32] (wt'[s] = dv*wtl[s] + dv^2*delta(x[v]=s), zero pad 16..31).
// ---------------------------------------------------------------------------
__global__ void binp4_kernel(const unsigned int* __restrict__ ebuf, const int* __restrict__ btot,
                             const int2* __restrict__ xd, _Float16* __restrict__ wt16) {
    int b = blockIdx.x, side = blockIdx.y, t = threadIdx.x;
    const int2* xdb = xd + (size_t)side * kN;
    __shared__ int s[256];
    __shared__ float wtl[256][16];
    int bv = (t < kNBKT) ? btot[side * kNBKT + t] : 0;
    s[t] = bv;
    #pragma unroll
    for (int q = 0; q < 16; q++) wtl[t][q] = 0.f;
    __syncthreads();
    for (int o = 1; o < 256; o <<= 1) {
        int u = (t >= o) ? s[t - o] : 0;
        __syncthreads();
        s[t] += u;
        __syncthreads();
    }
    int start = (b > 0) ? s[b - 1] : 0;
    int end   = s[b];
    for (int k = start + t; k < end; k += 256) {
        unsigned int v = ebuf[(size_t)side * kE + k];
        int src = v & 0xFFFFu;
        int d8 = (v >> 16) & 255;
        int2 xs = xdb[src];
        atomicAdd(&wtl[d8][xs.x], __int_as_float(xs.y));
    }
    __syncthreads();
    int node = (b << 8) | t;
    if (node < kN) {
        int2 xv = xdb[node];
        float dv = __int_as_float(xv.y);
        float dv2 = dv * dv;
        _Float16* wb = wt16 + ((size_t)side * kN + node) * 32;
        half8v o0, o1, z;
        #pragma unroll
        for (int q = 0; q < 8; q++) {
            o0[q] = (_Float16)(dv * wtl[t][q] + ((xv.x == q) ? dv2 : 0.f));
            o1[q] = (_Float16)(dv * wtl[t][q + 8] + ((xv.x == q + 8) ? dv2 : 0.f));
            z[q] = (_Float16)0.f;
        }
        *(half8v*)(wb) = o0;
        *(half8v*)(wb + 8) = o1;
        *(half8v*)(wb + 16) = z;
        *(half8v*)(wb + 24) = z;
    }
}

// ---------------------------------------------------------------------------
// Fused conv1-GEMM + conv2-GEMM: hs8 = fp8(128*dinv ⊙ (relu(wt16@M11+b1) @ W2))
// h2 computed on the fly per k0-step via swapped-operand mfma.
// ---------------------------------------------------------------------------
__launch_bounds__(256)
__global__ void gemm2f_kernel(const _Float16* __restrict__ wt16,
                              const _Float16* __restrict__ m11t,
                              const float* __restrict__ b1,
                              const _Float16* __restrict__ Bt,
                              const float* __restrict__ dinv,
                              unsigned char* __restrict__ C) {
    __shared__ _Float16 As[128][72];
    __shared__ _Float16 Bs[128][72];

    int side = blockIdx.z;
    const _Float16* Aw = wt16 + (size_t)side * kN * 32;
    const float* db = dinv + (size_t)side * kN;
    unsigned char* Cb = C + (size_t)side * kN * kGH;

    int tid = threadIdx.x;
    int wave = tid >> 6, lane = tid & 63;
    int quad = lane >> 4, r = lane & 15;
    int wm = wave >> 1, wn = wave & 1;
    int row0 = blockIdx.x * 128;
    int col0 = blockIdx.y * 128;

    floatx4 acc[4][4];
    #pragma unroll
    for (int i = 0; i < 4; i++)
        #pragma unroll
        for (int j = 0; j < 4; j++) acc[i][j] = (floatx4){0.f, 0.f, 0.f, 0.f};

    half8v afw[2];
    #pragma unroll
    for (int mt = 0; mt < 2; mt++) {
        int gr = row0 + wave * 32 + mt * 16 + r;
        if (gr >= kN) gr = kN - 1;
        afw[mt] = *(const half8v*)(Aw + (size_t)gr * 32 + quad * 8);
    }

    for (int k0 = 0; k0 < kGH; k0 += 64) {
        #pragma unroll
        for (int u = 0; u < 4; u++) {
            int idx = tid + u * 256;           // 0..1023
            int row = idx >> 3;                // 0..127
            int seg = (idx & 7) * 8;           // 0..56
            *(half8v*)&Bs[row][seg] = *(const half8v*)(Bt + (size_t)(col0 + row) * kGH + k0 + seg);
        }
        #pragma unroll
        for (int nt = 0; nt < 4; nt++) {
            half8v bfw = *(const half8v*)(m11t + (size_t)(k0 + nt * 16 + r) * 32 + quad * 8);
            float4 bia = *(const float4*)(b1 + k0 + nt * 16 + quad * 4);
            #pragma unroll
            for (int mt = 0; mt < 2; mt++) {
                floatx4 d = (floatx4){0.f, 0.f, 0.f, 0.f};
                d = __builtin_amdgcn_mfma_f32_16x16x32_f16(bfw, afw[mt], d, 0, 0, 0);
                half4v o;
                o[0] = (_Float16)fmaxf(d[0] + bia.x, 0.f);
                o[1] = (_Float16)fmaxf(d[1] + bia.y, 0.f);
                o[2] = (_Float16)fmaxf(d[2] + bia.z, 0.f);
                o[3] = (_Float16)fmaxf(d[3] + bia.w, 0.f);
                *(half4v*)&As[wave * 32 + mt * 16 + r][nt * 16 + quad * 4] = o;
            }
        }
        __syncthreads();
        #pragma unroll
        for (int ks = 0; ks < 2; ks++) {
            half8v af[4], bf[4];
            #pragma unroll
            for (int mt = 0; mt < 4; mt++)
                af[mt] = *(const half8v*)&As[wm * 64 + mt * 16 + r][ks * 32 + quad * 8];
            #pragma unroll
            for (int nt = 0; nt < 4; nt++)
                bf[nt] = *(const half8v*)&Bs[wn * 64 + nt * 16 + r][ks * 32 + quad * 8];
            #pragma unroll
            for (int mt = 0; mt < 4; mt++)
                #pragma unroll
                for (int nt = 0; nt < 4; nt++)
                    acc[mt][nt] = __builtin_amdgcn_mfma_f32_16x16x32_f16(af[mt], bf[nt],
                                                                         acc[mt][nt], 0, 0, 0);
        }
        __syncthreads();
    }

    #pragma unroll
    for (int mt = 0; mt < 4; mt++) {
        #pragma unroll
        for (int i = 0; i < 4; i++) {
            int grow = row0 + wm * 64 + mt * 16 + quad * 4 + i;
            if (grow >= kN) continue;
            float rsq = db[grow] * HS_SCALE;
            #pragma unroll
            for (int nt = 0; nt < 4; nt++) {
                int gcol = col0 + wn * 64 + nt * 16 + r;
                float q = acc[mt][nt][i] * rsq;
                Cb[(size_t)grow * kGH + gcol] =
                    (unsigned char)__builtin_amdgcn_cvt_pk_fp8_f32(q, q, 0, false);
            }
        }
    }
}

// ---------------------------------------------------------------------------
// Unified tail GEMM via MFMA f16 (fp32 accum): C = [relu](A @ B + bias)
// ---------------------------------------------------------------------------
__launch_bounds__(256)
__global__ void gemm_tail_kernel(const _Float16* __restrict__ A,
                                 const _Float16* __restrict__ Bt,
                                 void* __restrict__ Cout,
                                 int N, int K,
                                 const float* __restrict__ bias,
                                 int relu, int f32out) {
    __shared__ _Float16 As[64][72];
    __shared__ _Float16 Bs[64][72];
    int tid = threadIdx.x;
    int wave = tid >> 6, lane = tid & 63;
    int quad = lane >> 4, r = lane & 15;
    int wm = wave >> 1, wn = wave & 1;
    int row0 = blockIdx.x * 64, col0 = blockIdx.y * 64;

    floatx4 acc[2][2];
    #pragma unroll
    for (int i = 0; i < 2; i++)
        #pragma unroll
        for (int j = 0; j < 2; j++) acc[i][j] = (floatx4){0.f, 0.f, 0.f, 0.f};

    for (int k0 = 0; k0 < K; k0 += 64) {
        #pragma unroll
        for (int u = 0; u < 2; u++) {
            int idx = tid + u * 256;           // 0..511
            int row = idx >> 3;                // 0..63
            int seg = (idx & 7) * 8;           // 0..56
            *(half8v*)&As[row][seg] = *(const half8v*)(A + (size_t)(row0 + row) * K + k0 + seg);
            *(half8v*)&Bs[row][seg] = *(const half8v*)(Bt + (size_t)(col0 + row) * K + k0 + seg);
        }
        __syncthreads();
        #pragma unroll
        for (int ks = 0; ks < 2; ks++) {
            half8v af[2], bf[2];
            #pragma unroll
            for (int mt = 0; mt < 2; mt++)
                af[mt] = *(const half8v*)&As[wm * 32 + mt * 16 + r][ks * 32 + quad * 8];
            #pragma unroll
            for (int nt = 0; nt < 2; nt++)
                bf[nt] = *(const half8v*)&Bs[wn * 32 + nt * 16 + r][ks * 32 + quad * 8];
            #pragma unroll
            for (int mt = 0; mt < 2; mt++)
                #pragma unroll
                for (int nt = 0; nt < 2; nt++)
                    acc[mt][nt] = __builtin_amdgcn_mfma_f32_16x16x32_f16(af[mt], bf[nt],
                                                                         acc[mt][nt], 0, 0, 0);
        }
        __syncthreads();
    }

    #pragma unroll
    for (int mt = 0; mt < 2; mt++) {
        #pragma unroll
        for (int i = 0; i < 4; i++) {
            int grow = row0 + wm * 32 + mt * 16 + quad * 4 + i;
            #pragma unroll
            for (int nt = 0; nt < 2; nt++) {
                int gcol = col0 + wn * 32 + nt * 16 + r;
                float v = acc[mt][nt][i] + bias[gcol];
                if (relu) v = fmaxf(v, 0.f);
                if (f32out) ((float*)Cout)[(size_t)grow * N + gcol] = v;
                else ((_Float16*)Cout)[(size_t)grow * N + gcol] = (_Float16)v;
            }
        }
    }
}

// ---------------------------------------------------------------------------
// gemm_egs16 (R16): dW1 GEMM with egsprep fused into the A-load.
// A row g, col k: fp16(relu(float(srcA[g][k']) + float(srcA[g+kG][k'])))
// where srcA = gfc16 for k<256, ento16 for k>=256 — exact egsprep arithmetic.
// ---------------------------------------------------------------------------
__launch_bounds__(256)
__global__ void gemm_egs16_kernel(const _Float16* __restrict__ gfc16,
                                  const _Float16* __restrict__ ento16,
                                  const _Float16* __restrict__ Bt,
                                  _Float16* __restrict__ Cout,
                                  const float* __restrict__ bias) {
    const int N = kHID, K = kHID;
    __shared__ _Float16 As[64][72];
    __shared__ _Float16 Bs[64][72];
    int tid = threadIdx.x;
    int wave = tid >> 6, lane = tid & 63;
    int quad = lane >> 4, r = lane & 15;
    int wm = wave >> 1, wn = wave & 1;
    int row0 = blockIdx.x * 64, col0 = blockIdx.y * 64;

    floatx4 acc[2][2];
    #pragma unroll
    for (int i = 0; i < 2; i++)
        #pragma unroll
        for (int j = 0; j < 2; j++) acc[i][j] = (floatx4){0.f, 0.f, 0.f, 0.f};

    for (int k0 = 0; k0 < K; k0 += 64) {
        #pragma unroll
        for (int u = 0; u < 2; u++) {
            int idx = tid + u * 256;           // 0..511
            int row = idx >> 3;                // 0..63
            int seg = (idx & 7) * 8;           // 0..56
            int g = row0 + row;                // graph id (< kG)
            int k = k0 + seg;                  // 8-wide segment, within one src
            const _Float16* src = (k < kGH) ? gfc16 : ento16;
            int kk = (k < kGH) ? k : k - kGH;
            half8v a = *(const half8v*)(src + (size_t)g * kGH + kk);
            half8v b = *(const half8v*)(src + (size_t)(g + kG) * kGH + kk);
            half8v o;
            #pragma unroll
            for (int q = 0; q < 8; q++)
                o[q] = (_Float16)fmaxf((float)a[q] + (float)b[q], 0.f);
            *(half8v*)&As[row][seg] = o;
            *(half8v*)&Bs[row][seg] = *(const half8v*)(Bt + (size_t)(col0 + row) * K + k0 + seg);
        }
        __syncthreads();
        #pragma unroll
        for (int ks = 0; ks < 2; ks++) {
            half8v af[2], bf[2];
            #pragma unroll
            for (int mt = 0; mt < 2; mt++)
                af[mt] = *(const half8v*)&As[wm * 32 + mt * 16 + r][ks * 32 + quad * 8];
            #pragma unroll
            for (int nt = 0; nt < 2; nt++)
                bf[nt] = *(const half8v*)&Bs[wn * 32 + nt * 16 + r][ks * 32 + quad * 8];
            #pragma unroll
            for (int mt = 0; mt < 2; mt++)
                #pragma unroll
                for (int nt = 0; nt < 2; nt++)
                    acc[mt][nt] = __builtin_amdgcn_mfma_f32_16x16x32_f16(af[mt], bf[nt],
                                                                         acc[mt][nt], 0, 0, 0);
        }
        __syncthreads();
    }

    #pragma unroll
    for (int mt = 0; mt < 2; mt++) {
        #pragma unroll
        for (int i = 0; i < 4; i++) {
            int grow = row0 + wm * 32 + mt * 16 + quad * 4 + i;
            #pragma unroll
            for (int nt = 0; nt < 2; nt++) {
                int gcol = col0 + wn * 32 + nt * 16 + r;
                float v = fmaxf(acc[mt][nt][i] + bias[gcol], 0.f);
                Cout[(size_t)grow * N + gcol] = (_Float16)v;
            }
        }
    }
}

// ---------------------------------------------------------------------------
// gemm_pair: the two INDEPENDENT first tail GEMMs in one launch (z=0: fc,
// z=1: eW1). Same M=2048, N=256; K/relu differ per z.
// ---------------------------------------------------------------------------
__launch_bounds__(256)
__global__ void gemm_pair_kernel(const _Float16* __restrict__ pooled16,
                                 const _Float16* __restrict__ fcWt,
                                 _Float16* __restrict__ gfc16,
                                 const float* __restrict__ fcb,
                                 const _Float16* __restrict__ e16,
                                 const _Float16* __restrict__ eW1t,
                                 _Float16* __restrict__ etmp16,
                                 const float* __restrict__ eb1) {
    const _Float16* A; const _Float16* Bt; _Float16* Cout; const float* bias;
    int K, relu;
    if (blockIdx.z == 0) { A = pooled16; Bt = fcWt; Cout = gfc16; bias = fcb; K = kGH; relu = 0; }
    else                 { A = e16; Bt = eW1t; Cout = etmp16; bias = eb1; K = kEMB; relu = 1; }
    const int N = kGH;

    __shared__ _Float16 As[64][72];
    __shared__ _Float16 Bs[64][72];
    int tid = threadIdx.x;
    int wave = tid >> 6, lane = tid & 63;
    int quad = lane >> 4, r = lane & 15;
    int wm = wave >> 1, wn = wave & 1;
    int row0 = blockIdx.x * 64, col0 = blockIdx.y * 64;

    floatx4 acc[2][2];
    #pragma unroll
    for (int i = 0; i < 2; i++)
        #pragma unroll
        for (int j = 0; j < 2; j++) acc[i][j] = (floatx4){0.f, 0.f, 0.f, 0.f};

    for (int k0 = 0; k0 < K; k0 += 64) {
        #pragma unroll
        for (int u = 0; u < 2; u++) {
            int idx = tid + u * 256;
            int row = idx >> 3;
            int seg = (idx & 7) * 8;
            *(half8v*)&As[row][seg] = *(const half8v*)(A + (size_t)(row0 + row) * K + k0 + seg);
            *(half8v*)&Bs[row][seg] = *(const half8v*)(Bt + (size_t)(col0 + row) * K + k0 + seg);
        }
        __syncthreads();
        #pragma unroll
        for (int ks = 0; ks < 2; ks++) {
            half8v af[2], bf[2];
            #pragma unroll
            for (int mt = 0; mt < 2; mt++)
                af[mt] = *(const half8v*)&As[wm * 32 + mt * 16 + r][ks * 32 + quad * 8];
            #pragma unroll
            for (int nt = 0; nt < 2; nt++)
                bf[nt] = *(const half8v*)&Bs[wn * 32 + nt * 16 + r][ks * 32 + quad * 8];
            #pragma unroll
            for (int mt = 0; mt < 2; mt++)
                #pragma unroll
                for (int nt = 0; nt < 2; nt++)
                    acc[mt][nt] = __builtin_amdgcn_mfma_f32_16x16x32_f16(af[mt], bf[nt],
                                                                         acc[mt][nt], 0, 0, 0);
        }
        __syncthreads();
    }

    #pragma unroll
    for (int mt = 0; mt < 2; mt++) {
        #pragma unroll
        for (int i = 0; i < 4; i++) {
            int grow = row0 + wm * 32 + mt * 16 + quad * 4 + i;
            #pragma unroll
            for (int nt = 0; nt < 2; nt++) {
                int gcol = col0 + wn * 32 + nt * 16 + r;
                float v = acc[mt][nt][i] + bias[gcol];
                if (relu) v = fmaxf(v, 0.f);
                Cout[(size_t)grow * N + gcol] = (_Float16)v;
            }
        }
    }
}

// ---------------------------------------------------------------------------
// Conv2 aggregate (proven floor): one wave per node, no barriers. fp8 h4 out.
// ---------------------------------------------------------------------------
__global__ void aggregate2_kernel(const unsigned char* __restrict__ hs, const float* __restrict__ dinv,
                                  const int* __restrict__ counts,
                                  const unsigned short* __restrict__ col_ell,
                                  const float* __restrict__ bias, unsigned char* __restrict__ out) {
    int side = blockIdx.y;
    const unsigned char* hb = hs + (size_t)side * kN * kGH;
    const float* dv_ = dinv + side * kN;
    const int* deg = counts + side * kN;
    const unsigned short* ci = col_ell + (size_t)side * kN * kMD;
    unsigned char* ob = out + (size_t)side * kN * kGH;

    int wave = threadIdx.x >> 6;
    int lane = threadIdx.x & 63;
    int v = blockIdx.x * 4 + wave;
    if (v >= kN) return;
    int c = lane * 4;
    float4 bia = *(const float4*)(bias + c);
    float dv = dv_[v];
    float a0 = 0.f, a1 = 0.f, a2 = 0.f, a3 = 0.f;
    acc_fp8x4(*(const unsigned int*)(hb + (size_t)v * kGH + c), a0, a1, a2, a3);  // self-loop
    int cnt = min(deg[v], kMD);
    int idxl = (lane < cnt) ? (int)ci[(size_t)v * kMD + lane] : 0;
    int j = 0;
    for (; j + 16 <= cnt; j += 16) {
        unsigned int w[16];
        #pragma unroll
        for (int u = 0; u < 16; u++)
            w[u] = *(const unsigned int*)(hb + (size_t)__shfl(idxl, j + u) * kGH + c);
        #pragma unroll
        for (int u = 0; u < 16; u++) acc_fp8x4(w[u], a0, a1, a2, a3);
    }
    for (; j + 8 <= cnt; j += 8) {
        unsigned int w[8];
        #pragma unroll
        for (int u = 0; u < 8; u++)
            w[u] = *(const unsigned int*)(hb + (size_t)__shfl(idxl, j + u) * kGH + c);
        #pragma unroll
        for (int u = 0; u < 8; u++) acc_fp8x4(w[u], a0, a1, a2, a3);
    }
    for (; j < cnt; j++)
        acc_fp8x4(*(const unsigned int*)(hb + (size_t)__shfl(idxl, j) * kGH + c),
                  a0, a1, a2, a3);
    float f = dv * HS_INV;
    float q0 = fmaxf(f * a0 + bia.x, 0.f) * HS_SCALE;
    float q1 = fmaxf(f * a1 + bia.y, 0.f) * HS_SCALE;
    float q2 = fmaxf(f * a2 + bia.z, 0.f) * HS_SCALE;
    float q3 = fmaxf(f * a3 + bia.w, 0.f) * HS_SCALE;
    unsigned int w = __builtin_amdgcn_cvt_pk_fp8_f32(q0, q1, 0, false);
    w = __builtin_amdgcn_cvt_pk_fp8_f32(q2, q3, w, true);
    __builtin_nontemporal_store(w, (unsigned int*)(ob + (size_t)v * kGH + c));
}

// ---------------------------------------------------------------------------
// pooleg: mean-pool (y<2) + entity gather (y==2) in one dispatch.
// ---------------------------------------------------------------------------
__global__ void pooleg_kernel(const unsigned char* __restrict__ h,
                              const int* __restrict__ gstart,
                              _Float16* __restrict__ pooled16,
                              const float* __restrict__ emb,
                              const int* __restrict__ ent1, const int* __restrict__ ent2,
                              _Float16* __restrict__ e16) {
    if (blockIdx.y == 2) {
        int rr = blockIdx.x * 2 + (threadIdx.x >> 7);   // 0..2047
        int k = threadIdx.x & 127;
        int idx = (rr < kG) ? ent1[rr] : ent2[rr - kG];
        e16[(size_t)rr * kEMB + k] = (_Float16)fmaxf(emb[(size_t)idx * kEMB + k], 0.f);
        return;
    }
    int side = blockIdx.y;
    int g = blockIdx.x;
    const unsigned char* hb = h + (size_t)side * kN * kGH;
    int start = gstart[side * (kG + 1) + g];
    int end   = gstart[side * (kG + 1) + g + 1];
    int wave = threadIdx.x >> 6, lane = threadIdx.x & 63;
    int c = lane * 4;
    float a0 = 0.f, a1 = 0.f, a2 = 0.f, a3 = 0.f;
    for (int v = start + wave; v < end; v += 4)
        acc_fp8x4(*(const unsigned int*)(hb + (size_t)v * kGH + c), a0, a1, a2, a3);
    __shared__ float ps[4][256];
    *(float4*)&ps[wave][c] = make_float4(a0, a1, a2, a3);
    __syncthreads();
    int t = threadIdx.x;
    float s = ps[0][t] + ps[1][t] + ps[2][t] + ps[3][t];
    float inv = HS_INV / fmaxf((float)(end - start), 1.0f);
    pooled16[(size_t)(side * kG + g) * kGH + t] = (_Float16)(s * inv);
}

// ---------------------------------------------------------------------------
// Host launch
// ---------------------------------------------------------------------------
static inline char* carve(char*& p, size_t bytes) {
    char* r = p;
    p += (bytes + 255) & ~(size_t)255;
    return r;
}

extern "C" void kernel_launch(void* const* d_in, const int* in_sizes, int n_in,
                              void* d_out, int out_size, void* d_ws, size_t ws_size,
                              hipStream_t stream) {
    const int*   x1       = (const int*)d_in[0];
    const int*   ei1      = (const int*)d_in[1];
    const int*   ent1     = (const int*)d_in[2];
    const int*   batch1   = (const int*)d_in[3];
    const int*   x2       = (const int*)d_in[4];
    const int*   ei2      = (const int*)d_in[5];
    const int*   ent2     = (const int*)d_in[6];
    const int*   batch2   = (const int*)d_in[7];
    const float* atom_emb = (const float*)d_in[8];
    const float* gW1      = (const float*)d_in[9];
    const float* gb1      = (const float*)d_in[10];
    const float* gW2      = (const float*)d_in[11];
    const float* gb2      = (const float*)d_in[12];
    const float* fcW      = (const float*)d_in[13];
    const float* fcb      = (const float*)d_in[14];
    const float* ent_emb  = (const float*)d_in[15];
    const float* eW1      = (const float*)d_in[16];
    const float* eb1      = (const float*)d_in[17];
    const float* eW2      = (const float*)d_in[18];
    const float* eb2      = (const float*)d_in[19];
    const float* dW1      = (const float*)d_in[20];
    const float* db1      = (const float*)d_in[21];
    const float* dW2      = (const float*)d_in[22];
    const float* db2      = (const float*)d_in[23];
    const float* dW3      = (const float*)d_in[24];
    const float* db3      = (const float*)d_in[25];
    float* out = (float*)d_out;

    // Workspace carve (no zeroed spans needed — binp3 writes all counts).
    char* p = (char*)d_ws;
    unsigned char* h4_8 = (unsigned char*)carve(p, (size_t)2 * kN * kGH);  // fp8 h4
    unsigned char* hs8  = (unsigned char*)carve(p, (size_t)2 * kN * kGH);  // fp8 hs
    unsigned short* col_ell = (unsigned short*)carve(p, (size_t)2 * kN * kMD * 2);
    unsigned int* ebuf = (unsigned int*)carve(p, (size_t)2 * kE * 4);
    int*   poff    = (int*)  carve(p, (size_t)2 * kNBKT * 256 * 4);
    int*   btot    = (int*)  carve(p, (size_t)2 * kNBKT * 4);
    int*   counts  = (int*)  carve(p, (size_t)2 * kN * 4);
    float* dinv    = (float*)carve(p, (size_t)2 * kN * 4);
    int2*  xd      = (int2*) carve(p, (size_t)2 * kN * 8);
    int*   gstart  = (int*)  carve(p, (size_t)2 * (kG + 1) * 4);
    float* M11     = (float*)carve(p, 11 * kGH * 4);
    _Float16* w2t  = (_Float16*)carve(p, (size_t)kGH * kGH * 2);
    _Float16* m11t = (_Float16*)carve(p, (size_t)256 * 32 * 2);
    _Float16* wt16 = (_Float16*)carve(p, (size_t)2 * kN * 32 * 2);
    // fp16 tail buffers
    _Float16* pooled16 = (_Float16*)carve(p, (size_t)2 * kG * kGH * 2);
    _Float16* gfc16    = (_Float16*)carve(p, (size_t)2 * kG * kGH * 2);
    _Float16* e16      = (_Float16*)carve(p, (size_t)2 * kG * kEMB * 2);
    _Float16* etmp16   = (_Float16*)carve(p, (size_t)2 * kG * kEH * 2);
    _Float16* ento16   = (_Float16*)carve(p, (size_t)2 * kG * kEH * 2);
    _Float16* dh1_16   = (_Float16*)carve(p, (size_t)kG * kHID * 2);
    _Float16* dh2_16   = (_Float16*)carve(p, (size_t)kG * kHID * 2);
    // fp16 transposed tail weights
    _Float16* dW1t = (_Float16*)carve(p, (size_t)kHID * kHID * 2);
    _Float16* dW2t = (_Float16*)carve(p, (size_t)kHID * kHID * 2);
    _Float16* dW3t = (_Float16*)carve(p, (size_t)kOUT * kHID * 2);
    _Float16* fcWt = (_Float16*)carve(p, (size_t)kGH * kGH * 2);
    _Float16* eW1t = (_Float16*)carve(p, (size_t)kEH * kEMB * 2);
    _Float16* eW2t = (_Float16*)carve(p, (size_t)kEH * kEH * 2);

    // --- Setup (prep + tiled wtrans + binp1 + gbounds, one dispatch) ---
    setup_kernel<<<299 + 184 + 512 + 10, 256, 0, stream>>>(
        atom_emb, gW1, gW2, M11, w2t, m11t,
        dW1, dW2, dW3, fcW, eW1, eW2,
        dW1t, dW2t, dW3t, fcWt, eW1t, eW2t,
        batch1, batch2, gstart,
        ei1, ei2, poff);
    // --- Graph structure via LDS binning (zero global atomics) ---
    scanA_kernel<<<dim3(kNBKT, 2), 256, 0, stream>>>(poff, btot);
    binp2_kernel<<<dim3(kPBLK, 2), 256, 0, stream>>>(ei1, ei2, poff, btot, ebuf);
    binp3_kernel<<<dim3(kNBKT, 2), 256, 0, stream>>>(ebuf, btot, col_ell, counts,
                                                     dinv, xd, x1, x2);
    // --- Conv1 histogram, edge-centric (LDS float atomics) -> wt16 ---
    binp4_kernel<<<dim3(kNBKT, 2), 256, 0, stream>>>(ebuf, btot, xd, wt16);
    // --- Fused conv1-GEMM + conv2-GEMM: hs8 directly from wt16 (no h2) ---
    gemm2f_kernel<<<dim3((kN + 127) / 128, kGH / 128, 2), 256, 0, stream>>>(
        wt16, m11t, gb1, w2t, dinv, hs8);
    // --- Conv2 aggregate (proven floor) -> h4 (fp8) ---
    aggregate2_kernel<<<dim3((kN + 3) / 4, 2), 256, 0, stream>>>(hs8, dinv, counts, col_ell,
                                                                 gb2, h4_8);
    // --- Mean-pool + entity gather (one dispatch) ---
    pooleg_kernel<<<dim3(kG, 3), 256, 0, stream>>>(h4_8, gstart, pooled16,
                                                   ent_emb, ent1, ent2, e16);
    // --- fc & eW1 (independent) in one dispatch ---
    gemm_pair_kernel<<<dim3(2 * kG / 64, kGH / 64, 2), 256, 0, stream>>>(
        pooled16, fcWt, gfc16, fcb, e16, eW1t, etmp16, eb1);
    // --- Remaining tail (sequential deps); egsprep fused into dW1 GEMM ---
    gemm_tail_kernel<<<dim3(2 * kG / 64, kEH / 64), 256, 0, stream>>>(
        etmp16, eW2t, ento16, kEH, kEH, eb2, 1, 0);
    gemm_egs16_kernel<<<dim3(kG / 64, kHID / 64), 256, 0, stream>>>(
        gfc16, ento16, dW1t, dh1_16, db1);
    gemm_tail_kernel<<<dim3(kG / 64, kHID / 64), 256, 0, stream>>>(
        dh1_16, dW2t, dh2_16, kHID, kHID, db2, 1, 0);
    gemm_tail_kernel<<<dim3(kG / 64, kOUT / 64), 256, 0, stream>>>(
        dh2_16, dW3t, out, kOUT, kHID, db3, 0, 1);
}